// Round 2
// baseline (1420.930 us; speedup 1.0000x reference)
//
#include <hip/hip_runtime.h>
#include <cstdint>
#include <cstddef>

typedef unsigned short u16;
typedef short bf16x8 __attribute__((ext_vector_type(8)));
typedef float f32x4 __attribute__((ext_vector_type(4)));

#define DEV __device__ __forceinline__

// ---------- constants ----------
constexpr int Bb = 4, Tt = 1024, Cc = 2048, Hh = 32, Nd = 64, FF = 7168;
constexpr int BT = Bb * Tt; // 4096

// ---------- helpers ----------
DEV u16 f2bf(float f) {
  union { float f; unsigned u; } un; un.f = f;
  unsigned r = un.u + 0x7FFFu + ((un.u >> 16) & 1u);
  return (u16)(r >> 16);
}
DEV float bf2f(u16 h) {
  union { unsigned u; float f; } un; un.u = ((unsigned)h) << 16;
  return un.f;
}
DEV float rlane(float x, int l) {
  return __builtin_bit_cast(float, __builtin_amdgcn_readlane(__builtin_bit_cast(int, x), l));
}
// global -> LDS direct, 16B per lane. Proper addrspacecasts (CK/HK pattern).
DEV void gll16(const u16* gp, u16* lp) {
  __builtin_amdgcn_global_load_lds(
      (const __attribute__((address_space(1))) unsigned int*)gp,
      (__attribute__((address_space(3))) unsigned int*)lp,
      16, 0, 0);
}

// ---------- transpose + f32->bf16: W[Kk][Nn] -> Wt[Nn][Kk] ----------
__global__ void transpose_to_bf16(const float* __restrict__ W, u16* __restrict__ Wt,
                                  int Kk, int Nn) {
  __shared__ float tile[32][33];
  int n0 = blockIdx.x * 32, k0 = blockIdx.y * 32;
  int tx = threadIdx.x & 31, ty = threadIdx.x >> 5; // 32 x 8
  #pragma unroll
  for (int r = 0; r < 32; r += 8)
    tile[r + ty][tx] = W[(size_t)(k0 + r + ty) * Nn + n0 + tx];
  __syncthreads();
  #pragma unroll
  for (int r = 0; r < 32; r += 8)
    Wt[(size_t)(n0 + r + ty) * Kk + k0 + tx] = f2bf(tile[tx][r + ty]);
}

// ---------- block LayerNorm stats helper (256 threads, C=2048) ----------
DEV void block_ln(const float* __restrict__ src, int tid, float* red,
                  float vals[8], float& mean, float& inv) {
  float s = 0.f, ss = 0.f;
  #pragma unroll
  for (int i = 0; i < 8; i++) {
    float t = src[tid + i * 256];
    vals[i] = t; s += t; ss += t * t;
  }
  #pragma unroll
  for (int m = 1; m < 64; m <<= 1) { s += __shfl_xor(s, m); ss += __shfl_xor(ss, m); }
  int lane = tid & 63, wv = tid >> 6;
  __syncthreads();                 // protect red from any previous use
  if (lane == 0) { red[wv] = s; red[4 + wv] = ss; }
  __syncthreads();
  s = red[0] + red[1] + red[2] + red[3];
  ss = red[4] + red[5] + red[6] + red[7];
  mean = s * (1.f / Cc);
  float var = ss * (1.f / Cc) - mean * mean;
  inv = rsqrtf(var + 1e-5f);
}

// ---------- fused LN + 4-way token-shift mix (attention side) ----------
__global__ __launch_bounds__(256)
void ln_mix4(const float* __restrict__ x, const float* __restrict__ shift,
             const float* __restrict__ w, const float* __restrict__ b,
             const float* __restrict__ mk, const float* __restrict__ mv,
             const float* __restrict__ mr, const float* __restrict__ mg,
             u16* __restrict__ xk, u16* __restrict__ xv,
             u16* __restrict__ xr, u16* __restrict__ xg,
             float* __restrict__ last) {
  int row = blockIdx.x;
  int t = row & (Tt - 1), bb = row >> 10;
  int tid = threadIdx.x;
  __shared__ float red[8];
  const float* cur = x + (size_t)row * Cc;
  float cv[8], pv[8], cm, ci, pm = 0.f, pi = 1.f;
  block_ln(cur, tid, red, cv, cm, ci);
  bool t0 = (t == 0);                    // block-uniform
  const float* prev = t0 ? (shift + (size_t)bb * Cc) : (cur - Cc);
  if (!t0) {
    block_ln(prev, tid, red, pv, pm, pi);
  } else {
    #pragma unroll
    for (int i = 0; i < 8; i++) pv[i] = prev[tid + i * 256];
  }
  size_t o = (size_t)row * Cc;
  bool isLast = (t == Tt - 1);
  #pragma unroll
  for (int i = 0; i < 8; i++) {
    int c = tid + i * 256;
    float xc = (cv[i] - cm) * ci * w[c] + b[c];
    float xp = t0 ? pv[i] : (pv[i] - pm) * pi * w[c] + b[c];
    xk[o + c] = f2bf(xp + mk[c] * (xc - xp));
    xv[o + c] = f2bf(xp + mv[c] * (xc - xp));
    xr[o + c] = f2bf(xp + mr[c] * (xc - xp));
    xg[o + c] = f2bf(xp + mg[c] * (xc - xp));
    if (isLast) last[(size_t)bb * Cc + c] = xc;
  }
}

// ---------- fused LN + 2-way token-shift mix (FFN side) ----------
__global__ __launch_bounds__(256)
void ln_mix2(const float* __restrict__ x, const float* __restrict__ shift,
             const float* __restrict__ w, const float* __restrict__ b,
             const float* __restrict__ ck, const float* __restrict__ cr,
             u16* __restrict__ xck, u16* __restrict__ xcr,
             float* __restrict__ last) {
  int row = blockIdx.x;
  int t = row & (Tt - 1), bb = row >> 10;
  int tid = threadIdx.x;
  __shared__ float red[8];
  const float* cur = x + (size_t)row * Cc;
  float cv[8], pv[8], cm, ci, pm = 0.f, pi = 1.f;
  block_ln(cur, tid, red, cv, cm, ci);
  bool t0 = (t == 0);
  const float* prev = t0 ? (shift + (size_t)bb * Cc) : (cur - Cc);
  if (!t0) {
    block_ln(prev, tid, red, pv, pm, pi);
  } else {
    #pragma unroll
    for (int i = 0; i < 8; i++) pv[i] = prev[tid + i * 256];
  }
  size_t o = (size_t)row * Cc;
  bool isLast = (t == Tt - 1);
  #pragma unroll
  for (int i = 0; i < 8; i++) {
    int c = tid + i * 256;
    float xc = (cv[i] - cm) * ci * w[c] + b[c];
    float xp = t0 ? pv[i] : (pv[i] - pm) * pi * w[c] + b[c];
    xck[o + c] = f2bf(xp + ck[c] * (xc - xp));
    xcr[o + c] = f2bf(xp + cr[c] * (xc - xp));
    if (isLast) last[(size_t)bb * Cc + c] = xc;
  }
}

// ---------- GEMM: C[M][N] = A[M][K](bf16,rm) * Bt[N][K](bf16,rm)^T ----------
// 128x128 tile, BK=32, 4 waves (2x2), each wave 4x4 frags of 16x16x32 MFMA.
// EPI: 0=f32, 1=bf16, 2=silu->bf16, 3=relu^2->bf16, 4=X1+val->f32,
//      5=X1+sigmoid(val)*X2->f32
template <int EPI>
__global__ __launch_bounds__(256)
void gemm_bt(const u16* __restrict__ A, const u16* __restrict__ Bt,
             int M, int N, int K,
             float* __restrict__ Co, u16* __restrict__ Cb,
             const float* __restrict__ X1, const float* __restrict__ X2) {
  __shared__ u16 As[128 * 32];
  __shared__ u16 Bs[128 * 32];
  const int tid = threadIdx.x;
  const int m0 = blockIdx.y * 128, n0 = blockIdx.x * 128;
  const int wave = tid >> 6, lane = tid & 63;
  const int wm = (wave >> 1) * 64, wn = (wave & 1) * 64;
  const int lrow = lane & 15, kg = lane >> 4;
  const int srow = tid >> 2, skoff = (tid & 3) * 8;

  const u16* Ab = A + (size_t)(m0 + srow) * K + skoff;
  const u16* Bbp = Bt + (size_t)(n0 + srow) * K + skoff;

  f32x4 acc[4][4] = {};

  const u16* Ard = As + (wm + lrow) * 32 + kg * 8;
  const u16* Brd = Bs + (wn + lrow) * 32 + kg * 8;

  for (int kt = 0; kt < K; kt += 32) {
    __syncthreads();
    gll16(Ab + kt, As + tid * 8);
    gll16(Ab + kt + (size_t)64 * K, As + tid * 8 + 2048);
    gll16(Bbp + kt, Bs + tid * 8);
    gll16(Bbp + kt + (size_t)64 * K, Bs + tid * 8 + 2048);
    __syncthreads();
    bf16x8 af[4], bfr[4];
    #pragma unroll
    for (int mi = 0; mi < 4; mi++) af[mi] = *(const bf16x8*)(Ard + mi * 512);
    #pragma unroll
    for (int ni = 0; ni < 4; ni++) bfr[ni] = *(const bf16x8*)(Brd + ni * 512);
    #pragma unroll
    for (int mi = 0; mi < 4; mi++)
      #pragma unroll
      for (int ni = 0; ni < 4; ni++)
        acc[mi][ni] = __builtin_amdgcn_mfma_f32_16x16x32_bf16(af[mi], bfr[ni], acc[mi][ni], 0, 0, 0);
  }

  #pragma unroll
  for (int mi = 0; mi < 4; mi++) {
    #pragma unroll
    for (int jj = 0; jj < 4; jj++) {
      const int gr = m0 + wm + mi * 16 + kg * 4 + jj;
      const size_t ro = (size_t)gr * N;
      #pragma unroll
      for (int ni = 0; ni < 4; ni++) {
        const int gc = n0 + wn + ni * 16 + lrow;
        float val = acc[mi][ni][jj];
        if constexpr (EPI == 0) {
          Co[ro + gc] = val;
        } else if constexpr (EPI == 1) {
          Cb[ro + gc] = f2bf(val);
        } else if constexpr (EPI == 2) {
          float s = 1.f / (1.f + __expf(-val));
          Cb[ro + gc] = f2bf(val * s);
        } else if constexpr (EPI == 3) {
          float t = fmaxf(val, 0.f);
          Cb[ro + gc] = f2bf(t * t);
        } else if constexpr (EPI == 4) {
          Co[ro + gc] = X1[ro + gc] + val;
        } else {
          float s = 1.f / (1.f + __expf(-val));
          Co[ro + gc] = fmaf(s, X2[ro + gc], X1[ro + gc]);
        }
      }
    }
  }
}

// ---------- WKV scan: 1 block per (b,h); 4 waves split i; lane = j ----------
__global__ __launch_bounds__(256)
void wkv_scan_kernel(const u16* __restrict__ r, const u16* __restrict__ k,
                     const u16* __restrict__ v, const float* __restrict__ s0,
                     const float* __restrict__ td, const float* __restrict__ tf,
                     float* __restrict__ att, float* __restrict__ sout) {
  int bh = blockIdx.x;
  int b = bh >> 5, h = bh & 31;
  int lane = threadIdx.x & 63, ww = threadIdx.x >> 6;
  int i0 = ww * 16;
  int q = lane & 15;
  float wq = __expf(-__expf(td[h * 64 + i0 + q]));
  float uq = tf[h * 64 + i0 + q];
  float wi_[16], ui_[16];
  #pragma unroll
  for (int il = 0; il < 16; il++) { wi_[il] = rlane(wq, il); ui_[il] = rlane(uq, il); }

  float s[16];
  size_t sbase = ((size_t)(b * 32 + h) * 64 + i0) * 64 + lane;
  #pragma unroll
  for (int il = 0; il < 16; il++) s[il] = s0[sbase + (size_t)il * 64];

  __shared__ float yp[2][4][64];
  size_t idx = (size_t)(b * Tt) * Cc + (size_t)h * 64; // [B,T,H,N] flat, t=0
  for (int t = 0; t < Tt; t++) {
    float rv = bf2f(r[idx + i0 + q]);
    float kv = bf2f(k[idx + i0 + q]);
    float vj = bf2f(v[idx + lane]);
    float y = 0.f;
    #pragma unroll
    for (int il = 0; il < 16; il++) {
      float ri = rlane(rv, il);
      float ki = rlane(kv, il);
      float kvv = ki * vj;
      y = fmaf(ri, fmaf(ui_[il], kvv, s[il]), y);
      s[il] = fmaf(s[il], wi_[il], kvv);
    }
    yp[t & 1][ww][lane] = y;
    __syncthreads();
    if (ww == 0)
      att[idx + lane] = yp[t & 1][0][lane] + yp[t & 1][1][lane] +
                        yp[t & 1][2][lane] + yp[t & 1][3][lane];
    idx += Cc;
  }
  #pragma unroll
  for (int il = 0; il < 16; il++) sout[sbase + (size_t)il * 64] = s[il];
}

// ---------- GroupNorm(att/8) * g -> bf16 ----------
__global__ void gn_mul_kernel(const float* __restrict__ att, const u16* __restrict__ g,
                              const float* __restrict__ gw, const float* __restrict__ gb,
                              u16* __restrict__ xo) {
  int row = blockIdx.x;
  int lane = threadIdx.x & 63, ww = threadIdx.x >> 6;
  size_t base = (size_t)row * Cc;
  #pragma unroll
  for (int hh = 0; hh < 8; hh++) {
    int c = (ww * 8 + hh) * 64 + lane;
    float z = att[base + c] * 0.125f;
    float s = z, ss = z * z;
    #pragma unroll
    for (int m = 1; m < 64; m <<= 1) { s += __shfl_xor(s, m); ss += __shfl_xor(ss, m); }
    float mean = s * (1.f / 64.f);
    float var = ss * (1.f / 64.f) - mean * mean;
    float zn = (z - mean) * rsqrtf(var + 1e-5f) * gw[c] + gb[c];
    xo[base + c] = f2bf(zn * bf2f(g[base + c]));
  }
}

// ---------- orchestration ----------
extern "C" void kernel_launch(void* const* d_in, const int* in_sizes, int n_in,
                              void* d_out, int out_size, void* d_ws, size_t ws_size,
                              hipStream_t stream) {
  const float* x         = (const float*)d_in[0];
  const float* att_shift = (const float*)d_in[1];
  const float* wkv0      = (const float*)d_in[2];
  const float* ffn_shift = (const float*)d_in[3];
  const float* ln1w = (const float*)d_in[4];
  const float* ln1b = (const float*)d_in[5];
  const float* ln2w = (const float*)d_in[6];
  const float* ln2b = (const float*)d_in[7];
  const float* mixk = (const float*)d_in[8];
  const float* mixv = (const float*)d_in[9];
  const float* mixr = (const float*)d_in[10];
  const float* mixg = (const float*)d_in[11];
  const float* Wr = (const float*)d_in[12];
  const float* Wk = (const float*)d_in[13];
  const float* Wv = (const float*)d_in[14];
  const float* Wg = (const float*)d_in[15];
  const float* Wo = (const float*)d_in[16];
  const float* td = (const float*)d_in[17];
  const float* tf = (const float*)d_in[18];
  const float* gnw = (const float*)d_in[19];
  const float* gnb = (const float*)d_in[20];
  const float* cmk = (const float*)d_in[21];
  const float* cmr = (const float*)d_in[22];
  const float* Wck = (const float*)d_in[23];
  const float* Wcr = (const float*)d_in[24];
  const float* Wcv = (const float*)d_in[25];

  // ---- workspace layout (peak 232 MiB) ----
  constexpr size_t SZ_CC = (size_t)Cc * Cc * 2;       //  8,388,608
  constexpr size_t SZ_CF = (size_t)Cc * FF * 2;       // 29,360,128
  constexpr size_t SZ_AB = (size_t)BT * Cc * 2;       // 16,777,216 (bf16 act)
  constexpr size_t O_W   = 0;
  constexpr size_t O_R1  = 6 * SZ_CC + 2 * SZ_CF;     // 109,051,904
  constexpr size_t R1_SZ = 4 * SZ_AB;                 // 67,108,864
  constexpr size_t O_R2  = O_R1 + R1_SZ;              // 176,160,768
  constexpr size_t R2_SZ = 3 * SZ_AB;                 // 50,331,648
  constexpr size_t O_R3  = O_R2 + R2_SZ;              // 226,492,416
  constexpr size_t WS_NEED = O_R3 + SZ_AB;            // 243,269,632

  if (ws_size < WS_NEED) return;  // signals ws-too-small as clean absmax fail

  char* ws = (char*)d_ws;
  u16* WrT  = (u16*)(ws + O_W);
  u16* WkT  = (u16*)(ws + O_W + 1 * SZ_CC);
  u16* WvT  = (u16*)(ws + O_W + 2 * SZ_CC);
  u16* WgT  = (u16*)(ws + O_W + 3 * SZ_CC);
  u16* WoT  = (u16*)(ws + O_W + 4 * SZ_CC);
  u16* WcrT = (u16*)(ws + O_W + 5 * SZ_CC);
  u16* WckT = (u16*)(ws + O_W + 6 * SZ_CC);
  u16* WcvT = (u16*)(ws + O_W + 6 * SZ_CC + SZ_CF);

  // REG1: xk,xv,xr,xg -> att(f32,32MiB) -> kk(bf16,56MiB)
  u16*   xk  = (u16*)(ws + O_R1);
  u16*   xv  = (u16*)(ws + O_R1 + SZ_AB);
  u16*   xr  = (u16*)(ws + O_R1 + 2 * SZ_AB);
  u16*   xg  = (u16*)(ws + O_R1 + 3 * SZ_AB);
  float* att = (float*)(ws + O_R1);
  u16*   kk  = (u16*)(ws + O_R1);
  // REG2: rb,kb,vb -> xo,xck,xcr -> kv(f32,32MiB)+xcr
  u16*   rb  = (u16*)(ws + O_R2);
  u16*   kb  = (u16*)(ws + O_R2 + SZ_AB);
  u16*   vb  = (u16*)(ws + O_R2 + 2 * SZ_AB);
  u16*   xo  = (u16*)(ws + O_R2);
  u16*   xck = (u16*)(ws + O_R2 + SZ_AB);
  u16*   xcr = (u16*)(ws + O_R2 + 2 * SZ_AB);
  float* kv  = (float*)(ws + O_R2);
  // REG3: gbuf
  u16*   gbuf = (u16*)(ws + O_R3);

  float* out      = (float*)d_out;          // also serves as x_after scratch
  float* x1_last  = out + (size_t)BT * Cc;
  float* wkv_out  = x1_last + (size_t)Bb * Cc;
  float* x2_last  = wkv_out + (size_t)Bb * Hh * Nd * Nd;

  // 1) weight transposes (f32 -> bf16^T)
  transpose_to_bf16<<<dim3(64, 64), 256, 0, stream>>>(Wr, WrT, Cc, Cc);
  transpose_to_bf16<<<dim3(64, 64), 256, 0, stream>>>(Wk, WkT, Cc, Cc);
  transpose_to_bf16<<<dim3(64, 64), 256, 0, stream>>>(Wv, WvT, Cc, Cc);
  transpose_to_bf16<<<dim3(64, 64), 256, 0, stream>>>(Wg, WgT, Cc, Cc);
  transpose_to_bf16<<<dim3(64, 64), 256, 0, stream>>>(Wo, WoT, Cc, Cc);
  transpose_to_bf16<<<dim3(64, 64), 256, 0, stream>>>(Wcr, WcrT, Cc, Cc);
  transpose_to_bf16<<<dim3(224, 64), 256, 0, stream>>>(Wck, WckT, Cc, FF);
  transpose_to_bf16<<<dim3(64, 224), 256, 0, stream>>>(Wcv, WcvT, FF, Cc);

  // 2) fused ln1 + mix4 -> xk,xv,xr,xg ; x1_last
  ln_mix4<<<BT, 256, 0, stream>>>(x, att_shift, ln1w, ln1b,
                                  mixk, mixv, mixr, mixg, xk, xv, xr, xg, x1_last);
  // 3) projections
  gemm_bt<1><<<dim3(16, 32), 256, 0, stream>>>(xr, WrT, BT, Cc, Cc, nullptr, rb, nullptr, nullptr);
  gemm_bt<1><<<dim3(16, 32), 256, 0, stream>>>(xk, WkT, BT, Cc, Cc, nullptr, kb, nullptr, nullptr);
  gemm_bt<1><<<dim3(16, 32), 256, 0, stream>>>(xv, WvT, BT, Cc, Cc, nullptr, vb, nullptr, nullptr);
  gemm_bt<2><<<dim3(16, 32), 256, 0, stream>>>(xg, WgT, BT, Cc, Cc, nullptr, gbuf, nullptr, nullptr);
  // 4) WKV scan -> att ; new_wkv
  wkv_scan_kernel<<<Bb * Hh, 256, 0, stream>>>(rb, kb, vb, wkv0, td, tf, att, wkv_out);
  // 5) groupnorm * g -> xo
  gn_mul_kernel<<<BT, 256, 0, stream>>>(att, gbuf, gnw, gnb, xo);
  // 6) x_after (in out) = x + xo @ Wo
  gemm_bt<4><<<dim3(16, 32), 256, 0, stream>>>(xo, WoT, BT, Cc, Cc, out, nullptr, x, nullptr);
  // 7) fused ln2 + mix2 -> xck,xcr ; x2_last
  ln_mix2<<<BT, 256, 0, stream>>>(out, ffn_shift, ln2w, ln2b, cmk, cmr, xck, xcr, x2_last);
  // 8) kk = relu(xck @ Wck)^2
  gemm_bt<3><<<dim3(56, 32), 256, 0, stream>>>(xck, WckT, BT, FF, Cc, nullptr, kk, nullptr, nullptr);
  // 9) kv = kk @ Wcv  (overwrites xo+xck, both dead)
  gemm_bt<0><<<dim3(16, 32), 256, 0, stream>>>(kk, WcvT, BT, Cc, FF, kv, nullptr, nullptr, nullptr);
  // 10) out = x_after + sigmoid(xcr @ Wcr) * kv   (in-place per-element on out)
  gemm_bt<5><<<dim3(16, 32), 256, 0, stream>>>(xcr, WcrT, BT, Cc, Cc, out, nullptr, out, kv);

  (void)in_sizes; (void)n_in; (void)out_size;
}

// Round 3
// 1101.107 us; speedup vs baseline: 1.2905x; 1.2905x over previous
//
#include <hip/hip_runtime.h>
#include <cstdint>
#include <cstddef>

typedef unsigned short u16;
typedef unsigned int u32;
typedef short bf16x8 __attribute__((ext_vector_type(8)));
typedef unsigned short u16x4 __attribute__((ext_vector_type(4)));
typedef unsigned short u16x8 __attribute__((ext_vector_type(8)));
typedef float f32x4 __attribute__((ext_vector_type(4)));

#define DEV __device__ __forceinline__

// ---------- constants ----------
constexpr int Bb = 4, Tt = 1024, Cc = 2048, Hh = 32, Nd = 64, FF = 7168;
constexpr int BT = Bb * Tt; // 4096
constexpr int CH = 64;      // wkv chunk length
constexpr int NCH = Tt / CH;

// ---------- helpers ----------
DEV u16 f2bf(float f) {
  union { float f; unsigned u; } un; un.f = f;
  unsigned r = un.u + 0x7FFFu + ((un.u >> 16) & 1u);
  return (u16)(r >> 16);
}
DEV float bf2f(u16 h) {
  union { unsigned u; float f; } un; un.u = ((unsigned)h) << 16;
  return un.f;
}
// global -> LDS direct, 16B per lane.
DEV void gll16(const u16* gp, u16* lp) {
  __builtin_amdgcn_global_load_lds(
      (const __attribute__((address_space(1))) unsigned int*)gp,
      (__attribute__((address_space(3))) unsigned int*)lp,
      16, 0, 0);
}

// ---------- transpose + f32->bf16: W[Kk][Nn] -> Wt[Nn][Kk] ----------
__global__ void transpose_to_bf16(const float* __restrict__ W, u16* __restrict__ Wt,
                                  int Kk, int Nn) {
  __shared__ float tile[32][33];
  int n0 = blockIdx.x * 32, k0 = blockIdx.y * 32;
  int tx = threadIdx.x & 31, ty = threadIdx.x >> 5; // 32 x 8
  #pragma unroll
  for (int r = 0; r < 32; r += 8)
    tile[r + ty][tx] = W[(size_t)(k0 + r + ty) * Nn + n0 + tx];
  __syncthreads();
  #pragma unroll
  for (int r = 0; r < 32; r += 8)
    Wt[(size_t)(n0 + r + ty) * Kk + k0 + tx] = f2bf(tile[tx][r + ty]);
}

// ---------- block LayerNorm stats helper (256 threads, C=2048) ----------
DEV void block_ln(const float* __restrict__ src, int tid, float* red,
                  float vals[8], float& mean, float& inv) {
  float s = 0.f, ss = 0.f;
  #pragma unroll
  for (int i = 0; i < 8; i++) {
    float t = src[tid + i * 256];
    vals[i] = t; s += t; ss += t * t;
  }
  #pragma unroll
  for (int m = 1; m < 64; m <<= 1) { s += __shfl_xor(s, m); ss += __shfl_xor(ss, m); }
  int lane = tid & 63, wv = tid >> 6;
  __syncthreads();
  if (lane == 0) { red[wv] = s; red[4 + wv] = ss; }
  __syncthreads();
  s = red[0] + red[1] + red[2] + red[3];
  ss = red[4] + red[5] + red[6] + red[7];
  mean = s * (1.f / Cc);
  float var = ss * (1.f / Cc) - mean * mean;
  inv = rsqrtf(var + 1e-5f);
}

// ---------- fused LN + 4-way token-shift mix (attention side) ----------
__global__ __launch_bounds__(256)
void ln_mix4(const float* __restrict__ x, const float* __restrict__ shift,
             const float* __restrict__ w, const float* __restrict__ b,
             const float* __restrict__ mk, const float* __restrict__ mv,
             const float* __restrict__ mr, const float* __restrict__ mg,
             u16* __restrict__ xk, u16* __restrict__ xv,
             u16* __restrict__ xr, u16* __restrict__ xg,
             float* __restrict__ last) {
  int row = blockIdx.x;
  int t = row & (Tt - 1), bb = row >> 10;
  int tid = threadIdx.x;
  __shared__ float red[8];
  const float* cur = x + (size_t)row * Cc;
  float cv[8], pv[8], cm, ci, pm = 0.f, pi = 1.f;
  block_ln(cur, tid, red, cv, cm, ci);
  bool t0 = (t == 0);
  const float* prev = t0 ? (shift + (size_t)bb * Cc) : (cur - Cc);
  if (!t0) {
    block_ln(prev, tid, red, pv, pm, pi);
  } else {
    #pragma unroll
    for (int i = 0; i < 8; i++) pv[i] = prev[tid + i * 256];
  }
  size_t o = (size_t)row * Cc;
  bool isLast = (t == Tt - 1);
  #pragma unroll
  for (int i = 0; i < 8; i++) {
    int c = tid + i * 256;
    float xc = (cv[i] - cm) * ci * w[c] + b[c];
    float xp = t0 ? pv[i] : (pv[i] - pm) * pi * w[c] + b[c];
    xk[o + c] = f2bf(xp + mk[c] * (xc - xp));
    xv[o + c] = f2bf(xp + mv[c] * (xc - xp));
    xr[o + c] = f2bf(xp + mr[c] * (xc - xp));
    xg[o + c] = f2bf(xp + mg[c] * (xc - xp));
    if (isLast) last[(size_t)bb * Cc + c] = xc;
  }
}

// ---------- fused LN + 2-way token-shift mix (FFN side) ----------
__global__ __launch_bounds__(256)
void ln_mix2(const float* __restrict__ x, const float* __restrict__ shift,
             const float* __restrict__ w, const float* __restrict__ b,
             const float* __restrict__ ck, const float* __restrict__ cr,
             u16* __restrict__ xck, u16* __restrict__ xcr,
             float* __restrict__ last) {
  int row = blockIdx.x;
  int t = row & (Tt - 1), bb = row >> 10;
  int tid = threadIdx.x;
  __shared__ float red[8];
  const float* cur = x + (size_t)row * Cc;
  float cv[8], pv[8], cm, ci, pm = 0.f, pi = 1.f;
  block_ln(cur, tid, red, cv, cm, ci);
  bool t0 = (t == 0);
  const float* prev = t0 ? (shift + (size_t)bb * Cc) : (cur - Cc);
  if (!t0) {
    block_ln(prev, tid, red, pv, pm, pi);
  } else {
    #pragma unroll
    for (int i = 0; i < 8; i++) pv[i] = prev[tid + i * 256];
  }
  size_t o = (size_t)row * Cc;
  bool isLast = (t == Tt - 1);
  #pragma unroll
  for (int i = 0; i < 8; i++) {
    int c = tid + i * 256;
    float xc = (cv[i] - cm) * ci * w[c] + b[c];
    float xp = t0 ? pv[i] : (pv[i] - pm) * pi * w[c] + b[c];
    xck[o + c] = f2bf(xp + ck[c] * (xc - xp));
    xcr[o + c] = f2bf(xp + cr[c] * (xc - xp));
    if (isLast) last[(size_t)bb * Cc + c] = xc;
  }
}

// ---------- GEMM: C[M][N] = A[M][K](bf16,rm) * Bt[N][K](bf16,rm)^T ----------
template <int EPI>
__global__ __launch_bounds__(256)
void gemm_bt(const u16* __restrict__ A, const u16* __restrict__ Bt,
             int M, int N, int K,
             float* __restrict__ Co, u16* __restrict__ Cb,
             const float* __restrict__ X1, const float* __restrict__ X2) {
  __shared__ u16 As[128 * 32];
  __shared__ u16 Bs[128 * 32];
  const int tid = threadIdx.x;
  const int m0 = blockIdx.y * 128, n0 = blockIdx.x * 128;
  const int wave = tid >> 6, lane = tid & 63;
  const int wm = (wave >> 1) * 64, wn = (wave & 1) * 64;
  const int lrow = lane & 15, kg = lane >> 4;
  const int srow = tid >> 2, skoff = (tid & 3) * 8;

  const u16* Ab = A + (size_t)(m0 + srow) * K + skoff;
  const u16* Bbp = Bt + (size_t)(n0 + srow) * K + skoff;

  f32x4 acc[4][4] = {};

  const u16* Ard = As + (wm + lrow) * 32 + kg * 8;
  const u16* Brd = Bs + (wn + lrow) * 32 + kg * 8;

  for (int kt = 0; kt < K; kt += 32) {
    __syncthreads();
    gll16(Ab + kt, As + tid * 8);
    gll16(Ab + kt + (size_t)64 * K, As + tid * 8 + 2048);
    gll16(Bbp + kt, Bs + tid * 8);
    gll16(Bbp + kt + (size_t)64 * K, Bs + tid * 8 + 2048);
    __syncthreads();
    bf16x8 af[4], bfr[4];
    #pragma unroll
    for (int mi = 0; mi < 4; mi++) af[mi] = *(const bf16x8*)(Ard + mi * 512);
    #pragma unroll
    for (int ni = 0; ni < 4; ni++) bfr[ni] = *(const bf16x8*)(Brd + ni * 512);
    #pragma unroll
    for (int mi = 0; mi < 4; mi++)
      #pragma unroll
      for (int ni = 0; ni < 4; ni++)
        acc[mi][ni] = __builtin_amdgcn_mfma_f32_16x16x32_bf16(af[mi], bfr[ni], acc[mi][ni], 0, 0, 0);
  }

  #pragma unroll
  for (int mi = 0; mi < 4; mi++) {
    #pragma unroll
    for (int jj = 0; jj < 4; jj++) {
      const int gr = m0 + wm + mi * 16 + kg * 4 + jj;
      const size_t ro = (size_t)gr * N;
      #pragma unroll
      for (int ni = 0; ni < 4; ni++) {
        const int gc = n0 + wn + ni * 16 + lrow;
        float val = acc[mi][ni][jj];
        if constexpr (EPI == 0) {
          Co[ro + gc] = val;
        } else if constexpr (EPI == 1) {
          Cb[ro + gc] = f2bf(val);
        } else if constexpr (EPI == 2) {
          float s = 1.f / (1.f + __expf(-val));
          Cb[ro + gc] = f2bf(val * s);
        } else if constexpr (EPI == 3) {
          float t = fmaxf(val, 0.f);
          Cb[ro + gc] = f2bf(t * t);
        } else if constexpr (EPI == 4) {
          Co[ro + gc] = X1[ro + gc] + val;
        } else {
          float s = 1.f / (1.f + __expf(-val));
          Co[ro + gc] = fmaf(s, X2[ro + gc], X1[ro + gc]);
        }
      }
    }
  }
}

// ---------- chunked WKV ----------
// Block = (bh, jhalf): 256 blocks, 256 threads. State S[64][32] f32 in LDS.
// Per chunk c (len 64):
//   Y[tau,j] = sum_i R~[tau,i]*S[i,j] + sum_{s<=tau} A[tau,s]*v[s,j]
//   A[tau,s] = sum_i r k w^(tau-1-s)  (s<tau);  A[tau,tau] = sum_i r u k
//   S <- w^64 * S + sum_s (k w^(63-s)) (x) v
constexpr int ROWB = 144;  // LDS row bytes: 128B content + 16B pad (16B-aligned)
DEV char* ldsp(void* base, int row, int bc) {
  return (char*)base + row * ROWB + (bc ^ ((row & 7) << 4));
}

__global__ __launch_bounds__(256)
void wkv_chunk_kernel(const u16* __restrict__ rg, const u16* __restrict__ kg,
                      const u16* __restrict__ vg, const float* __restrict__ s0g,
                      const float* __restrict__ td, const float* __restrict__ tf,
                      float* __restrict__ att, float* __restrict__ sout) {
  __shared__ float Pt[65][68];   // P[e][i] = w_i^e
  __shared__ float Sl[64][33];   // S[i][jloc]
  __shared__ u16 rB[64 * 72];    // raw r[tau][i] -> R~ in place
  __shared__ u16 kB[64 * 72];    // raw k[s][i]  -> K^T[i][s] in place
  __shared__ u16 aB[64 * 72];    // A[tau][s] bf16
  __shared__ u16 vB[32 * 72];    // vT[jloc][s]
  __shared__ u16 sB[32 * 72];    // ST[jloc][i] bf16
  __shared__ float uL[64];

  const int tid = threadIdx.x;
  const int bid = blockIdx.x;
  const int bh = bid >> 1, jh = bid & 1;
  const int b = bh >> 5, h = bh & 31;
  const int lane = tid & 63, w = tid >> 6;
  const int m16 = lane & 15, kgq = lane >> 4;
  const size_t tbase = (size_t)b * Tt;       // token-row base
  const int col0 = h * 64 + jh * 32;         // j-half column base in C

  // ---- prologue: P table, u, S init ----
  {
    int i = tid & 63;
    float d = __expf(td[h * 64 + i]);
    float c1 = -1.4426950408889634f * d;
    for (int e = (tid >> 6); e <= 64; e += 4)
      Pt[e][i] = exp2f(c1 * (float)e);
    if (tid < 64) uL[tid] = tf[h * 64 + tid];
    #pragma unroll
    for (int n = 0; n < 8; n++) {
      int e = tid + 256 * n;
      int i2 = e >> 5, j2 = e & 31;
      Sl[i2][j2] = s0g[((size_t)bh * 64 + i2) * 64 + jh * 32 + j2];
    }
  }

  // ---- per-thread constant task decode (A tiles, lower-incl-diag 16x16 grid) ----
  int tr = 0, tc = 0, Bofs = 0, isDiag = 0, hasTask = (tid < 136);
  int ztr = 0, ztc = 0;
  if (hasTask) {
    int task = tid;
    tr = (int)((sqrtf(8.f * task + 1.f) - 1.f) * 0.5f);
    while ((tr + 1) * (tr + 2) / 2 <= task) tr++;
    while (tr * (tr + 1) / 2 > task) tr--;
    tc = task - tr * (tr + 1) / 2;
    Bofs = tr * 4 - 1 - tc * 4;
    isDiag = (tr == tc);
  } else {
    int u = tid - 136;  // 0..119 strict-lower decode, then transpose -> upper tile
    int rr = (int)((1.f + sqrtf(8.f * u + 1.f)) * 0.5f);
    while (rr * (rr - 1) / 2 > u) rr--;
    while ((rr + 1) * rr / 2 <= u) rr++;
    int cc2 = u - rr * (rr - 1) / 2;
    ztr = cc2; ztc = rr;   // upper tile (rows ztr*4, cols ztc*4)
  }

  __syncthreads();

  for (int c = 0; c < NCH; c++) {
    // ===== phase 1: global loads (issue early), ST build, LDS writes =====
    const int sr = tid >> 2, q = tid & 3;
    size_t gro = (tbase + c * 64 + sr) * (size_t)Cc + h * 64 + q * 16;
    u16x8 rv0 = *(const u16x8*)(rg + gro);
    u16x8 rv1 = *(const u16x8*)(rg + gro + 8);
    u16x8 kv0 = *(const u16x8*)(kg + gro);
    u16x8 kv1 = *(const u16x8*)(kg + gro + 8);
    const int s2 = tid & 31, jq = tid >> 5;
    size_t gvo = (tbase + c * 64 + 2 * s2) * (size_t)Cc + col0 + jq * 4;
    u16x4 vr0 = *(const u16x4*)(vg + gvo);
    u16x4 vr1 = *(const u16x4*)(vg + gvo + Cc);

    // ST build from Sl (bf16, transposed, i-pair packed)
    {
      const int i2 = tid & 31, jq2 = tid >> 5;
      #pragma unroll
      for (int dj = 0; dj < 4; dj++) {
        int j = jq2 * 4 + dj;
        float f0 = Sl[2 * i2][j], f1 = Sl[2 * i2 + 1][j];
        u32 pk = ((u32)f2bf(f1) << 16) | f2bf(f0);
        *(u32*)ldsp(sB, j, i2 * 4) = pk;
      }
    }
    // write r,k rows (swizzled)
    *(u16x8*)ldsp(rB, sr, q * 32)      = rv0;
    *(u16x8*)ldsp(rB, sr, q * 32 + 16) = rv1;
    *(u16x8*)ldsp(kB, sr, q * 32)      = kv0;
    *(u16x8*)ldsp(kB, sr, q * 32 + 16) = kv1;
    // write vT (s-pair packed)
    #pragma unroll
    for (int dj = 0; dj < 4; dj++) {
      u32 pk = ((u32)vr1[dj] << 16) | vr0[dj];
      *(u32*)ldsp(vB, jq * 4 + dj, s2 * 4) = pk;
    }
    __syncthreads();

    // ===== phase 2: A-direct (register-tiled 4x4) =====
    if (hasTask) {
      float a[4][4] = {};
      const int t0 = tr * 4, s0 = tc * 4;
      for (int i4 = 0; i4 < 16; i4++) {
        const int i0 = i4 * 4;
        float rf[4][4], kf[4][4];
        #pragma unroll
        for (int dt = 0; dt < 4; dt++) {
          u16x4 rv = *(const u16x4*)ldsp(rB, t0 + dt, i0 * 2);
          #pragma unroll
          for (int di = 0; di < 4; di++) rf[dt][di] = bf2f(rv[di]);
        }
        #pragma unroll
        for (int ds = 0; ds < 4; ds++) {
          u16x4 kv = *(const u16x4*)ldsp(kB, s0 + ds, i0 * 2);
          #pragma unroll
          for (int di = 0; di < 4; di++) kf[ds][di] = bf2f(kv[di]);
        }
        if (!isDiag) {
          f32x4 pp[7];
          #pragma unroll
          for (int d = 0; d < 7; d++) pp[d] = *(const f32x4*)&Pt[Bofs - 3 + d][i0];
          #pragma unroll
          for (int dt = 0; dt < 4; dt++)
            #pragma unroll
            for (int ds = 0; ds < 4; ds++) {
              const f32x4 p = pp[dt - ds + 3];
              #pragma unroll
              for (int di = 0; di < 4; di++)
                a[dt][ds] = fmaf(rf[dt][di] * kf[ds][di], p[di], a[dt][ds]);
            }
        } else {
          f32x4 p0 = *(const f32x4*)&Pt[0][i0];
          f32x4 p1 = *(const f32x4*)&Pt[1][i0];
          f32x4 p2 = *(const f32x4*)&Pt[2][i0];
          f32x4 u4 = *(const f32x4*)&uL[i0];
          #pragma unroll
          for (int dt = 0; dt < 4; dt++)
            #pragma unroll
            for (int ds = 0; ds < 4; ds++) {
              if (dt > ds) {
                const f32x4 p = (dt - ds == 1) ? p0 : ((dt - ds == 2) ? p1 : p2);
                #pragma unroll
                for (int di = 0; di < 4; di++)
                  a[dt][ds] = fmaf(rf[dt][di] * kf[ds][di], p[di], a[dt][ds]);
              } else if (dt == ds) {
                #pragma unroll
                for (int di = 0; di < 4; di++)
                  a[dt][ds] = fmaf(rf[dt][di] * kf[ds][di], u4[di], a[dt][ds]);
              }
            }
        }
      }
      // write A tile (bf16, pair-packed), zero strictly-upper pairs in diag tiles
      #pragma unroll
      for (int dt = 0; dt < 4; dt++) {
        float v0 = a[dt][0], v1 = a[dt][1], v2 = a[dt][2], v3 = a[dt][3];
        if (isDiag) {
          if (dt < 1) v1 = 0.f;
          if (dt < 2) v2 = 0.f;
          if (dt < 3) v3 = 0.f;
        }
        u32 lo = ((u32)f2bf(v1) << 16) | f2bf(v0);
        u32 hi = ((u32)f2bf(v3) << 16) | f2bf(v2);
        *(u32*)ldsp(aB, t0 + dt, s0 * 2) = lo;
        *(u32*)ldsp(aB, t0 + dt, s0 * 2 + 4) = hi;
      }
    } else {
      // zero upper tiles
      const int t0 = ztr * 4, s0 = ztc * 4;
      #pragma unroll
      for (int dt = 0; dt < 4; dt++) {
        *(u32*)ldsp(aB, t0 + dt, s0 * 2) = 0u;
        *(u32*)ldsp(aB, t0 + dt, s0 * 2 + 4) = 0u;
      }
    }
    __syncthreads();

    // ===== phase 3a: k-swap reads+compute; R~ in place =====
    u32 kw[4][2];  // packed K^T writes for 2 tiles x 4 rows... (flattened below)
    u32 kw2[4][2];
    if (hasTask) {
      const int Ab2 = tc, Bb2 = tr;  // A<=B
      // tileP: old rows s=A*4.., cols i=B*4..  -> new rows i=B*4.., cols s=A*4..
      float nv[4][4];
      #pragma unroll
      for (int dr = 0; dr < 4; dr++) {
        int s = Ab2 * 4 + dr;
        u16x4 ov = *(const u16x4*)ldsp(kB, s, (Bb2 * 4) * 2);
        f32x4 p = *(const f32x4*)&Pt[63 - s][Bb2 * 4];
        #pragma unroll
        for (int dc = 0; dc < 4; dc++) nv[dc][dr] = bf2f(ov[dc]) * p[dc];
      }
      #pragma unroll
      for (int dc = 0; dc < 4; dc++) {
        kw[dc][0] = ((u32)f2bf(nv[dc][1]) << 16) | f2bf(nv[dc][0]);
        kw[dc][1] = ((u32)f2bf(nv[dc][3]) << 16) | f2bf(nv[dc][2]);
      }
      if (!isDiag) {
        float nv2[4][4];
        #pragma unroll
        for (int dr = 0; dr < 4; dr++) {
          int s = Bb2 * 4 + dr;
          u16x4 ov = *(const u16x4*)ldsp(kB, s, (Ab2 * 4) * 2);
          f32x4 p = *(const f32x4*)&Pt[63 - s][Ab2 * 4];
          #pragma unroll
          for (int dc = 0; dc < 4; dc++) nv2[dc][dr] = bf2f(ov[dc]) * p[dc];
        }
        #pragma unroll
        for (int dc = 0; dc < 4; dc++) {
          kw2[dc][0] = ((u32)f2bf(nv2[dc][1]) << 16) | f2bf(nv2[dc][0]);
          kw2[dc][1] = ((u32)f2bf(nv2[dc][3]) << 16) | f2bf(nv2[dc][2]);
        }
      }
    }
    // R~ in place: r[tau][i] *= P[tau][i]  (own elements only)
    {
      const int tau = tid >> 2, qq = tid & 3;
      u16x8 r0 = *(const u16x8*)ldsp(rB, tau, qq * 32);
      u16x8 r1 = *(const u16x8*)ldsp(rB, tau, qq * 32 + 16);
      u16x8 o0, o1;
      #pragma unroll
      for (int e = 0; e < 8; e++) {
        o0[e] = (short)f2bf(bf2f((u16)r0[e]) * Pt[tau][qq * 16 + e]);
        o1[e] = (short)f2bf(bf2f((u16)r1[e]) * Pt[tau][qq * 16 + 8 + e]);
      }
      __syncthreads();  // all k-swap reads + R~ reads done
      *(u16x8*)ldsp(rB, tau, qq * 32) = o0;
      *(u16x8*)ldsp(rB, tau, qq * 32 + 16) = o1;
    }
    // ===== phase 3b: K^T writes =====
    if (hasTask) {
      const int Ab2 = tc, Bb2 = tr;
      #pragma unroll
      for (int dc = 0; dc < 4; dc++) {
        *(u32*)ldsp(kB, Bb2 * 4 + dc, (Ab2 * 4) * 2) = kw[dc][0];
        *(u32*)ldsp(kB, Bb2 * 4 + dc, (Ab2 * 4) * 2 + 4) = kw[dc][1];
      }
      if (!isDiag) {
        #pragma unroll
        for (int dc = 0; dc < 4; dc++) {
          *(u32*)ldsp(kB, Ab2 * 4 + dc, (Bb2 * 4) * 2) = kw2[dc][0];
          *(u32*)ldsp(kB, Ab2 * 4 + dc, (Bb2 * 4) * 2 + 4) = kw2[dc][1];
        }
      }
    }
    __syncthreads();

    // ===== phase 4: MFMAs =====
    f32x4 yacc[2] = {};
    #pragma unroll
    for (int kf = 0; kf < 2; kf++) {
      bf16x8 aA = *(const bf16x8*)ldsp(aB, w * 16 + m16, kf * 64 + kgq * 16);
      bf16x8 aR = *(const bf16x8*)ldsp(rB, w * 16 + m16, kf * 64 + kgq * 16);
      #pragma unroll
      for (int nf = 0; nf < 2; nf++) {
        bf16x8 bV = *(const bf16x8*)ldsp(vB, nf * 16 + m16, kf * 64 + kgq * 16);
        bf16x8 bS = *(const bf16x8*)ldsp(sB, nf * 16 + m16, kf * 64 + kgq * 16);
        yacc[nf] = __builtin_amdgcn_mfma_f32_16x16x32_bf16(aA, bV, yacc[nf], 0, 0, 0);
        yacc[nf] = __builtin_amdgcn_mfma_f32_16x16x32_bf16(aR, bS, yacc[nf], 0, 0, 0);
      }
    }
    #pragma unroll
    for (int nf = 0; nf < 2; nf++) {
      #pragma unroll
      for (int reg = 0; reg < 4; reg++) {
        int tau = w * 16 + kgq * 4 + reg;
        int j = nf * 16 + m16;
        att[(tbase + c * 64 + tau) * (size_t)Cc + col0 + j] = yacc[nf][reg];
      }
    }
    // dS = vT(j,s) x K^T(i,s):  D[j][i]
    f32x4 dacc[2] = {};
    const int jf = w >> 1, ifb = (w & 1) * 2;
    #pragma unroll
    for (int kf = 0; kf < 2; kf++) {
      bf16x8 aV = *(const bf16x8*)ldsp(vB, jf * 16 + m16, kf * 64 + kgq * 16);
      #pragma unroll
      for (int f = 0; f < 2; f++) {
        bf16x8 bK = *(const bf16x8*)ldsp(kB, (ifb + f) * 16 + m16, kf * 64 + kgq * 16);
        dacc[f] = __builtin_amdgcn_mfma_f32_16x16x32_bf16(aV, bK, dacc[f], 0, 0, 0);
      }
    }
    // ===== phase 5: S update =====
    #pragma unroll
    for (int f = 0; f < 2; f++) {
      int ii = (ifb + f) * 16 + m16;
      float w64 = Pt[64][ii];
      #pragma unroll
      for (int reg = 0; reg < 4; reg++) {
        int jj = jf * 16 + kgq * 4 + reg;
        Sl[ii][jj] = w64 * Sl[ii][jj] + dacc[f][reg];
      }
    }
    __syncthreads();
  }

  // ---- epilogue: write final state ----
  #pragma unroll
  for (int n = 0; n < 8; n++) {
    int e = tid + 256 * n;
    int i2 = e >> 5, j2 = e & 31;
    sout[((size_t)bh * 64 + i2) * 64 + jh * 32 + j2] = Sl[i2][j2];
  }
}

// ---------- GroupNorm(att/8) * g -> bf16 ----------
__global__ void gn_mul_kernel(const float* __restrict__ att, const u16* __restrict__ g,
                              const float* __restrict__ gw, const float* __restrict__ gb,
                              u16* __restrict__ xo) {
  int row = blockIdx.x;
  int lane = threadIdx.x & 63, ww = threadIdx.x >> 6;
  size_t base = (size_t)row * Cc;
  #pragma unroll
  for (int hh = 0; hh < 8; hh++) {
    int c = (ww * 8 + hh) * 64 + lane;
    float z = att[base + c] * 0.125f;
    float s = z, ss = z * z;
    #pragma unroll
    for (int m = 1; m < 64; m <<= 1) { s += __shfl_xor(s, m); ss += __shfl_xor(ss, m); }
    float mean = s * (1.f / 64.f);
    float var = ss * (1.f / 64.f) - mean * mean;
    float zn = (z - mean) * rsqrtf(var + 1e-5f) * gw[c] + gb[c];
    xo[base + c] = f2bf(zn * bf2f(g[base + c]));
  }
}

// ---------- orchestration ----------
extern "C" void kernel_launch(void* const* d_in, const int* in_sizes, int n_in,
                              void* d_out, int out_size, void* d_ws, size_t ws_size,
                              hipStream_t stream) {
  const float* x         = (const float*)d_in[0];
  const float* att_shift = (const float*)d_in[1];
  const float* wkv0      = (const float*)d_in[2];
  const float* ffn_shift = (const float*)d_in[3];
  const float* ln1w = (const float*)d_in[4];
  const float* ln1b = (const float*)d_in[5];
  const float* ln2w = (const float*)d_in[6];
  const float* ln2b = (const float*)d_in[7];
  const float* mixk = (const float*)d_in[8];
  const float* mixv = (const float*)d_in[9];
  const float* mixr = (const float*)d_in[10];
  const float* mixg = (const float*)d_in[11];
  const float* Wr = (const float*)d_in[12];
  const float* Wk = (const float*)d_in[13];
  const float* Wv = (const float*)d_in[14];
  const float* Wg = (const float*)d_in[15];
  const float* Wo = (const float*)d_in[16];
  const float* td = (const float*)d_in[17];
  const float* tf = (const float*)d_in[18];
  const float* gnw = (const float*)d_in[19];
  const float* gnb = (const float*)d_in[20];
  const float* cmk = (const float*)d_in[21];
  const float* cmr = (const float*)d_in[22];
  const float* Wck = (const float*)d_in[23];
  const float* Wcr = (const float*)d_in[24];
  const float* Wcv = (const float*)d_in[25];

  // ---- workspace layout (peak 232 MiB) ----
  constexpr size_t SZ_CC = (size_t)Cc * Cc * 2;
  constexpr size_t SZ_CF = (size_t)Cc * FF * 2;
  constexpr size_t SZ_AB = (size_t)BT * Cc * 2;
  constexpr size_t O_W   = 0;
  constexpr size_t O_R1  = 6 * SZ_CC + 2 * SZ_CF;
  constexpr size_t R1_SZ = 4 * SZ_AB;
  constexpr size_t O_R2  = O_R1 + R1_SZ;
  constexpr size_t R2_SZ = 3 * SZ_AB;
  constexpr size_t O_R3  = O_R2 + R2_SZ;
  constexpr size_t WS_NEED = O_R3 + SZ_AB;

  if (ws_size < WS_NEED) return;

  char* ws = (char*)d_ws;
  u16* WrT  = (u16*)(ws + O_W);
  u16* WkT  = (u16*)(ws + O_W + 1 * SZ_CC);
  u16* WvT  = (u16*)(ws + O_W + 2 * SZ_CC);
  u16* WgT  = (u16*)(ws + O_W + 3 * SZ_CC);
  u16* WoT  = (u16*)(ws + O_W + 4 * SZ_CC);
  u16* WcrT = (u16*)(ws + O_W + 5 * SZ_CC);
  u16* WckT = (u16*)(ws + O_W + 6 * SZ_CC);
  u16* WcvT = (u16*)(ws + O_W + 6 * SZ_CC + SZ_CF);

  u16*   xk  = (u16*)(ws + O_R1);
  u16*   xv  = (u16*)(ws + O_R1 + SZ_AB);
  u16*   xr  = (u16*)(ws + O_R1 + 2 * SZ_AB);
  u16*   xg  = (u16*)(ws + O_R1 + 3 * SZ_AB);
  float* att = (float*)(ws + O_R1);
  u16*   kk  = (u16*)(ws + O_R1);
  u16*   rb  = (u16*)(ws + O_R2);
  u16*   kb  = (u16*)(ws + O_R2 + SZ_AB);
  u16*   vb  = (u16*)(ws + O_R2 + 2 * SZ_AB);
  u16*   xo  = (u16*)(ws + O_R2);
  u16*   xck = (u16*)(ws + O_R2 + SZ_AB);
  u16*   xcr = (u16*)(ws + O_R2 + 2 * SZ_AB);
  float* kv  = (float*)(ws + O_R2);
  u16*   gbuf = (u16*)(ws + O_R3);

  float* out      = (float*)d_out;
  float* x1_last  = out + (size_t)BT * Cc;
  float* wkv_out  = x1_last + (size_t)Bb * Cc;
  float* x2_last  = wkv_out + (size_t)Bb * Hh * Nd * Nd;

  transpose_to_bf16<<<dim3(64, 64), 256, 0, stream>>>(Wr, WrT, Cc, Cc);
  transpose_to_bf16<<<dim3(64, 64), 256, 0, stream>>>(Wk, WkT, Cc, Cc);
  transpose_to_bf16<<<dim3(64, 64), 256, 0, stream>>>(Wv, WvT, Cc, Cc);
  transpose_to_bf16<<<dim3(64, 64), 256, 0, stream>>>(Wg, WgT, Cc, Cc);
  transpose_to_bf16<<<dim3(64, 64), 256, 0, stream>>>(Wo, WoT, Cc, Cc);
  transpose_to_bf16<<<dim3(64, 64), 256, 0, stream>>>(Wcr, WcrT, Cc, Cc);
  transpose_to_bf16<<<dim3(224, 64), 256, 0, stream>>>(Wck, WckT, Cc, FF);
  transpose_to_bf16<<<dim3(64, 224), 256, 0, stream>>>(Wcv, WcvT, FF, Cc);

  ln_mix4<<<BT, 256, 0, stream>>>(x, att_shift, ln1w, ln1b,
                                  mixk, mixv, mixr, mixg, xk, xv, xr, xg, x1_last);
  gemm_bt<1><<<dim3(16, 32), 256, 0, stream>>>(xr, WrT, BT, Cc, Cc, nullptr, rb, nullptr, nullptr);
  gemm_bt<1><<<dim3(16, 32), 256, 0, stream>>>(xk, WkT, BT, Cc, Cc, nullptr, kb, nullptr, nullptr);
  gemm_bt<1><<<dim3(16, 32), 256, 0, stream>>>(xv, WvT, BT, Cc, Cc, nullptr, vb, nullptr, nullptr);
  gemm_bt<2><<<dim3(16, 32), 256, 0, stream>>>(xg, WgT, BT, Cc, Cc, nullptr, gbuf, nullptr, nullptr);
  wkv_chunk_kernel<<<Bb * Hh * 2, 256, 0, stream>>>(rb, kb, vb, wkv0, td, tf, att, wkv_out);
  gn_mul_kernel<<<BT, 256, 0, stream>>>(att, gbuf, gnw, gnb, xo);
  gemm_bt<4><<<dim3(16, 32), 256, 0, stream>>>(xo, WoT, BT, Cc, Cc, out, nullptr, x, nullptr);
  ln_mix2<<<BT, 256, 0, stream>>>(out, ffn_shift, ln2w, ln2b, cmk, cmr, xck, xcr, x2_last);
  gemm_bt<3><<<dim3(56, 32), 256, 0, stream>>>(xck, WckT, BT, FF, Cc, nullptr, kk, nullptr, nullptr);
  gemm_bt<0><<<dim3(16, 32), 256, 0, stream>>>(kk, WcvT, BT, Cc, FF, kv, nullptr, nullptr, nullptr);
  gemm_bt<5><<<dim3(16, 32), 256, 0, stream>>>(xcr, WcrT, BT, Cc, Cc, out, nullptr, out, kv);

  (void)in_sizes; (void)n_in; (void)out_size;
}

// Round 4
// 946.325 us; speedup vs baseline: 1.5015x; 1.1636x over previous
//
#include <hip/hip_runtime.h>
#include <cstdint>
#include <cstddef>

typedef unsigned short u16;
typedef unsigned int u32;
typedef short bf16x8 __attribute__((ext_vector_type(8)));
typedef unsigned short u16x4 __attribute__((ext_vector_type(4)));
typedef unsigned short u16x8 __attribute__((ext_vector_type(8)));
typedef float f32x4 __attribute__((ext_vector_type(4)));

#define DEV __device__ __forceinline__

// ---------- constants ----------
constexpr int Bb = 4, Tt = 1024, Cc = 2048, Hh = 32, Nd = 64, FF = 7168;
constexpr int BT = Bb * Tt; // 4096
constexpr int NCH = 16;     // chunks of 64

// ---------- helpers ----------
DEV u16 f2bf(float f) {
  union { float f; unsigned u; } un; un.f = f;
  unsigned r = un.u + 0x7FFFu + ((un.u >> 16) & 1u);
  return (u16)(r >> 16);
}
DEV float bf2f(u16 h) {
  union { unsigned u; float f; } un; un.u = ((unsigned)h) << 16;
  return un.f;
}
DEV void gll16(const u16* gp, u16* lp) {
  __builtin_amdgcn_global_load_lds(
      (const __attribute__((address_space(1))) unsigned int*)gp,
      (__attribute__((address_space(3))) unsigned int*)lp,
      16, 0, 0);
}

// ---------- transpose + f32->bf16: W[Kk][Nn] -> Wt[Nn][Kk] ----------
__global__ void transpose_to_bf16(const float* __restrict__ W, u16* __restrict__ Wt,
                                  int Kk, int Nn) {
  __shared__ float tile[32][33];
  int n0 = blockIdx.x * 32, k0 = blockIdx.y * 32;
  int tx = threadIdx.x & 31, ty = threadIdx.x >> 5;
  #pragma unroll
  for (int r = 0; r < 32; r += 8)
    tile[r + ty][tx] = W[(size_t)(k0 + r + ty) * Nn + n0 + tx];
  __syncthreads();
  #pragma unroll
  for (int r = 0; r < 32; r += 8)
    Wt[(size_t)(n0 + r + ty) * Kk + k0 + tx] = f2bf(tile[tx][r + ty]);
}

// ---------- block LayerNorm stats helper ----------
DEV void block_ln(const float* __restrict__ src, int tid, float* red,
                  float vals[8], float& mean, float& inv) {
  float s = 0.f, ss = 0.f;
  #pragma unroll
  for (int i = 0; i < 8; i++) {
    float t = src[tid + i * 256];
    vals[i] = t; s += t; ss += t * t;
  }
  #pragma unroll
  for (int m = 1; m < 64; m <<= 1) { s += __shfl_xor(s, m); ss += __shfl_xor(ss, m); }
  int lane = tid & 63, wv = tid >> 6;
  __syncthreads();
  if (lane == 0) { red[wv] = s; red[4 + wv] = ss; }
  __syncthreads();
  s = red[0] + red[1] + red[2] + red[3];
  ss = red[4] + red[5] + red[6] + red[7];
  mean = s * (1.f / Cc);
  float var = ss * (1.f / Cc) - mean * mean;
  inv = rsqrtf(var + 1e-5f);
}

// ---------- fused LN + 4-way mix ----------
__global__ __launch_bounds__(256)
void ln_mix4(const float* __restrict__ x, const float* __restrict__ shift,
             const float* __restrict__ w, const float* __restrict__ b,
             const float* __restrict__ mk, const float* __restrict__ mv,
             const float* __restrict__ mr, const float* __restrict__ mg,
             u16* __restrict__ xk, u16* __restrict__ xv,
             u16* __restrict__ xr, u16* __restrict__ xg,
             float* __restrict__ last) {
  int row = blockIdx.x;
  int t = row & (Tt - 1), bb = row >> 10;
  int tid = threadIdx.x;
  __shared__ float red[8];
  const float* cur = x + (size_t)row * Cc;
  float cv[8], pv[8], cm, ci, pm = 0.f, pi = 1.f;
  block_ln(cur, tid, red, cv, cm, ci);
  bool t0 = (t == 0);
  const float* prev = t0 ? (shift + (size_t)bb * Cc) : (cur - Cc);
  if (!t0) {
    block_ln(prev, tid, red, pv, pm, pi);
  } else {
    #pragma unroll
    for (int i = 0; i < 8; i++) pv[i] = prev[tid + i * 256];
  }
  size_t o = (size_t)row * Cc;
  bool isLast = (t == Tt - 1);
  #pragma unroll
  for (int i = 0; i < 8; i++) {
    int c = tid + i * 256;
    float xc = (cv[i] - cm) * ci * w[c] + b[c];
    float xp = t0 ? pv[i] : (pv[i] - pm) * pi * w[c] + b[c];
    xk[o + c] = f2bf(xp + mk[c] * (xc - xp));
    xv[o + c] = f2bf(xp + mv[c] * (xc - xp));
    xr[o + c] = f2bf(xp + mr[c] * (xc - xp));
    xg[o + c] = f2bf(xp + mg[c] * (xc - xp));
    if (isLast) last[(size_t)bb * Cc + c] = xc;
  }
}

// ---------- fused LN + 2-way mix ----------
__global__ __launch_bounds__(256)
void ln_mix2(const float* __restrict__ x, const float* __restrict__ shift,
             const float* __restrict__ w, const float* __restrict__ b,
             const float* __restrict__ ck, const float* __restrict__ cr,
             u16* __restrict__ xck, u16* __restrict__ xcr,
             float* __restrict__ last) {
  int row = blockIdx.x;
  int t = row & (Tt - 1), bb = row >> 10;
  int tid = threadIdx.x;
  __shared__ float red[8];
  const float* cur = x + (size_t)row * Cc;
  float cv[8], pv[8], cm, ci, pm = 0.f, pi = 1.f;
  block_ln(cur, tid, red, cv, cm, ci);
  bool t0 = (t == 0);
  const float* prev = t0 ? (shift + (size_t)bb * Cc) : (cur - Cc);
  if (!t0) {
    block_ln(prev, tid, red, pv, pm, pi);
  } else {
    #pragma unroll
    for (int i = 0; i < 8; i++) pv[i] = prev[tid + i * 256];
  }
  size_t o = (size_t)row * Cc;
  bool isLast = (t == Tt - 1);
  #pragma unroll
  for (int i = 0; i < 8; i++) {
    int c = tid + i * 256;
    float xc = (cv[i] - cm) * ci * w[c] + b[c];
    float xp = t0 ? pv[i] : (pv[i] - pm) * pi * w[c] + b[c];
    xck[o + c] = f2bf(xp + ck[c] * (xc - xp));
    xcr[o + c] = f2bf(xp + cr[c] * (xc - xp));
    if (isLast) last[(size_t)bb * Cc + c] = xc;
  }
}

// ---------- GEMM core macro body (128x128 tile, BK=32) ----------
template <int EPI>
__global__ __launch_bounds__(256)
void gemm_bt(const u16* __restrict__ A, const u16* __restrict__ Bt,
             int M, int N, int K,
             float* __restrict__ Co, u16* __restrict__ Cb,
             const float* __restrict__ X1, const float* __restrict__ X2) {
  __shared__ u16 As[128 * 32];
  __shared__ u16 Bs[128 * 32];
  const int tid = threadIdx.x;
  const int m0 = blockIdx.y * 128, n0 = blockIdx.x * 128;
  const int wave = tid >> 6, lane = tid & 63;
  const int wm = (wave >> 1) * 64, wn = (wave & 1) * 64;
  const int lrow = lane & 15, kg = lane >> 4;
  const int srow = tid >> 2, skoff = (tid & 3) * 8;

  const u16* Ab = A + (size_t)(m0 + srow) * K + skoff;
  const u16* Bbp = Bt + (size_t)(n0 + srow) * K + skoff;

  f32x4 acc[4][4] = {};
  const u16* Ard = As + (wm + lrow) * 32 + kg * 8;
  const u16* Brd = Bs + (wn + lrow) * 32 + kg * 8;

  for (int kt = 0; kt < K; kt += 32) {
    __syncthreads();
    gll16(Ab + kt, As + tid * 8);
    gll16(Ab + kt + (size_t)64 * K, As + tid * 8 + 2048);
    gll16(Bbp + kt, Bs + tid * 8);
    gll16(Bbp + kt + (size_t)64 * K, Bs + tid * 8 + 2048);
    __syncthreads();
    bf16x8 af[4], bfr[4];
    #pragma unroll
    for (int mi = 0; mi < 4; mi++) af[mi] = *(const bf16x8*)(Ard + mi * 512);
    #pragma unroll
    for (int ni = 0; ni < 4; ni++) bfr[ni] = *(const bf16x8*)(Brd + ni * 512);
    #pragma unroll
    for (int mi = 0; mi < 4; mi++)
      #pragma unroll
      for (int ni = 0; ni < 4; ni++)
        acc[mi][ni] = __builtin_amdgcn_mfma_f32_16x16x32_bf16(af[mi], bfr[ni], acc[mi][ni], 0, 0, 0);
  }

  #pragma unroll
  for (int mi = 0; mi < 4; mi++) {
    #pragma unroll
    for (int jj = 0; jj < 4; jj++) {
      const int gr = m0 + wm + mi * 16 + kg * 4 + jj;
      const size_t ro = (size_t)gr * N;
      #pragma unroll
      for (int ni = 0; ni < 4; ni++) {
        const int gc = n0 + wn + ni * 16 + lrow;
        float val = acc[mi][ni][jj];
        if constexpr (EPI == 0) {
          Co[ro + gc] = val;
        } else if constexpr (EPI == 1) {
          Cb[ro + gc] = f2bf(val);
        } else if constexpr (EPI == 2) {
          float s = 1.f / (1.f + __expf(-val));
          Cb[ro + gc] = f2bf(val * s);
        } else if constexpr (EPI == 3) {
          float t = fmaxf(val, 0.f);
          Cb[ro + gc] = f2bf(t * t);
        } else if constexpr (EPI == 4) {
          Co[ro + gc] = X1[ro + gc] + val;
        } else {
          float s = 1.f / (1.f + __expf(-val));
          Co[ro + gc] = fmaf(s, X2[ro + gc], X1[ro + gc]);
        }
      }
    }
  }
}

// ---------- batched projection GEMM (4 GEMMs via blockIdx.z; z==3 -> silu) ----------
__global__ __launch_bounds__(256)
void gemm_proj(const u16* __restrict__ A0, const u16* __restrict__ A1,
               const u16* __restrict__ A2, const u16* __restrict__ A3,
               const u16* __restrict__ B0, const u16* __restrict__ B1,
               const u16* __restrict__ B2, const u16* __restrict__ B3,
               u16* __restrict__ C0, u16* __restrict__ C1,
               u16* __restrict__ C2, u16* __restrict__ C3) {
  const int z = blockIdx.z;
  const u16* A = (z == 0) ? A0 : (z == 1) ? A1 : (z == 2) ? A2 : A3;
  const u16* Bt = (z == 0) ? B0 : (z == 1) ? B1 : (z == 2) ? B2 : B3;
  u16* Cb = (z == 0) ? C0 : (z == 1) ? C1 : (z == 2) ? C2 : C3;
  const int K = Cc, N = Cc;

  __shared__ u16 As[128 * 32];
  __shared__ u16 Bs[128 * 32];
  const int tid = threadIdx.x;
  const int m0 = blockIdx.y * 128, n0 = blockIdx.x * 128;
  const int wave = tid >> 6, lane = tid & 63;
  const int wm = (wave >> 1) * 64, wn = (wave & 1) * 64;
  const int lrow = lane & 15, kg = lane >> 4;
  const int srow = tid >> 2, skoff = (tid & 3) * 8;

  const u16* Ab = A + (size_t)(m0 + srow) * K + skoff;
  const u16* Bbp = Bt + (size_t)(n0 + srow) * K + skoff;

  f32x4 acc[4][4] = {};
  const u16* Ard = As + (wm + lrow) * 32 + kg * 8;
  const u16* Brd = Bs + (wn + lrow) * 32 + kg * 8;

  for (int kt = 0; kt < K; kt += 32) {
    __syncthreads();
    gll16(Ab + kt, As + tid * 8);
    gll16(Ab + kt + (size_t)64 * K, As + tid * 8 + 2048);
    gll16(Bbp + kt, Bs + tid * 8);
    gll16(Bbp + kt + (size_t)64 * K, Bs + tid * 8 + 2048);
    __syncthreads();
    bf16x8 af[4], bfr[4];
    #pragma unroll
    for (int mi = 0; mi < 4; mi++) af[mi] = *(const bf16x8*)(Ard + mi * 512);
    #pragma unroll
    for (int ni = 0; ni < 4; ni++) bfr[ni] = *(const bf16x8*)(Brd + ni * 512);
    #pragma unroll
    for (int mi = 0; mi < 4; mi++)
      #pragma unroll
      for (int ni = 0; ni < 4; ni++)
        acc[mi][ni] = __builtin_amdgcn_mfma_f32_16x16x32_bf16(af[mi], bfr[ni], acc[mi][ni], 0, 0, 0);
  }

  const bool silu = (z == 3);
  #pragma unroll
  for (int mi = 0; mi < 4; mi++) {
    #pragma unroll
    for (int jj = 0; jj < 4; jj++) {
      const int gr = m0 + wm + mi * 16 + kg * 4 + jj;
      const size_t ro = (size_t)gr * N;
      #pragma unroll
      for (int ni = 0; ni < 4; ni++) {
        const int gc = n0 + wn + ni * 16 + lrow;
        float val = acc[mi][ni][jj];
        if (silu) val = val / (1.f + __expf(-val));
        Cb[ro + gc] = f2bf(val);
      }
    }
  }
}

// ======================= chunked WKV : three kernels =======================
// pre:  per (bh,c): A (MFMA via sub-chunk factorization + VALU diag),
//       Y_intra = A@V, D = K~^T@V, R~ out.   scan: S_{c+1}=w64*S_c+D_c.
// post: Y = Y_intra + R~@S_c, fused groupnorm*g -> xo.

__global__ __launch_bounds__(256)
void wkv_pre(const u16* __restrict__ rg, const u16* __restrict__ kg,
             const u16* __restrict__ vg, const float* __restrict__ td,
             const float* __restrict__ tf,
             float* __restrict__ Yb, float* __restrict__ Db,
             u16* __restrict__ Rtb) {
  __shared__ float Pt[64][68];
  __shared__ float uL[64];
  __shared__ u16 rB[64 * 72];
  __shared__ u16 kB[64 * 72];
  __shared__ u16 Rh[64 * 72];
  __shared__ u16 KhX[96 * 72];   // K-hat variants; later aliased as K~^T (rows 0..63)
  __shared__ u16 vA[64 * 72];    // raw v; later aliased as A (bf16)
  __shared__ u16 Vt[64 * 72];

  const int tid = threadIdx.x, bid = blockIdx.x;
  const int bh = bid >> 4, c = bid & 15;
  const int b = bh >> 5, h = bh & 31;
  const int lane = tid & 63, w = tid >> 6;

  // ---- Pt power table ----
  {
    int i = tid & 63;
    float d = __expf(td[h * 64 + i]);
    float c1 = -1.4426950408889634f * d;
    int e0 = (tid >> 6) * 16;
    #pragma unroll
    for (int e = 0; e < 16; e++) Pt[e0 + e][i] = exp2f(c1 * (float)(e0 + e));
    if (tid < 64) uL[tid] = tf[h * 64 + tid];
  }
  __syncthreads();

  // ---- stage r,k,v + derived R^,R~,K^ variants ----
  const int row = tid >> 2, col0 = (tid & 3) * 16;
  const int tl = row & 15;
  {
    size_t gro = ((size_t)b * Tt + c * 64 + row) * Cc + h * 64 + col0;
    u16x8 rv0 = *(const u16x8*)(rg + gro);
    u16x8 rv1 = *(const u16x8*)(rg + gro + 8);
    u16x8 kv0 = *(const u16x8*)(kg + gro);
    u16x8 kv1 = *(const u16x8*)(kg + gro + 8);
    u16x8 vv0 = *(const u16x8*)(vg + gro);
    u16x8 vv1 = *(const u16x8*)(vg + gro + 8);
    *(u16x8*)&rB[row * 72 + col0] = rv0; *(u16x8*)&rB[row * 72 + col0 + 8] = rv1;
    *(u16x8*)&kB[row * 72 + col0] = kv0; *(u16x8*)&kB[row * 72 + col0 + 8] = kv1;
    *(u16x8*)&vA[row * 72 + col0] = vv0; *(u16x8*)&vA[row * 72 + col0 + 8] = vv1;
    float rf[16], kf[16];
    #pragma unroll
    for (int e = 0; e < 8; e++) { rf[e] = bf2f(rv0[e]); rf[8 + e] = bf2f(rv1[e]); }
    #pragma unroll
    for (int e = 0; e < 8; e++) { kf[e] = bf2f(kv0[e]); kf[8 + e] = bf2f(kv1[e]); }
    // R^ = r*w^(tau%16);  R~ = r*w^tau -> global
    u16x8 o0, o1, t0_, t1_;
    #pragma unroll
    for (int e = 0; e < 8; e++) {
      o0[e] = f2bf(rf[e] * Pt[tl][col0 + e]);
      o1[e] = f2bf(rf[8 + e] * Pt[tl][col0 + 8 + e]);
      t0_[e] = f2bf(rf[e] * Pt[row][col0 + e]);
      t1_[e] = f2bf(rf[8 + e] * Pt[row][col0 + 8 + e]);
    }
    *(u16x8*)&Rh[row * 72 + col0] = o0; *(u16x8*)&Rh[row * 72 + col0 + 8] = o1;
    u16* rtp = Rtb + (size_t)bid * 4096 + row * 64 + col0;
    *(u16x8*)rtp = t0_; *(u16x8*)(rtp + 8) = t1_;
    // K^ variants: exponent (15-tl) + 16d
    if (row < 48) {
      u16x8 a0, a1;
      #pragma unroll
      for (int e = 0; e < 8; e++) {
        a0[e] = f2bf(kf[e] * Pt[15 - tl][col0 + e]);
        a1[e] = f2bf(kf[8 + e] * Pt[15 - tl][col0 + 8 + e]);
      }
      *(u16x8*)&KhX[row * 72 + col0] = a0; *(u16x8*)&KhX[row * 72 + col0 + 8] = a1;
    }
    if (row < 32) {
      u16x8 a0, a1;
      #pragma unroll
      for (int e = 0; e < 8; e++) {
        a0[e] = f2bf(kf[e] * Pt[31 - tl][col0 + e]);
        a1[e] = f2bf(kf[8 + e] * Pt[31 - tl][col0 + 8 + e]);
      }
      *(u16x8*)&KhX[(48 + row) * 72 + col0] = a0; *(u16x8*)&KhX[(48 + row) * 72 + col0 + 8] = a1;
    }
    if (row < 16) {
      u16x8 a0, a1;
      #pragma unroll
      for (int e = 0; e < 8; e++) {
        a0[e] = f2bf(kf[e] * Pt[47 - tl][col0 + e]);
        a1[e] = f2bf(kf[8 + e] * Pt[47 - tl][col0 + 8 + e]);
      }
      *(u16x8*)&KhX[(80 + row) * 72 + col0] = a0; *(u16x8*)&KhX[(80 + row) * 72 + col0 + 8] = a1;
    }
  }
  __syncthreads();

  // ---- build Vt[j][s] from vA ----
  {
    const int jj = tid & 63, s0 = (tid >> 6) * 16;
    #pragma unroll
    for (int ds = 0; ds < 16; ds += 2) {
      u32 pk = ((u32)vA[(s0 + ds + 1) * 72 + jj] << 16) | vA[(s0 + ds) * 72 + jj];
      *(u32*)&Vt[jj * 72 + s0 + ds] = pk;
    }
  }
  __syncthreads();

  // ---- P1: A matrix (aB aliases vA) ----
  u16* aB = vA;
  {
    // off-diagonal pairs via MFMA
    const int pr[6] = {1, 2, 3, 2, 3, 3};
    const int qr[6] = {0, 1, 2, 0, 1, 0};
    const int dr[6] = {0, 0, 0, 1, 1, 2};
    const int lr = lane & 15, kq = lane >> 4;
    for (int pi = w; pi < 6; pi += 4) {
      const int p = pr[pi], q = qr[pi], d = dr[pi];
      const int kbase = (d == 0) ? q * 16 : (d == 1) ? 48 + q * 16 : 80 + q * 16;
      f32x4 aacc = {};
      #pragma unroll
      for (int kf2 = 0; kf2 < 2; kf2++) {
        bf16x8 af = *(const bf16x8*)&Rh[(p * 16 + lr) * 72 + kf2 * 32 + kq * 8];
        bf16x8 bf_ = *(const bf16x8*)&KhX[(kbase + lr) * 72 + kf2 * 32 + kq * 8];
        aacc = __builtin_amdgcn_mfma_f32_16x16x32_bf16(af, bf_, aacc, 0, 0, 0);
      }
      #pragma unroll
      for (int reg = 0; reg < 4; reg++) {
        aB[(p * 16 + kq * 4 + reg) * 72 + q * 16 + lr] = f2bf(aacc[reg]);
        aB[(q * 16 + kq * 4 + reg) * 72 + p * 16 + lr] = 0;  // zero mirror tile
      }
    }
    // diagonal block p = w (VALU, banded + u on diag)
    for (int e = lane; e < 256; e += 64) {
      const int tl2 = e >> 4, sl = e & 15;
      float a = 0.f;
      if (sl <= tl2) {
        const u16* rp = &rB[(w * 16 + tl2) * 72];
        const u16* kp = &kB[(w * 16 + sl) * 72];
        const float* pp = (sl == tl2) ? uL : &Pt[tl2 - 1 - sl][0];
        #pragma unroll
        for (int i0 = 0; i0 < 64; i0 += 4) {
          u16x4 ra = *(const u16x4*)(rp + i0);
          u16x4 ka = *(const u16x4*)(kp + i0);
          f32x4 pa = *(const f32x4*)(pp + i0);
          #pragma unroll
          for (int di = 0; di < 4; di++)
            a = fmaf(bf2f(ra[di]) * bf2f(ka[di]), pa[di], a);
        }
      }
      aB[(w * 16 + tl2) * 72 + w * 16 + sl] = f2bf(a);
    }
  }
  __syncthreads();

  // ---- build K~^T[i][s] = k[s,i]*w^(63-s) into KhX rows 0..63 ----
  u16* Ktt = KhX;
  {
    const int ii = tid & 63, s0 = (tid >> 6) * 16;
    #pragma unroll
    for (int ds = 0; ds < 16; ds += 2) {
      float v0 = bf2f(kB[(s0 + ds) * 72 + ii]) * Pt[63 - (s0 + ds)][ii];
      float v1 = bf2f(kB[(s0 + ds + 1) * 72 + ii]) * Pt[63 - (s0 + ds + 1)][ii];
      u32 pk = ((u32)f2bf(v1) << 16) | f2bf(v0);
      *(u32*)&Ktt[ii * 72 + s0 + ds] = pk;
    }
  }
  __syncthreads();

  // ---- P2: Y_intra = A@V^T', D = K~^T@V ----
  const int lr = lane & 15, kq = lane >> 4;
  {
    f32x4 yac[4] = {};
    #pragma unroll
    for (int kf2 = 0; kf2 < 2; kf2++) {
      bf16x8 af = *(const bf16x8*)&aB[(w * 16 + lr) * 72 + kf2 * 32 + kq * 8];
      #pragma unroll
      for (int nf = 0; nf < 4; nf++) {
        bf16x8 bf_ = *(const bf16x8*)&Vt[(nf * 16 + lr) * 72 + kf2 * 32 + kq * 8];
        yac[nf] = __builtin_amdgcn_mfma_f32_16x16x32_bf16(af, bf_, yac[nf], 0, 0, 0);
      }
    }
    float* Yp = Yb + (size_t)bid * 4096;
    #pragma unroll
    for (int nf = 0; nf < 4; nf++)
      #pragma unroll
      for (int reg = 0; reg < 4; reg++)
        Yp[(w * 16 + kq * 4 + reg) * 64 + nf * 16 + lr] = yac[nf][reg];

    f32x4 dac[4] = {};
    #pragma unroll
    for (int kf2 = 0; kf2 < 2; kf2++) {
      bf16x8 af = *(const bf16x8*)&Ktt[(w * 16 + lr) * 72 + kf2 * 32 + kq * 8];
      #pragma unroll
      for (int nf = 0; nf < 4; nf++) {
        bf16x8 bf_ = *(const bf16x8*)&Vt[(nf * 16 + lr) * 72 + kf2 * 32 + kq * 8];
        dac[nf] = __builtin_amdgcn_mfma_f32_16x16x32_bf16(af, bf_, dac[nf], 0, 0, 0);
      }
    }
    float* Dp = Db + (size_t)bid * 4096;
    #pragma unroll
    for (int nf = 0; nf < 4; nf++)
      #pragma unroll
      for (int reg = 0; reg < 4; reg++)
        Dp[(w * 16 + kq * 4 + reg) * 64 + nf * 16 + lr] = dac[nf][reg];
  }
}

__global__ __launch_bounds__(256)
void wkv_scan(const float* __restrict__ s0g, const float* __restrict__ td,
              const float* __restrict__ Db, u16* __restrict__ Sbb,
              float* __restrict__ sout) {
  const int bh = blockIdx.x, h = bh & 31;
  const int tid = threadIdx.x;
  const int i = tid >> 2, j0 = (tid & 3) * 16;
  float d = __expf(td[h * 64 + i]);
  float w64 = exp2f(-1.4426950408889634f * d * 64.f);
  f32x4 S[4];
  const float* sp = s0g + ((size_t)bh * 64 + i) * 64 + j0;
  #pragma unroll
  for (int q = 0; q < 4; q++) S[q] = *(const f32x4*)(sp + q * 4);
  for (int c = 0; c < NCH; c++) {
    u16* op = Sbb + ((size_t)(bh * 16 + c)) * 4096 + i * 64 + j0;
    u16x8 o0, o1;
    #pragma unroll
    for (int e = 0; e < 4; e++) { o0[e] = f2bf(S[0][e]); o0[4 + e] = f2bf(S[1][e]);
                                  o1[e] = f2bf(S[2][e]); o1[4 + e] = f2bf(S[3][e]); }
    *(u16x8*)op = o0; *(u16x8*)(op + 8) = o1;
    const float* dp = Db + ((size_t)(bh * 16 + c)) * 4096 + i * 64 + j0;
    #pragma unroll
    for (int q = 0; q < 4; q++) {
      f32x4 dv = *(const f32x4*)(dp + q * 4);
      #pragma unroll
      for (int e = 0; e < 4; e++) S[q][e] = fmaf(w64, S[q][e], dv[e]);
    }
  }
  float* fo = sout + ((size_t)bh * 64 + i) * 64 + j0;
  #pragma unroll
  for (int q = 0; q < 4; q++) *(f32x4*)(fo + q * 4) = S[q];
}

__global__ __launch_bounds__(256)
void wkv_post(const u16* __restrict__ Rtb, const u16* __restrict__ Sbb,
              const float* __restrict__ Yb, const u16* __restrict__ g,
              const float* __restrict__ gnw, const float* __restrict__ gnb,
              u16* __restrict__ xo) {
  __shared__ u16 Rt[64 * 72];
  __shared__ u16 St[64 * 72];
  __shared__ u16 xoL[64 * 72];
  const int tid = threadIdx.x, bid = blockIdx.x;
  const int bh = bid >> 4, c = bid & 15;
  const int b = bh >> 5, h = bh & 31;
  const int lane = tid & 63, w = tid >> 6;
  const int row = tid >> 2, col0 = (tid & 3) * 16;

  // stage R~
  {
    const u16* rp = Rtb + (size_t)bid * 4096 + row * 64 + col0;
    u16x8 a0 = *(const u16x8*)rp, a1 = *(const u16x8*)(rp + 8);
    *(u16x8*)&Rt[row * 72 + col0] = a0; *(u16x8*)&Rt[row * 72 + col0 + 8] = a1;
  }
  // stage S transposed -> St[j][i]
  {
    const u16* sp = Sbb + ((size_t)(bh * 16 + c)) * 4096 + row * 64 + col0;
    u16x8 s0 = *(const u16x8*)sp, s1 = *(const u16x8*)(sp + 8);
    #pragma unroll
    for (int e = 0; e < 8; e++) {
      St[(col0 + e) * 72 + row] = s0[e];
      St[(col0 + 8 + e) * 72 + row] = s1[e];
    }
  }
  // acc init = Y_intra
  const int lr = lane & 15, kq = lane >> 4;
  f32x4 acc[4];
  {
    const float* Yp = Yb + (size_t)bid * 4096;
    #pragma unroll
    for (int nf = 0; nf < 4; nf++)
      #pragma unroll
      for (int reg = 0; reg < 4; reg++)
        acc[nf][reg] = Yp[(w * 16 + kq * 4 + reg) * 64 + nf * 16 + lr];
  }
  __syncthreads();
  #pragma unroll
  for (int kf2 = 0; kf2 < 2; kf2++) {
    bf16x8 af = *(const bf16x8*)&Rt[(w * 16 + lr) * 72 + kf2 * 32 + kq * 8];
    #pragma unroll
    for (int nf = 0; nf < 4; nf++) {
      bf16x8 bf_ = *(const bf16x8*)&St[(nf * 16 + lr) * 72 + kf2 * 32 + kq * 8];
      acc[nf] = __builtin_amdgcn_mfma_f32_16x16x32_bf16(af, bf_, acc[nf], 0, 0, 0);
    }
  }
  // fused groupnorm(y/8)*g
  #pragma unroll
  for (int reg = 0; reg < 4; reg++) {
    float s = 0.f, ss = 0.f;
    #pragma unroll
    for (int nf = 0; nf < 4; nf++) {
      float z = acc[nf][reg] * 0.125f;
      s += z; ss += z * z;
    }
    #pragma unroll
    for (int m = 1; m < 16; m <<= 1) { s += __shfl_xor(s, m); ss += __shfl_xor(ss, m); }
    float mean = s * (1.f / 64.f);
    float var = ss * (1.f / 64.f) - mean * mean;
    float inv = rsqrtf(var + 1e-5f);
    const int tau = w * 16 + kq * 4 + reg;
    #pragma unroll
    for (int nf = 0; nf < 4; nf++) {
      const int col = nf * 16 + lr;
      float z = acc[nf][reg] * 0.125f;
      float zn = (z - mean) * inv * gnw[h * 64 + col] + gnb[h * 64 + col];
      float gv = bf2f(g[((size_t)b * Tt + c * 64 + tau) * Cc + h * 64 + col]);
      xoL[tau * 72 + col] = f2bf(zn * gv);
    }
  }
  __syncthreads();
  {
    u16x8 o0 = *(const u16x8*)&xoL[row * 72 + col0];
    u16x8 o1 = *(const u16x8*)&xoL[row * 72 + col0 + 8];
    u16* xop = xo + ((size_t)b * Tt + c * 64 + row) * Cc + h * 64 + col0;
    *(u16x8*)xop = o0; *(u16x8*)(xop + 8) = o1;
  }
}

// ---------- orchestration ----------
extern "C" void kernel_launch(void* const* d_in, const int* in_sizes, int n_in,
                              void* d_out, int out_size, void* d_ws, size_t ws_size,
                              hipStream_t stream) {
  const float* x         = (const float*)d_in[0];
  const float* att_shift = (const float*)d_in[1];
  const float* wkv0      = (const float*)d_in[2];
  const float* ffn_shift = (const float*)d_in[3];
  const float* ln1w = (const float*)d_in[4];
  const float* ln1b = (const float*)d_in[5];
  const float* ln2w = (const float*)d_in[6];
  const float* ln2b = (const float*)d_in[7];
  const float* mixk = (const float*)d_in[8];
  const float* mixv = (const float*)d_in[9];
  const float* mixr = (const float*)d_in[10];
  const float* mixg = (const float*)d_in[11];
  const float* Wr = (const float*)d_in[12];
  const float* Wk = (const float*)d_in[13];
  const float* Wv = (const float*)d_in[14];
  const float* Wg = (const float*)d_in[15];
  const float* Wo = (const float*)d_in[16];
  const float* td = (const float*)d_in[17];
  const float* tf = (const float*)d_in[18];
  const float* gnw = (const float*)d_in[19];
  const float* gnb = (const float*)d_in[20];
  const float* cmk = (const float*)d_in[21];
  const float* cmr = (const float*)d_in[22];
  const float* Wck = (const float*)d_in[23];
  const float* Wcr = (const float*)d_in[24];
  const float* Wcv = (const float*)d_in[25];

  constexpr size_t SZ_CC = (size_t)Cc * Cc * 2;
  constexpr size_t SZ_CF = (size_t)Cc * FF * 2;
  constexpr size_t SZ_AB = (size_t)BT * Cc * 2;
  constexpr size_t O_W   = 0;
  constexpr size_t O_R1  = 6 * SZ_CC + 2 * SZ_CF;
  constexpr size_t R1_SZ = 4 * SZ_AB;
  constexpr size_t O_R2  = O_R1 + R1_SZ;
  constexpr size_t R2_SZ = 3 * SZ_AB;
  constexpr size_t O_R3  = O_R2 + R2_SZ;
  constexpr size_t WS_NEED = O_R3 + SZ_AB;

  if (ws_size < WS_NEED) return;

  char* ws = (char*)d_ws;
  u16* WrT  = (u16*)(ws + O_W);
  u16* WkT  = (u16*)(ws + O_W + 1 * SZ_CC);
  u16* WvT  = (u16*)(ws + O_W + 2 * SZ_CC);
  u16* WgT  = (u16*)(ws + O_W + 3 * SZ_CC);
  u16* WoT  = (u16*)(ws + O_W + 4 * SZ_CC);
  u16* WcrT = (u16*)(ws + O_W + 5 * SZ_CC);
  u16* WckT = (u16*)(ws + O_W + 6 * SZ_CC);
  u16* WcvT = (u16*)(ws + O_W + 6 * SZ_CC + SZ_CF);

  // R1: xk,xv,xr,xg -> (Yb | Rtb | Sbb) -> kk
  u16*   xk  = (u16*)(ws + O_R1);
  u16*   xv  = (u16*)(ws + O_R1 + SZ_AB);
  u16*   xr  = (u16*)(ws + O_R1 + 2 * SZ_AB);
  u16*   xg  = (u16*)(ws + O_R1 + 3 * SZ_AB);
  float* Yb  = (float*)(ws + O_R1);                 // 32 MiB
  u16*   Rtb = (u16*)(ws + O_R1 + 2 * SZ_AB);       // 16 MiB
  u16*   Sbb = (u16*)(ws + O_R1 + 3 * SZ_AB);       // 16 MiB
  u16*   kk  = (u16*)(ws + O_R1);
  // R2: rb,kb,vb -> xo,xck,xcr -> kv+xcr
  u16*   rb  = (u16*)(ws + O_R2);
  u16*   kb  = (u16*)(ws + O_R2 + SZ_AB);
  u16*   vb  = (u16*)(ws + O_R2 + 2 * SZ_AB);
  u16*   xo  = (u16*)(ws + O_R2);
  u16*   xck = (u16*)(ws + O_R2 + SZ_AB);
  u16*   xcr = (u16*)(ws + O_R2 + 2 * SZ_AB);
  float* kv  = (float*)(ws + O_R2);
  u16*   gbuf = (u16*)(ws + O_R3);

  float* out      = (float*)d_out;
  float* x1_last  = out + (size_t)BT * Cc;
  float* wkv_out  = x1_last + (size_t)Bb * Cc;
  float* x2_last  = wkv_out + (size_t)Bb * Hh * Nd * Nd;
  float* Db       = out;  // free until Wo-gemm; scan consumes it first

  transpose_to_bf16<<<dim3(64, 64), 256, 0, stream>>>(Wr, WrT, Cc, Cc);
  transpose_to_bf16<<<dim3(64, 64), 256, 0, stream>>>(Wk, WkT, Cc, Cc);
  transpose_to_bf16<<<dim3(64, 64), 256, 0, stream>>>(Wv, WvT, Cc, Cc);
  transpose_to_bf16<<<dim3(64, 64), 256, 0, stream>>>(Wg, WgT, Cc, Cc);
  transpose_to_bf16<<<dim3(64, 64), 256, 0, stream>>>(Wo, WoT, Cc, Cc);
  transpose_to_bf16<<<dim3(64, 64), 256, 0, stream>>>(Wcr, WcrT, Cc, Cc);
  transpose_to_bf16<<<dim3(224, 64), 256, 0, stream>>>(Wck, WckT, Cc, FF);
  transpose_to_bf16<<<dim3(64, 224), 256, 0, stream>>>(Wcv, WcvT, FF, Cc);

  ln_mix4<<<BT, 256, 0, stream>>>(x, att_shift, ln1w, ln1b,
                                  mixk, mixv, mixr, mixg, xk, xv, xr, xg, x1_last);
  gemm_proj<<<dim3(16, 32, 4), 256, 0, stream>>>(xr, xk, xv, xg,
                                                 WrT, WkT, WvT, WgT,
                                                 rb, kb, vb, gbuf);
  wkv_pre<<<Bb * Hh * NCH, 256, 0, stream>>>(rb, kb, vb, td, tf, Yb, Db, Rtb);
  wkv_scan<<<Bb * Hh, 256, 0, stream>>>(wkv0, td, Db, Sbb, wkv_out);
  wkv_post<<<Bb * Hh * NCH, 256, 0, stream>>>(Rtb, Sbb, Yb, gbuf, gnw, gnb, xo);
  gemm_bt<4><<<dim3(16, 32), 256, 0, stream>>>(xo, WoT, BT, Cc, Cc, out, nullptr, x, nullptr);
  ln_mix2<<<BT, 256, 0, stream>>>(out, ffn_shift, ln2w, ln2b, cmk, cmr, xck, xcr, x2_last);
  gemm_bt<3><<<dim3(56, 32), 256, 0, stream>>>(xck, WckT, BT, FF, Cc, nullptr, kk, nullptr, nullptr);
  gemm_bt<0><<<dim3(16, 32), 256, 0, stream>>>(kk, WcvT, BT, Cc, FF, kv, nullptr, nullptr, nullptr);
  gemm_bt<5><<<dim3(16, 32), 256, 0, stream>>>(xcr, WcrT, BT, Cc, Cc, out, nullptr, out, kv);

  (void)in_sizes; (void)n_in; (void)out_size;
}

// Round 5
// 809.371 us; speedup vs baseline: 1.7556x; 1.1692x over previous
//
#include <hip/hip_runtime.h>
#include <cstdint>
#include <cstddef>

typedef unsigned short u16;
typedef unsigned int u32;
typedef short bf16x8 __attribute__((ext_vector_type(8)));
typedef unsigned short u16x4 __attribute__((ext_vector_type(4)));
typedef unsigned short u16x8 __attribute__((ext_vector_type(8)));
typedef float f32x4 __attribute__((ext_vector_type(4)));

#define DEV __device__ __forceinline__

// ---------- constants ----------
constexpr int Bb = 4, Tt = 1024, Cc = 2048, Hh = 32, Nd = 64, FF = 7168;
constexpr int BT = Bb * Tt; // 4096
constexpr int NCH = 16;     // chunks of 64

// ---------- helpers ----------
DEV u16 f2bf(float f) {
  union { float f; unsigned u; } un; un.f = f;
  unsigned r = un.u + 0x7FFFu + ((un.u >> 16) & 1u);
  return (u16)(r >> 16);
}
DEV float bf2f(u16 h) {
  union { unsigned u; float f; } un; un.u = ((unsigned)h) << 16;
  return un.f;
}
DEV void gll16(const u16* gp, u16* lp) {
  __builtin_amdgcn_global_load_lds(
      (const __attribute__((address_space(1))) unsigned int*)gp,
      (__attribute__((address_space(3))) unsigned int*)lp,
      16, 0, 0);
}

// ---------- transpose + f32->bf16: W[Kk][Nn] -> Wt[Nn][Kk] ----------
__global__ void transpose_to_bf16(const float* __restrict__ W, u16* __restrict__ Wt,
                                  int Kk, int Nn) {
  __shared__ float tile[32][33];
  int n0 = blockIdx.x * 32, k0 = blockIdx.y * 32;
  int tx = threadIdx.x & 31, ty = threadIdx.x >> 5;
  #pragma unroll
  for (int r = 0; r < 32; r += 8)
    tile[r + ty][tx] = W[(size_t)(k0 + r + ty) * Nn + n0 + tx];
  __syncthreads();
  #pragma unroll
  for (int r = 0; r < 32; r += 8)
    Wt[(size_t)(n0 + r + ty) * Kk + k0 + tx] = f2bf(tile[tx][r + ty]);
}

// ---------- block LayerNorm stats helper ----------
DEV void block_ln(const float* __restrict__ src, int tid, float* red,
                  float vals[8], float& mean, float& inv) {
  float s = 0.f, ss = 0.f;
  #pragma unroll
  for (int i = 0; i < 8; i++) {
    float t = src[tid + i * 256];
    vals[i] = t; s += t; ss += t * t;
  }
  #pragma unroll
  for (int m = 1; m < 64; m <<= 1) { s += __shfl_xor(s, m); ss += __shfl_xor(ss, m); }
  int lane = tid & 63, wv = tid >> 6;
  __syncthreads();
  if (lane == 0) { red[wv] = s; red[4 + wv] = ss; }
  __syncthreads();
  s = red[0] + red[1] + red[2] + red[3];
  ss = red[4] + red[5] + red[6] + red[7];
  mean = s * (1.f / Cc);
  float var = ss * (1.f / Cc) - mean * mean;
  inv = rsqrtf(var + 1e-5f);
}

// ---------- fused LN + 4-way mix ----------
__global__ __launch_bounds__(256)
void ln_mix4(const float* __restrict__ x, const float* __restrict__ shift,
             const float* __restrict__ w, const float* __restrict__ b,
             const float* __restrict__ mk, const float* __restrict__ mv,
             const float* __restrict__ mr, const float* __restrict__ mg,
             u16* __restrict__ xk, u16* __restrict__ xv,
             u16* __restrict__ xr, u16* __restrict__ xg,
             float* __restrict__ last) {
  int row = blockIdx.x;
  int t = row & (Tt - 1), bb = row >> 10;
  int tid = threadIdx.x;
  __shared__ float red[8];
  const float* cur = x + (size_t)row * Cc;
  float cv[8], pv[8], cm, ci, pm = 0.f, pi = 1.f;
  block_ln(cur, tid, red, cv, cm, ci);
  bool t0 = (t == 0);
  const float* prev = t0 ? (shift + (size_t)bb * Cc) : (cur - Cc);
  if (!t0) {
    block_ln(prev, tid, red, pv, pm, pi);
  } else {
    #pragma unroll
    for (int i = 0; i < 8; i++) pv[i] = prev[tid + i * 256];
  }
  size_t o = (size_t)row * Cc;
  bool isLast = (t == Tt - 1);
  #pragma unroll
  for (int i = 0; i < 8; i++) {
    int c = tid + i * 256;
    float xc = (cv[i] - cm) * ci * w[c] + b[c];
    float xp = t0 ? pv[i] : (pv[i] - pm) * pi * w[c] + b[c];
    xk[o + c] = f2bf(xp + mk[c] * (xc - xp));
    xv[o + c] = f2bf(xp + mv[c] * (xc - xp));
    xr[o + c] = f2bf(xp + mr[c] * (xc - xp));
    xg[o + c] = f2bf(xp + mg[c] * (xc - xp));
    if (isLast) last[(size_t)bb * Cc + c] = xc;
  }
}

// ---------- fused LN + 2-way mix ----------
__global__ __launch_bounds__(256)
void ln_mix2(const float* __restrict__ x, const float* __restrict__ shift,
             const float* __restrict__ w, const float* __restrict__ b,
             const float* __restrict__ ck, const float* __restrict__ cr,
             u16* __restrict__ xck, u16* __restrict__ xcr,
             float* __restrict__ last) {
  int row = blockIdx.x;
  int t = row & (Tt - 1), bb = row >> 10;
  int tid = threadIdx.x;
  __shared__ float red[8];
  const float* cur = x + (size_t)row * Cc;
  float cv[8], pv[8], cm, ci, pm = 0.f, pi = 1.f;
  block_ln(cur, tid, red, cv, cm, ci);
  bool t0 = (t == 0);
  const float* prev = t0 ? (shift + (size_t)bb * Cc) : (cur - Cc);
  if (!t0) {
    block_ln(prev, tid, red, pv, pm, pi);
  } else {
    #pragma unroll
    for (int i = 0; i < 8; i++) pv[i] = prev[tid + i * 256];
  }
  size_t o = (size_t)row * Cc;
  bool isLast = (t == Tt - 1);
  #pragma unroll
  for (int i = 0; i < 8; i++) {
    int c = tid + i * 256;
    float xc = (cv[i] - cm) * ci * w[c] + b[c];
    float xp = t0 ? pv[i] : (pv[i] - pm) * pi * w[c] + b[c];
    xck[o + c] = f2bf(xp + ck[c] * (xc - xp));
    xcr[o + c] = f2bf(xp + cr[c] * (xc - xp));
    if (isLast) last[(size_t)bb * Cc + c] = xc;
  }
}

// ================= 256x256 deep-pipelined GEMM (8-wave, BK=64) =================
// C[M][N] = A[M][K](bf16 rm) * Bt[N][K](bf16 rm)^T
// LDS: 8 slots of 16KB: [A buf0 h0, A b0 h1, A b1 h0, A b1 h1, B b0 h0, ...]
// swizzle: within a slot, byte off in row XORed with row bits 1-3 -> bits 4-6.
// Phase p (nh=p>>1, kh=p&1): reads A frags (p<2, cached), B frags (4),
// stages one half-tile, barrier, 16 MFMA (setprio), barrier.
// vmcnt(4) once per K-tile (counted, never 0 until tail).

DEV int swzoff(int row, int off) {
  return (row << 7) +
         (off ^ ((((row >> 1) & 1) << 4) | (((row >> 2) & 1) << 5) | (((row >> 3) & 1) << 6)));
}

DEV void stage_half(const u16* __restrict__ gbase, int ldK, u16* slot, int tid) {
  #pragma unroll
  for (int c2 = 0; c2 < 2; c2++) {
    const int D = c2 * 8192 + tid * 16;   // linear dest byte within slot
    const int row = D >> 7;
    const int off = (D & 127) ^ ((((row >> 1) & 1) << 4) | (((row >> 2) & 1) << 5) | (((row >> 3) & 1) << 6));
    gll16(gbase + (size_t)row * ldK + (off >> 1), (u16*)((char*)slot + D));
  }
}

// EPI: 0=f32, 1=bf16 (+act: silu), 3=relu^2->bf16, 4=X1+val->f32, 5=X1+sigmoid(val)*X2->f32
template <int EPI>
DEV void g256_core(const u16* __restrict__ A, const u16* __restrict__ Bt,
                   int N, int K,
                   float* __restrict__ Co, u16* __restrict__ Cb,
                   const float* __restrict__ X1, const float* __restrict__ X2,
                   u16 (*lds)[8192], int m0, int n0, int act) {
  const int tid = threadIdx.x;
  const int w = tid >> 6, lane = tid & 63;
  const int l15 = lane & 15, l4 = lane >> 4;
  const int wm = (w & 3) * 64, wn = (w >> 2) * 128;
  const int ahalf = wm >> 7;          // 0,0,1,1
  const int arow0 = wm & 127;         // 0,64,0,64  (wait: 0,64,128&127=0,192&127=64) -> 0/64 within half
  const int bhalf = wn >> 7;
  const int nt = K >> 6;

  const u16* Ag = A + (size_t)m0 * K;
  const u16* Bg = Bt + (size_t)n0 * K;

  f32x4 acc[4][8] = {};
  bf16x8 a[4][2];

  // ---- prologue: tile0 A+B, tile1 A ----
  stage_half(Ag, K, lds[0], tid);
  stage_half(Ag + (size_t)128 * K, K, lds[1], tid);
  stage_half(Bg, K, lds[4], tid);
  stage_half(Bg + (size_t)128 * K, K, lds[5], tid);
  if (nt > 1) {
    stage_half(Ag + 64, K, lds[2], tid);
    stage_half(Ag + (size_t)128 * K + 64, K, lds[3], tid);
    asm volatile("s_waitcnt vmcnt(4)" ::: "memory");
  } else {
    asm volatile("s_waitcnt vmcnt(0)" ::: "memory");
  }
  asm volatile("s_barrier" ::: "memory");

  for (int t = 0; t < nt; t++) {
    const int buf = t & 1;
    const char* Aslot = (const char*)lds[buf * 2 + ahalf];
    const char* Bslot = (const char*)lds[4 + buf * 2 + bhalf];

#define G256_PHASE(p)                                                                       \
    {                                                                                       \
      constexpr int nh = (p) >> 1, kh = (p) & 1;                                            \
      if constexpr ((p) < 2) {                                                              \
        _Pragma("unroll")                                                                   \
        for (int mf = 0; mf < 4; mf++) {                                                    \
          const int row = arow0 + mf * 16 + l15;                                            \
          a[mf][kh] = *(const bf16x8*)(Aslot + swzoff(row, kh * 64 + l4 * 16));             \
        }                                                                                   \
      }                                                                                     \
      bf16x8 bfr[4];                                                                        \
      _Pragma("unroll")                                                                     \
      for (int j = 0; j < 4; j++) {                                                         \
        const int row = (nh * 4 + j) * 16 + l15;                                            \
        bfr[j] = *(const bf16x8*)(Bslot + swzoff(row, kh * 64 + l4 * 16));                  \
      }                                                                                     \
      if constexpr ((p) == 0) {                                                             \
        if (t + 1 < nt) stage_half(Bg + (size_t)(t + 1) * 64, K,                            \
                                   lds[4 + (((t + 1) & 1) << 1)], tid);                     \
      } else if constexpr ((p) == 1) {                                                      \
        if (t + 1 < nt) stage_half(Bg + (size_t)128 * K + (size_t)(t + 1) * 64, K,          \
                                   lds[4 + (((t + 1) & 1) << 1) + 1], tid);                 \
      } else if constexpr ((p) == 2) {                                                      \
        if (t + 2 < nt) stage_half(Ag + (size_t)(t + 2) * 64, K, lds[buf << 1], tid);       \
      } else {                                                                              \
        if (t + 2 < nt) stage_half(Ag + (size_t)128 * K + (size_t)(t + 2) * 64, K,          \
                                   lds[(buf << 1) + 1], tid);                               \
      }                                                                                     \
      asm volatile("s_barrier" ::: "memory");                                               \
      __builtin_amdgcn_s_setprio(1);                                                       \
      _Pragma("unroll")                                                                     \
      for (int mf = 0; mf < 4; mf++)                                                        \
        _Pragma("unroll")                                                                   \
        for (int j = 0; j < 4; j++)                                                         \
          acc[mf][nh * 4 + j] = __builtin_amdgcn_mfma_f32_16x16x32_bf16(                    \
              a[mf][kh], bfr[j], acc[mf][nh * 4 + j], 0, 0, 0);                             \
      __builtin_amdgcn_s_setprio(0);                                                       \
      if constexpr ((p) == 3) {                                                             \
        if (t + 2 < nt) asm volatile("s_waitcnt vmcnt(4)" ::: "memory");                    \
        else            asm volatile("s_waitcnt vmcnt(0)" ::: "memory");                    \
      }                                                                                     \
      asm volatile("s_barrier" ::: "memory");                                               \
    }

    G256_PHASE(0)
    G256_PHASE(1)
    G256_PHASE(2)
    G256_PHASE(3)
#undef G256_PHASE
  }

  // ---- epilogue ----
  #pragma unroll
  for (int mf = 0; mf < 4; mf++) {
    #pragma unroll
    for (int reg = 0; reg < 4; reg++) {
      const int gr = m0 + wm + mf * 16 + l4 * 4 + reg;
      const size_t ro = (size_t)gr * N;
      #pragma unroll
      for (int nf = 0; nf < 8; nf++) {
        const int gc = n0 + wn + nf * 16 + l15;
        float val = acc[mf][nf][reg];
        if constexpr (EPI == 0) {
          Co[ro + gc] = val;
        } else if constexpr (EPI == 1) {
          if (act) val = val / (1.f + __expf(-val));
          Cb[ro + gc] = f2bf(val);
        } else if constexpr (EPI == 3) {
          float tr = fmaxf(val, 0.f);
          Cb[ro + gc] = f2bf(tr * tr);
        } else if constexpr (EPI == 4) {
          Co[ro + gc] = X1[ro + gc] + val;
        } else {
          float s = 1.f / (1.f + __expf(-val));
          Co[ro + gc] = fmaf(s, X2[ro + gc], X1[ro + gc]);
        }
      }
    }
  }
}

template <int EPI>
__global__ __launch_bounds__(512, 2)
void gemm256(const u16* __restrict__ A, const u16* __restrict__ Bt,
             int N, int K,
             float* __restrict__ Co, u16* __restrict__ Cb,
             const float* __restrict__ X1, const float* __restrict__ X2) {
  __shared__ __align__(16) u16 lds[8][8192];
  g256_core<EPI>(A, Bt, N, K, Co, Cb, X1, X2, lds, blockIdx.y * 256, blockIdx.x * 256, 0);
}

__global__ __launch_bounds__(512, 2)
void gemm256_proj(const u16* __restrict__ A0, const u16* __restrict__ A1,
                  const u16* __restrict__ A2, const u16* __restrict__ A3,
                  const u16* __restrict__ B0, const u16* __restrict__ B1,
                  const u16* __restrict__ B2, const u16* __restrict__ B3,
                  u16* __restrict__ C0, u16* __restrict__ C1,
                  u16* __restrict__ C2, u16* __restrict__ C3) {
  __shared__ __align__(16) u16 lds[8][8192];
  const int z = blockIdx.z;
  const u16* A = (z == 0) ? A0 : (z == 1) ? A1 : (z == 2) ? A2 : A3;
  const u16* Bt = (z == 0) ? B0 : (z == 1) ? B1 : (z == 2) ? B2 : B3;
  u16* Cb = (z == 0) ? C0 : (z == 1) ? C1 : (z == 2) ? C2 : C3;
  g256_core<1>(A, Bt, Cc, Cc, nullptr, Cb, nullptr, nullptr, lds,
               blockIdx.y * 256, blockIdx.x * 256, z == 3);
}

// ======================= chunked WKV : three kernels =======================
__global__ __launch_bounds__(256)
void wkv_pre(const u16* __restrict__ rg, const u16* __restrict__ kg,
             const u16* __restrict__ vg, const float* __restrict__ td,
             const float* __restrict__ tf,
             float* __restrict__ Yb, float* __restrict__ Db,
             u16* __restrict__ Rtb) {
  __shared__ float Pt[64][68];
  __shared__ float uL[64];
  __shared__ u16 rB[64 * 72];
  __shared__ u16 kB[64 * 72];
  __shared__ u16 Rh[64 * 72];
  __shared__ u16 KhX[96 * 72];
  __shared__ u16 vA[64 * 72];
  __shared__ u16 Vt[64 * 72];

  const int tid = threadIdx.x, bid = blockIdx.x;
  const int bh = bid >> 4, c = bid & 15;
  const int b = bh >> 5, h = bh & 31;
  const int lane = tid & 63, w = tid >> 6;

  {
    int i = tid & 63;
    float d = __expf(td[h * 64 + i]);
    float c1 = -1.4426950408889634f * d;
    int e0 = (tid >> 6) * 16;
    #pragma unroll
    for (int e = 0; e < 16; e++) Pt[e0 + e][i] = exp2f(c1 * (float)(e0 + e));
    if (tid < 64) uL[tid] = tf[h * 64 + tid];
  }
  __syncthreads();

  const int row = tid >> 2, col0 = (tid & 3) * 16;
  const int tl = row & 15;
  {
    size_t gro = ((size_t)b * Tt + c * 64 + row) * Cc + h * 64 + col0;
    u16x8 rv0 = *(const u16x8*)(rg + gro);
    u16x8 rv1 = *(const u16x8*)(rg + gro + 8);
    u16x8 kv0 = *(const u16x8*)(kg + gro);
    u16x8 kv1 = *(const u16x8*)(kg + gro + 8);
    u16x8 vv0 = *(const u16x8*)(vg + gro);
    u16x8 vv1 = *(const u16x8*)(vg + gro + 8);
    *(u16x8*)&rB[row * 72 + col0] = rv0; *(u16x8*)&rB[row * 72 + col0 + 8] = rv1;
    *(u16x8*)&kB[row * 72 + col0] = kv0; *(u16x8*)&kB[row * 72 + col0 + 8] = kv1;
    *(u16x8*)&vA[row * 72 + col0] = vv0; *(u16x8*)&vA[row * 72 + col0 + 8] = vv1;
    float rf[16], kf[16];
    #pragma unroll
    for (int e = 0; e < 8; e++) { rf[e] = bf2f(rv0[e]); rf[8 + e] = bf2f(rv1[e]); }
    #pragma unroll
    for (int e = 0; e < 8; e++) { kf[e] = bf2f(kv0[e]); kf[8 + e] = bf2f(kv1[e]); }
    u16x8 o0, o1, t0_, t1_;
    #pragma unroll
    for (int e = 0; e < 8; e++) {
      o0[e] = f2bf(rf[e] * Pt[tl][col0 + e]);
      o1[e] = f2bf(rf[8 + e] * Pt[tl][col0 + 8 + e]);
      t0_[e] = f2bf(rf[e] * Pt[row][col0 + e]);
      t1_[e] = f2bf(rf[8 + e] * Pt[row][col0 + 8 + e]);
    }
    *(u16x8*)&Rh[row * 72 + col0] = o0; *(u16x8*)&Rh[row * 72 + col0 + 8] = o1;
    u16* rtp = Rtb + (size_t)bid * 4096 + row * 64 + col0;
    *(u16x8*)rtp = t0_; *(u16x8*)(rtp + 8) = t1_;
    if (row < 48) {
      u16x8 a0, a1;
      #pragma unroll
      for (int e = 0; e < 8; e++) {
        a0[e] = f2bf(kf[e] * Pt[15 - tl][col0 + e]);
        a1[e] = f2bf(kf[8 + e] * Pt[15 - tl][col0 + 8 + e]);
      }
      *(u16x8*)&KhX[row * 72 + col0] = a0; *(u16x8*)&KhX[row * 72 + col0 + 8] = a1;
    }
    if (row < 32) {
      u16x8 a0, a1;
      #pragma unroll
      for (int e = 0; e < 8; e++) {
        a0[e] = f2bf(kf[e] * Pt[31 - tl][col0 + e]);
        a1[e] = f2bf(kf[8 + e] * Pt[31 - tl][col0 + 8 + e]);
      }
      *(u16x8*)&KhX[(48 + row) * 72 + col0] = a0; *(u16x8*)&KhX[(48 + row) * 72 + col0 + 8] = a1;
    }
    if (row < 16) {
      u16x8 a0, a1;
      #pragma unroll
      for (int e = 0; e < 8; e++) {
        a0[e] = f2bf(kf[e] * Pt[47 - tl][col0 + e]);
        a1[e] = f2bf(kf[8 + e] * Pt[47 - tl][col0 + 8 + e]);
      }
      *(u16x8*)&KhX[(80 + row) * 72 + col0] = a0; *(u16x8*)&KhX[(80 + row) * 72 + col0 + 8] = a1;
    }
  }
  __syncthreads();

  {
    const int jj = tid & 63, s0 = (tid >> 6) * 16;
    #pragma unroll
    for (int ds = 0; ds < 16; ds += 2) {
      u32 pk = ((u32)vA[(s0 + ds + 1) * 72 + jj] << 16) | vA[(s0 + ds) * 72 + jj];
      *(u32*)&Vt[jj * 72 + s0 + ds] = pk;
    }
  }
  __syncthreads();

  u16* aB = vA;
  {
    const int pr[6] = {1, 2, 3, 2, 3, 3};
    const int qr[6] = {0, 1, 2, 0, 1, 0};
    const int dr[6] = {0, 0, 0, 1, 1, 2};
    const int lr = lane & 15, kq = lane >> 4;
    for (int pi = w; pi < 6; pi += 4) {
      const int p = pr[pi], q = qr[pi], d = dr[pi];
      const int kbase = (d == 0) ? q * 16 : (d == 1) ? 48 + q * 16 : 80 + q * 16;
      f32x4 aacc = {};
      #pragma unroll
      for (int kf2 = 0; kf2 < 2; kf2++) {
        bf16x8 af = *(const bf16x8*)&Rh[(p * 16 + lr) * 72 + kf2 * 32 + kq * 8];
        bf16x8 bf_ = *(const bf16x8*)&KhX[(kbase + lr) * 72 + kf2 * 32 + kq * 8];
        aacc = __builtin_amdgcn_mfma_f32_16x16x32_bf16(af, bf_, aacc, 0, 0, 0);
      }
      #pragma unroll
      for (int reg = 0; reg < 4; reg++) {
        aB[(p * 16 + kq * 4 + reg) * 72 + q * 16 + lr] = f2bf(aacc[reg]);
        aB[(q * 16 + kq * 4 + reg) * 72 + p * 16 + lr] = 0;
      }
    }
    for (int e = lane; e < 256; e += 64) {
      const int tl2 = e >> 4, sl = e & 15;
      float a = 0.f;
      if (sl <= tl2) {
        const u16* rp = &rB[(w * 16 + tl2) * 72];
        const u16* kp = &kB[(w * 16 + sl) * 72];
        const float* pp = (sl == tl2) ? uL : &Pt[tl2 - 1 - sl][0];
        #pragma unroll
        for (int i0 = 0; i0 < 64; i0 += 4) {
          u16x4 ra = *(const u16x4*)(rp + i0);
          u16x4 ka = *(const u16x4*)(kp + i0);
          f32x4 pa = *(const f32x4*)(pp + i0);
          #pragma unroll
          for (int di = 0; di < 4; di++)
            a = fmaf(bf2f(ra[di]) * bf2f(ka[di]), pa[di], a);
        }
      }
      aB[(w * 16 + tl2) * 72 + w * 16 + sl] = f2bf(a);
    }
  }
  __syncthreads();

  u16* Ktt = KhX;
  {
    const int ii = tid & 63, s0 = (tid >> 6) * 16;
    #pragma unroll
    for (int ds = 0; ds < 16; ds += 2) {
      float v0 = bf2f(kB[(s0 + ds) * 72 + ii]) * Pt[63 - (s0 + ds)][ii];
      float v1 = bf2f(kB[(s0 + ds + 1) * 72 + ii]) * Pt[63 - (s0 + ds + 1)][ii];
      u32 pk = ((u32)f2bf(v1) << 16) | f2bf(v0);
      *(u32*)&Ktt[ii * 72 + s0 + ds] = pk;
    }
  }
  __syncthreads();

  const int lr = lane & 15, kq = lane >> 4;
  {
    f32x4 yac[4] = {};
    #pragma unroll
    for (int kf2 = 0; kf2 < 2; kf2++) {
      bf16x8 af = *(const bf16x8*)&aB[(w * 16 + lr) * 72 + kf2 * 32 + kq * 8];
      #pragma unroll
      for (int nf = 0; nf < 4; nf++) {
        bf16x8 bf_ = *(const bf16x8*)&Vt[(nf * 16 + lr) * 72 + kf2 * 32 + kq * 8];
        yac[nf] = __builtin_amdgcn_mfma_f32_16x16x32_bf16(af, bf_, yac[nf], 0, 0, 0);
      }
    }
    float* Yp = Yb + (size_t)bid * 4096;
    #pragma unroll
    for (int nf = 0; nf < 4; nf++)
      #pragma unroll
      for (int reg = 0; reg < 4; reg++)
        Yp[(w * 16 + kq * 4 + reg) * 64 + nf * 16 + lr] = yac[nf][reg];

    f32x4 dac[4] = {};
    #pragma unroll
    for (int kf2 = 0; kf2 < 2; kf2++) {
      bf16x8 af = *(const bf16x8*)&Ktt[(w * 16 + lr) * 72 + kf2 * 32 + kq * 8];
      #pragma unroll
      for (int nf = 0; nf < 4; nf++) {
        bf16x8 bf_ = *(const bf16x8*)&Vt[(nf * 16 + lr) * 72 + kf2 * 32 + kq * 8];
        dac[nf] = __builtin_amdgcn_mfma_f32_16x16x32_bf16(af, bf_, dac[nf], 0, 0, 0);
      }
    }
    float* Dp = Db + (size_t)bid * 4096;
    #pragma unroll
    for (int nf = 0; nf < 4; nf++)
      #pragma unroll
      for (int reg = 0; reg < 4; reg++)
        Dp[(w * 16 + kq * 4 + reg) * 64 + nf * 16 + lr] = dac[nf][reg];
  }
}

__global__ __launch_bounds__(256)
void wkv_scan(const float* __restrict__ s0g, const float* __restrict__ td,
              const float* __restrict__ Db, u16* __restrict__ Sbb,
              float* __restrict__ sout) {
  const int bh = blockIdx.x, h = bh & 31;
  const int tid = threadIdx.x;
  const int i = tid >> 2, j0 = (tid & 3) * 16;
  float d = __expf(td[h * 64 + i]);
  float w64 = exp2f(-1.4426950408889634f * d * 64.f);
  f32x4 S[4];
  const float* sp = s0g + ((size_t)bh * 64 + i) * 64 + j0;
  #pragma unroll
  for (int q = 0; q < 4; q++) S[q] = *(const f32x4*)(sp + q * 4);
  for (int c = 0; c < NCH; c++) {
    u16* op = Sbb + ((size_t)(bh * 16 + c)) * 4096 + i * 64 + j0;
    u16x8 o0, o1;
    #pragma unroll
    for (int e = 0; e < 4; e++) { o0[e] = f2bf(S[0][e]); o0[4 + e] = f2bf(S[1][e]);
                                  o1[e] = f2bf(S[2][e]); o1[4 + e] = f2bf(S[3][e]); }
    *(u16x8*)op = o0; *(u16x8*)(op + 8) = o1;
    const float* dp = Db + ((size_t)(bh * 16 + c)) * 4096 + i * 64 + j0;
    #pragma unroll
    for (int q = 0; q < 4; q++) {
      f32x4 dv = *(const f32x4*)(dp + q * 4);
      #pragma unroll
      for (int e = 0; e < 4; e++) S[q][e] = fmaf(w64, S[q][e], dv[e]);
    }
  }
  float* fo = sout + ((size_t)bh * 64 + i) * 64 + j0;
  #pragma unroll
  for (int q = 0; q < 4; q++) *(f32x4*)(fo + q * 4) = S[q];
}

__global__ __launch_bounds__(256)
void wkv_post(const u16* __restrict__ Rtb, const u16* __restrict__ Sbb,
              const float* __restrict__ Yb, const u16* __restrict__ g,
              const float* __restrict__ gnw, const float* __restrict__ gnb,
              u16* __restrict__ xo) {
  __shared__ u16 Rt[64 * 72];
  __shared__ u16 St[64 * 72];
  __shared__ u16 xoL[64 * 72];
  const int tid = threadIdx.x, bid = blockIdx.x;
  const int bh = bid >> 4, c = bid & 15;
  const int b = bh >> 5, h = bh & 31;
  const int lane = tid & 63, w = tid >> 6;
  const int row = tid >> 2, col0 = (tid & 3) * 16;

  {
    const u16* rp = Rtb + (size_t)bid * 4096 + row * 64 + col0;
    u16x8 a0 = *(const u16x8*)rp, a1 = *(const u16x8*)(rp + 8);
    *(u16x8*)&Rt[row * 72 + col0] = a0; *(u16x8*)&Rt[row * 72 + col0 + 8] = a1;
  }
  {
    const u16* sp = Sbb + ((size_t)(bh * 16 + c)) * 4096 + row * 64 + col0;
    u16x8 s0 = *(const u16x8*)sp, s1 = *(const u16x8*)(sp + 8);
    #pragma unroll
    for (int e = 0; e < 8; e++) {
      St[(col0 + e) * 72 + row] = s0[e];
      St[(col0 + 8 + e) * 72 + row] = s1[e];
    }
  }
  const int lr = lane & 15, kq = lane >> 4;
  f32x4 acc[4];
  {
    const float* Yp = Yb + (size_t)bid * 4096;
    #pragma unroll
    for (int nf = 0; nf < 4; nf++)
      #pragma unroll
      for (int reg = 0; reg < 4; reg++)
        acc[nf][reg] = Yp[(w * 16 + kq * 4 + reg) * 64 + nf * 16 + lr];
  }
  __syncthreads();
  #pragma unroll
  for (int kf2 = 0; kf2 < 2; kf2++) {
    bf16x8 af = *(const bf16x8*)&Rt[(w * 16 + lr) * 72 + kf2 * 32 + kq * 8];
    #pragma unroll
    for (int nf = 0; nf < 4; nf++) {
      bf16x8 bf_ = *(const bf16x8*)&St[(nf * 16 + lr) * 72 + kf2 * 32 + kq * 8];
      acc[nf] = __builtin_amdgcn_mfma_f32_16x16x32_bf16(af, bf_, acc[nf], 0, 0, 0);
    }
  }
  #pragma unroll
  for (int reg = 0; reg < 4; reg++) {
    float s = 0.f, ss = 0.f;
    #pragma unroll
    for (int nf = 0; nf < 4; nf++) {
      float z = acc[nf][reg] * 0.125f;
      s += z; ss += z * z;
    }
    #pragma unroll
    for (int m = 1; m < 16; m <<= 1) { s += __shfl_xor(s, m); ss += __shfl_xor(ss, m); }
    float mean = s * (1.f / 64.f);
    float var = ss * (1.f / 64.f) - mean * mean;
    float inv = rsqrtf(var + 1e-5f);
    const int tau = w * 16 + kq * 4 + reg;
    #pragma unroll
    for (int nf = 0; nf < 4; nf++) {
      const int col = nf * 16 + lr;
      float z = acc[nf][reg] * 0.125f;
      float zn = (z - mean) * inv * gnw[h * 64 + col] + gnb[h * 64 + col];
      float gv = bf2f(g[((size_t)b * Tt + c * 64 + tau) * Cc + h * 64 + col]);
      xoL[tau * 72 + col] = f2bf(zn * gv);
    }
  }
  __syncthreads();
  {
    u16x8 o0 = *(const u16x8*)&xoL[row * 72 + col0];
    u16x8 o1 = *(const u16x8*)&xoL[row * 72 + col0 + 8];
    u16* xop = xo + ((size_t)b * Tt + c * 64 + row) * Cc + h * 64 + col0;
    *(u16x8*)xop = o0; *(u16x8*)(xop + 8) = o1;
  }
}

// ---------- orchestration ----------
extern "C" void kernel_launch(void* const* d_in, const int* in_sizes, int n_in,
                              void* d_out, int out_size, void* d_ws, size_t ws_size,
                              hipStream_t stream) {
  const float* x         = (const float*)d_in[0];
  const float* att_shift = (const float*)d_in[1];
  const float* wkv0      = (const float*)d_in[2];
  const float* ffn_shift = (const float*)d_in[3];
  const float* ln1w = (const float*)d_in[4];
  const float* ln1b = (const float*)d_in[5];
  const float* ln2w = (const float*)d_in[6];
  const float* ln2b = (const float*)d_in[7];
  const float* mixk = (const float*)d_in[8];
  const float* mixv = (const float*)d_in[9];
  const float* mixr = (const float*)d_in[10];
  const float* mixg = (const float*)d_in[11];
  const float* Wr = (const float*)d_in[12];
  const float* Wk = (const float*)d_in[13];
  const float* Wv = (const float*)d_in[14];
  const float* Wg = (const float*)d_in[15];
  const float* Wo = (const float*)d_in[16];
  const float* td = (const float*)d_in[17];
  const float* tf = (const float*)d_in[18];
  const float* gnw = (const float*)d_in[19];
  const float* gnb = (const float*)d_in[20];
  const float* cmk = (const float*)d_in[21];
  const float* cmr = (const float*)d_in[22];
  const float* Wck = (const float*)d_in[23];
  const float* Wcr = (const float*)d_in[24];
  const float* Wcv = (const float*)d_in[25];

  constexpr size_t SZ_CC = (size_t)Cc * Cc * 2;
  constexpr size_t SZ_CF = (size_t)Cc * FF * 2;
  constexpr size_t SZ_AB = (size_t)BT * Cc * 2;
  constexpr size_t O_W   = 0;
  constexpr size_t O_R1  = 6 * SZ_CC + 2 * SZ_CF;
  constexpr size_t R1_SZ = 4 * SZ_AB;
  constexpr size_t O_R2  = O_R1 + R1_SZ;
  constexpr size_t R2_SZ = 3 * SZ_AB;
  constexpr size_t O_R3  = O_R2 + R2_SZ;
  constexpr size_t WS_NEED = O_R3 + SZ_AB;

  if (ws_size < WS_NEED) return;

  char* ws = (char*)d_ws;
  u16* WrT  = (u16*)(ws + O_W);
  u16* WkT  = (u16*)(ws + O_W + 1 * SZ_CC);
  u16* WvT  = (u16*)(ws + O_W + 2 * SZ_CC);
  u16* WgT  = (u16*)(ws + O_W + 3 * SZ_CC);
  u16* WoT  = (u16*)(ws + O_W + 4 * SZ_CC);
  u16* WcrT = (u16*)(ws + O_W + 5 * SZ_CC);
  u16* WckT = (u16*)(ws + O_W + 6 * SZ_CC);
  u16* WcvT = (u16*)(ws + O_W + 6 * SZ_CC + SZ_CF);

  u16*   xk  = (u16*)(ws + O_R1);
  u16*   xv  = (u16*)(ws + O_R1 + SZ_AB);
  u16*   xr  = (u16*)(ws + O_R1 + 2 * SZ_AB);
  u16*   xg  = (u16*)(ws + O_R1 + 3 * SZ_AB);
  float* Yb  = (float*)(ws + O_R1);
  u16*   Rtb = (u16*)(ws + O_R1 + 2 * SZ_AB);
  u16*   Sbb = (u16*)(ws + O_R1 + 3 * SZ_AB);
  u16*   kk  = (u16*)(ws + O_R1);
  u16*   rb  = (u16*)(ws + O_R2);
  u16*   kb  = (u16*)(ws + O_R2 + SZ_AB);
  u16*   vb  = (u16*)(ws + O_R2 + 2 * SZ_AB);
  u16*   xo  = (u16*)(ws + O_R2);
  u16*   xck = (u16*)(ws + O_R2 + SZ_AB);
  u16*   xcr = (u16*)(ws + O_R2 + 2 * SZ_AB);
  float* kv  = (float*)(ws + O_R2);
  u16*   gbuf = (u16*)(ws + O_R3);

  float* out      = (float*)d_out;
  float* x1_last  = out + (size_t)BT * Cc;
  float* wkv_out  = x1_last + (size_t)Bb * Cc;
  float* x2_last  = wkv_out + (size_t)Bb * Hh * Nd * Nd;
  float* Db       = out;  // free until Wo-gemm; scan consumes it first

  transpose_to_bf16<<<dim3(64, 64), 256, 0, stream>>>(Wr, WrT, Cc, Cc);
  transpose_to_bf16<<<dim3(64, 64), 256, 0, stream>>>(Wk, WkT, Cc, Cc);
  transpose_to_bf16<<<dim3(64, 64), 256, 0, stream>>>(Wv, WvT, Cc, Cc);
  transpose_to_bf16<<<dim3(64, 64), 256, 0, stream>>>(Wg, WgT, Cc, Cc);
  transpose_to_bf16<<<dim3(64, 64), 256, 0, stream>>>(Wo, WoT, Cc, Cc);
  transpose_to_bf16<<<dim3(64, 64), 256, 0, stream>>>(Wcr, WcrT, Cc, Cc);
  transpose_to_bf16<<<dim3(224, 64), 256, 0, stream>>>(Wck, WckT, Cc, FF);
  transpose_to_bf16<<<dim3(64, 224), 256, 0, stream>>>(Wcv, WcvT, FF, Cc);

  ln_mix4<<<BT, 256, 0, stream>>>(x, att_shift, ln1w, ln1b,
                                  mixk, mixv, mixr, mixg, xk, xv, xr, xg, x1_last);
  gemm256_proj<<<dim3(8, 16, 4), 512, 0, stream>>>(xr, xk, xv, xg,
                                                   WrT, WkT, WvT, WgT,
                                                   rb, kb, vb, gbuf);
  wkv_pre<<<Bb * Hh * NCH, 256, 0, stream>>>(rb, kb, vb, td, tf, Yb, Db, Rtb);
  wkv_scan<<<Bb * Hh, 256, 0, stream>>>(wkv0, td, Db, Sbb, wkv_out);
  wkv_post<<<Bb * Hh * NCH, 256, 0, stream>>>(Rtb, Sbb, Yb, gbuf, gnw, gnb, xo);
  gemm256<4><<<dim3(8, 16), 512, 0, stream>>>(xo, WoT, Cc, Cc, out, nullptr, x, nullptr);
  ln_mix2<<<BT, 256, 0, stream>>>(out, ffn_shift, ln2w, ln2b, cmk, cmr, xck, xcr, x2_last);
  gemm256<3><<<dim3(28, 16), 512, 0, stream>>>(xck, WckT, FF, Cc, nullptr, kk, nullptr, nullptr);
  gemm256<0><<<dim3(8, 16), 512, 0, stream>>>(kk, WcvT, Cc, FF, kv, nullptr, nullptr, nullptr);
  gemm256<5><<<dim3(8, 16), 512, 0, stream>>>(xcr, WcrT, Cc, Cc, out, nullptr, out, kv);

  (void)in_sizes; (void)n_in; (void)out_size;
}

// Round 6
// 735.255 us; speedup vs baseline: 1.9326x; 1.1008x over previous
//
#include <hip/hip_runtime.h>
#include <cstdint>
#include <cstddef>

typedef unsigned short u16;
typedef unsigned int u32;
typedef short bf16x8 __attribute__((ext_vector_type(8)));
typedef unsigned short u16x4 __attribute__((ext_vector_type(4)));
typedef unsigned short u16x8 __attribute__((ext_vector_type(8)));
typedef float f32x4 __attribute__((ext_vector_type(4)));

#define DEV __device__ __forceinline__

// ---------- constants ----------
constexpr int Bb = 4, Tt = 1024, Cc = 2048, Hh = 32, Nd = 64, FF = 7168;
constexpr int BT = Bb * Tt; // 4096
constexpr int NCH = 16;     // chunks of 64

// ---------- helpers ----------
DEV u16 f2bf(float f) {
  union { float f; unsigned u; } un; un.f = f;
  unsigned r = un.u + 0x7FFFu + ((un.u >> 16) & 1u);
  return (u16)(r >> 16);
}
DEV float bf2f(u16 h) {
  union { unsigned u; float f; } un; un.u = ((unsigned)h) << 16;
  return un.f;
}
DEV void gll16(const u16* gp, u16* lp) {
  __builtin_amdgcn_global_load_lds(
      (const __attribute__((address_space(1))) unsigned int*)gp,
      (__attribute__((address_space(3))) unsigned int*)lp,
      16, 0, 0);
}

// ---------- transpose + f32->bf16: W[Kk][Nn] -> Wt[Nn][Kk] ----------
DEV void transp_body(const float* __restrict__ W, u16* __restrict__ Wt,
                     int Kk, int Nn, float (*tile)[33]) {
  int n0 = blockIdx.x * 32, k0 = blockIdx.y * 32;
  int tx = threadIdx.x & 31, ty = threadIdx.x >> 5;
  #pragma unroll
  for (int r = 0; r < 32; r += 8)
    tile[r + ty][tx] = W[(size_t)(k0 + r + ty) * Nn + n0 + tx];
  __syncthreads();
  #pragma unroll
  for (int r = 0; r < 32; r += 8)
    Wt[(size_t)(n0 + r + ty) * Kk + k0 + tx] = f2bf(tile[tx][r + ty]);
}

__global__ void transpose_to_bf16(const float* __restrict__ W, u16* __restrict__ Wt,
                                  int Kk, int Nn) {
  __shared__ float tile[32][33];
  transp_body(W, Wt, Kk, Nn, tile);
}

// six CxC transposes batched over blockIdx.z
__global__ void transpose6_cc(const float* __restrict__ W0, const float* __restrict__ W1,
                              const float* __restrict__ W2, const float* __restrict__ W3,
                              const float* __restrict__ W4, const float* __restrict__ W5,
                              u16* __restrict__ T0, u16* __restrict__ T1,
                              u16* __restrict__ T2, u16* __restrict__ T3,
                              u16* __restrict__ T4, u16* __restrict__ T5) {
  __shared__ float tile[32][33];
  const int z = blockIdx.z;
  const float* W = (z == 0) ? W0 : (z == 1) ? W1 : (z == 2) ? W2 :
                   (z == 3) ? W3 : (z == 4) ? W4 : W5;
  u16* T = (z == 0) ? T0 : (z == 1) ? T1 : (z == 2) ? T2 :
           (z == 3) ? T3 : (z == 4) ? T4 : T5;
  transp_body(W, T, Cc, Cc, tile);
}

// ---------- block LayerNorm stats helper ----------
DEV void block_ln(const float* __restrict__ src, int tid, float* red,
                  float vals[8], float& mean, float& inv) {
  float s = 0.f, ss = 0.f;
  #pragma unroll
  for (int i = 0; i < 8; i++) {
    float t = src[tid + i * 256];
    vals[i] = t; s += t; ss += t * t;
  }
  #pragma unroll
  for (int m = 1; m < 64; m <<= 1) { s += __shfl_xor(s, m); ss += __shfl_xor(ss, m); }
  int lane = tid & 63, wv = tid >> 6;
  __syncthreads();
  if (lane == 0) { red[wv] = s; red[4 + wv] = ss; }
  __syncthreads();
  s = red[0] + red[1] + red[2] + red[3];
  ss = red[4] + red[5] + red[6] + red[7];
  mean = s * (1.f / Cc);
  float var = ss * (1.f / Cc) - mean * mean;
  inv = rsqrtf(var + 1e-5f);
}

// ---------- fused LN + 4-way mix ----------
__global__ __launch_bounds__(256)
void ln_mix4(const float* __restrict__ x, const float* __restrict__ shift,
             const float* __restrict__ w, const float* __restrict__ b,
             const float* __restrict__ mk, const float* __restrict__ mv,
             const float* __restrict__ mr, const float* __restrict__ mg,
             u16* __restrict__ xk, u16* __restrict__ xv,
             u16* __restrict__ xr, u16* __restrict__ xg,
             float* __restrict__ last) {
  int row = blockIdx.x;
  int t = row & (Tt - 1), bb = row >> 10;
  int tid = threadIdx.x;
  __shared__ float red[8];
  const float* cur = x + (size_t)row * Cc;
  float cv[8], pv[8], cm, ci, pm = 0.f, pi = 1.f;
  block_ln(cur, tid, red, cv, cm, ci);
  bool t0 = (t == 0);
  const float* prev = t0 ? (shift + (size_t)bb * Cc) : (cur - Cc);
  if (!t0) {
    block_ln(prev, tid, red, pv, pm, pi);
  } else {
    #pragma unroll
    for (int i = 0; i < 8; i++) pv[i] = prev[tid + i * 256];
  }
  size_t o = (size_t)row * Cc;
  bool isLast = (t == Tt - 1);
  #pragma unroll
  for (int i = 0; i < 8; i++) {
    int c = tid + i * 256;
    float xc = (cv[i] - cm) * ci * w[c] + b[c];
    float xp = t0 ? pv[i] : (pv[i] - pm) * pi * w[c] + b[c];
    xk[o + c] = f2bf(xp + mk[c] * (xc - xp));
    xv[o + c] = f2bf(xp + mv[c] * (xc - xp));
    xr[o + c] = f2bf(xp + mr[c] * (xc - xp));
    xg[o + c] = f2bf(xp + mg[c] * (xc - xp));
    if (isLast) last[(size_t)bb * Cc + c] = xc;
  }
}

// ---------- fused LN + 2-way mix ----------
__global__ __launch_bounds__(256)
void ln_mix2(const float* __restrict__ x, const float* __restrict__ shift,
             const float* __restrict__ w, const float* __restrict__ b,
             const float* __restrict__ ck, const float* __restrict__ cr,
             u16* __restrict__ xck, u16* __restrict__ xcr,
             float* __restrict__ last) {
  int row = blockIdx.x;
  int t = row & (Tt - 1), bb = row >> 10;
  int tid = threadIdx.x;
  __shared__ float red[8];
  const float* cur = x + (size_t)row * Cc;
  float cv[8], pv[8], cm, ci, pm = 0.f, pi = 1.f;
  block_ln(cur, tid, red, cv, cm, ci);
  bool t0 = (t == 0);
  const float* prev = t0 ? (shift + (size_t)bb * Cc) : (cur - Cc);
  if (!t0) {
    block_ln(prev, tid, red, pv, pm, pi);
  } else {
    #pragma unroll
    for (int i = 0; i < 8; i++) pv[i] = prev[tid + i * 256];
  }
  size_t o = (size_t)row * Cc;
  bool isLast = (t == Tt - 1);
  #pragma unroll
  for (int i = 0; i < 8; i++) {
    int c = tid + i * 256;
    float xc = (cv[i] - cm) * ci * w[c] + b[c];
    float xp = t0 ? pv[i] : (pv[i] - pm) * pi * w[c] + b[c];
    xck[o + c] = f2bf(xp + ck[c] * (xc - xp));
    xcr[o + c] = f2bf(xp + cr[c] * (xc - xp));
    if (isLast) last[(size_t)bb * Cc + c] = xc;
  }
}

// ================= 256xBN deep-pipelined GEMM (8-wave, BK=64) =================
// NB = number of 128-row B half-tiles (2 -> BN=256, 1 -> BN=128).
// LDS slots of 16KB: A: [0..3] (2 bufs x 2 halves); B: [4 .. 4+2*NB-1].
// Per phase: ds_read frags || stage one half-tile -> barrier -> MFMA -> barrier.
// vmcnt(4) once per K-tile (counted; 0 only in tail).

DEV int swzoff(int row, int off) {
  return (row << 7) +
         (off ^ ((((row >> 1) & 1) << 4) | (((row >> 2) & 1) << 5) | (((row >> 3) & 1) << 6)));
}

DEV void stage_half(const u16* __restrict__ gbase, int ldK, u16* slot, int tid) {
  #pragma unroll
  for (int c2 = 0; c2 < 2; c2++) {
    const int D = c2 * 8192 + tid * 16;   // linear dest byte within slot
    const int row = D >> 7;
    const int off = (D & 127) ^ ((((row >> 1) & 1) << 4) | (((row >> 2) & 1) << 5) | (((row >> 3) & 1) << 6));
    gll16(gbase + (size_t)row * ldK + (off >> 1), (u16*)((char*)slot + D));
  }
}

// EPI: 0=f32, 1=bf16 (+act: silu), 3=relu^2->bf16, 4=X1+val->f32, 5=X1+sigmoid(val)*X2->f32
template <int EPI, int NB>
DEV void g256_core(const u16* __restrict__ A, const u16* __restrict__ Bt,
                   int N, int K,
                   float* __restrict__ Co, u16* __restrict__ Cb,
                   const float* __restrict__ X1, const float* __restrict__ X2,
                   u16 (*lds)[8192], int m0, int n0, int act) {
  const int tid = threadIdx.x;
  const int w = tid >> 6, lane = tid & 63;
  const int l15 = lane & 15, l4 = lane >> 4;
  const int wm = (w & 3) * 64;
  const int wn = (w >> 2) * (NB * 64);
  const int ahalf = wm >> 7;
  const int arow0 = wm & 127;
  const int bhalf = (NB == 2) ? (w >> 2) : 0;
  const int nt = K >> 6;

  const u16* Ag = A + (size_t)m0 * K;
  const u16* Bg = Bt + (size_t)n0 * K;

  f32x4 acc[4][NB * 4] = {};
  bf16x8 a[4][2];

  // ---- prologue: tile0 A+B, tile1 A ----
  stage_half(Ag, K, lds[0], tid);
  stage_half(Ag + (size_t)128 * K, K, lds[1], tid);
  stage_half(Bg, K, lds[4], tid);
  if constexpr (NB == 2) stage_half(Bg + (size_t)128 * K, K, lds[5], tid);
  if (nt > 1) {
    stage_half(Ag + 64, K, lds[2], tid);
    stage_half(Ag + (size_t)128 * K + 64, K, lds[3], tid);
    asm volatile("s_waitcnt vmcnt(4)" ::: "memory");
  } else {
    asm volatile("s_waitcnt vmcnt(0)" ::: "memory");
  }
  asm volatile("s_barrier" ::: "memory");

  for (int t = 0; t < nt; t++) {
    const int buf = t & 1;
    const char* Aslot = (const char*)lds[buf * 2 + ahalf];
    const char* Bslot = (const char*)lds[4 + buf * NB + bhalf];

#define G256_PHASE(p)                                                                       \
    {                                                                                       \
      constexpr int nh = (p) >> 1, kh = (p) & 1;                                            \
      if constexpr ((p) < 2) {                                                              \
        _Pragma("unroll")                                                                   \
        for (int mf = 0; mf < 4; mf++) {                                                    \
          const int row = arow0 + mf * 16 + l15;                                            \
          a[mf][kh] = *(const bf16x8*)(Aslot + swzoff(row, kh * 64 + l4 * 16));             \
        }                                                                                   \
      }                                                                                     \
      bf16x8 bfr[2 * NB];                                                                   \
      _Pragma("unroll")                                                                     \
      for (int j = 0; j < 2 * NB; j++) {                                                    \
        const int row = (NB == 2 ? 0 : wn) + (nh * 2 * NB + j) * 16 + l15;                  \
        bfr[j] = *(const bf16x8*)(Bslot + swzoff(row, kh * 64 + l4 * 16));                  \
      }                                                                                     \
      if constexpr ((p) == 0) {                                                             \
        if (t + 1 < nt) stage_half(Bg + (size_t)(t + 1) * 64, K,                            \
                                   lds[4 + ((t + 1) & 1) * NB], tid);                       \
      } else if constexpr ((p) == 1) {                                                      \
        if constexpr (NB == 2) {                                                            \
          if (t + 1 < nt) stage_half(Bg + (size_t)128 * K + (size_t)(t + 1) * 64, K,        \
                                     lds[4 + ((t + 1) & 1) * NB + 1], tid);                 \
        }                                                                                   \
      } else if constexpr ((p) == 2) {                                                      \
        if (t + 2 < nt) stage_half(Ag + (size_t)(t + 2) * 64, K, lds[buf << 1], tid);       \
      } else {                                                                              \
        if (t + 2 < nt) stage_half(Ag + (size_t)128 * K + (size_t)(t + 2) * 64, K,          \
                                   lds[(buf << 1) + 1], tid);                               \
      }                                                                                     \
      asm volatile("s_barrier" ::: "memory");                                               \
      __builtin_amdgcn_s_setprio(1);                                                       \
      _Pragma("unroll")                                                                     \
      for (int mf = 0; mf < 4; mf++)                                                        \
        _Pragma("unroll")                                                                   \
        for (int j = 0; j < 2 * NB; j++)                                                    \
          acc[mf][nh * 2 * NB + j] = __builtin_amdgcn_mfma_f32_16x16x32_bf16(               \
              a[mf][kh], bfr[j], acc[mf][nh * 2 * NB + j], 0, 0, 0);                        \
      __builtin_amdgcn_s_setprio(0);                                                       \
      if constexpr ((p) == 3) {                                                             \
        if (t + 2 < nt) asm volatile("s_waitcnt vmcnt(4)" ::: "memory");                    \
        else            asm volatile("s_waitcnt vmcnt(0)" ::: "memory");                    \
      }                                                                                     \
      asm volatile("s_barrier" ::: "memory");                                               \
    }

    G256_PHASE(0)
    G256_PHASE(1)
    G256_PHASE(2)
    G256_PHASE(3)
#undef G256_PHASE
  }

  // ---- epilogue ----
  #pragma unroll
  for (int mf = 0; mf < 4; mf++) {
    #pragma unroll
    for (int reg = 0; reg < 4; reg++) {
      const int gr = m0 + wm + mf * 16 + l4 * 4 + reg;
      const size_t ro = (size_t)gr * N;
      #pragma unroll
      for (int nf = 0; nf < NB * 4; nf++) {
        const int gc = n0 + wn + nf * 16 + l15;
        float val = acc[mf][nf][reg];
        if constexpr (EPI == 0) {
          Co[ro + gc] = val;
        } else if constexpr (EPI == 1) {
          if (act) val = val / (1.f + __expf(-val));
          Cb[ro + gc] = f2bf(val);
        } else if constexpr (EPI == 3) {
          float tr = fmaxf(val, 0.f);
          Cb[ro + gc] = f2bf(tr * tr);
        } else if constexpr (EPI == 4) {
          Co[ro + gc] = X1[ro + gc] + val;
        } else {
          float s = 1.f / (1.f + __expf(-val));
          Co[ro + gc] = fmaf(s, X2[ro + gc], X1[ro + gc]);
        }
      }
    }
  }
}

template <int EPI>
__global__ __launch_bounds__(512, 2)
void gemm256(const u16* __restrict__ A, const u16* __restrict__ Bt,
             int N, int K,
             float* __restrict__ Co, u16* __restrict__ Cb,
             const float* __restrict__ X1, const float* __restrict__ X2) {
  __shared__ __align__(16) u16 lds[8][8192];
  g256_core<EPI, 2>(A, Bt, N, K, Co, Cb, X1, X2, lds, blockIdx.y * 256, blockIdx.x * 256, 0);
}

// BN=128 variant: 256x128 tile, 6 LDS slots (96KB), grid.x = N/128
template <int EPI>
__global__ __launch_bounds__(512, 2)
void gemm128n(const u16* __restrict__ A, const u16* __restrict__ Bt,
              int N, int K,
              float* __restrict__ Co, u16* __restrict__ Cb,
              const float* __restrict__ X1, const float* __restrict__ X2) {
  __shared__ __align__(16) u16 lds[6][8192];
  g256_core<EPI, 1>(A, Bt, N, K, Co, Cb, X1, X2, lds, blockIdx.y * 256, blockIdx.x * 128, 0);
}

__global__ __launch_bounds__(512, 2)
void gemm256_proj(const u16* __restrict__ A0, const u16* __restrict__ A1,
                  const u16* __restrict__ A2, const u16* __restrict__ A3,
                  const u16* __restrict__ B0, const u16* __restrict__ B1,
                  const u16* __restrict__ B2, const u16* __restrict__ B3,
                  u16* __restrict__ C0, u16* __restrict__ C1,
                  u16* __restrict__ C2, u16* __restrict__ C3) {
  __shared__ __align__(16) u16 lds[8][8192];
  const int z = blockIdx.z;
  const u16* A = (z == 0) ? A0 : (z == 1) ? A1 : (z == 2) ? A2 : A3;
  const u16* Bt = (z == 0) ? B0 : (z == 1) ? B1 : (z == 2) ? B2 : B3;
  u16* Cb = (z == 0) ? C0 : (z == 1) ? C1 : (z == 2) ? C2 : C3;
  g256_core<1, 2>(A, Bt, Cc, Cc, nullptr, Cb, nullptr, nullptr, lds,
                  blockIdx.y * 256, blockIdx.x * 256, z == 3);
}

// ======================= chunked WKV : three kernels =======================
__global__ __launch_bounds__(256)
void wkv_pre(const u16* __restrict__ rg, const u16* __restrict__ kg,
             const u16* __restrict__ vg, const float* __restrict__ td,
             const float* __restrict__ tf,
             float* __restrict__ Yb, float* __restrict__ Db,
             u16* __restrict__ Rtb) {
  __shared__ float Pt[64][68];
  __shared__ float uL[64];
  __shared__ u16 rB[64 * 72];
  __shared__ u16 kB[64 * 72];
  __shared__ u16 Rh[64 * 72];
  __shared__ u16 KhX[96 * 72];
  __shared__ u16 vA[64 * 72];
  __shared__ u16 Vt[64 * 72];

  const int tid = threadIdx.x, bid = blockIdx.x;
  const int bh = bid >> 4, c = bid & 15;
  const int b = bh >> 5, h = bh & 31;
  const int lane = tid & 63, w = tid >> 6;

  {
    int i = tid & 63;
    float d = __expf(td[h * 64 + i]);
    float c1 = -1.4426950408889634f * d;
    int e0 = (tid >> 6) * 16;
    #pragma unroll
    for (int e = 0; e < 16; e++) Pt[e0 + e][i] = exp2f(c1 * (float)(e0 + e));
    if (tid < 64) uL[tid] = tf[h * 64 + tid];
  }
  __syncthreads();

  const int row = tid >> 2, col0 = (tid & 3) * 16;
  const int tl = row & 15;
  {
    size_t gro = ((size_t)b * Tt + c * 64 + row) * Cc + h * 64 + col0;
    u16x8 rv0 = *(const u16x8*)(rg + gro);
    u16x8 rv1 = *(const u16x8*)(rg + gro + 8);
    u16x8 kv0 = *(const u16x8*)(kg + gro);
    u16x8 kv1 = *(const u16x8*)(kg + gro + 8);
    u16x8 vv0 = *(const u16x8*)(vg + gro);
    u16x8 vv1 = *(const u16x8*)(vg + gro + 8);
    *(u16x8*)&rB[row * 72 + col0] = rv0; *(u16x8*)&rB[row * 72 + col0 + 8] = rv1;
    *(u16x8*)&kB[row * 72 + col0] = kv0; *(u16x8*)&kB[row * 72 + col0 + 8] = kv1;
    *(u16x8*)&vA[row * 72 + col0] = vv0; *(u16x8*)&vA[row * 72 + col0 + 8] = vv1;
    float rf[16], kf[16];
    #pragma unroll
    for (int e = 0; e < 8; e++) { rf[e] = bf2f(rv0[e]); rf[8 + e] = bf2f(rv1[e]); }
    #pragma unroll
    for (int e = 0; e < 8; e++) { kf[e] = bf2f(kv0[e]); kf[8 + e] = bf2f(kv1[e]); }
    u16x8 o0, o1, t0_, t1_;
    #pragma unroll
    for (int e = 0; e < 8; e++) {
      o0[e] = f2bf(rf[e] * Pt[tl][col0 + e]);
      o1[e] = f2bf(rf[8 + e] * Pt[tl][col0 + 8 + e]);
      t0_[e] = f2bf(rf[e] * Pt[row][col0 + e]);
      t1_[e] = f2bf(rf[8 + e] * Pt[row][col0 + 8 + e]);
    }
    *(u16x8*)&Rh[row * 72 + col0] = o0; *(u16x8*)&Rh[row * 72 + col0 + 8] = o1;
    u16* rtp = Rtb + (size_t)bid * 4096 + row * 64 + col0;
    *(u16x8*)rtp = t0_; *(u16x8*)(rtp + 8) = t1_;
    if (row < 48) {
      u16x8 a0, a1;
      #pragma unroll
      for (int e = 0; e < 8; e++) {
        a0[e] = f2bf(kf[e] * Pt[15 - tl][col0 + e]);
        a1[e] = f2bf(kf[8 + e] * Pt[15 - tl][col0 + 8 + e]);
      }
      *(u16x8*)&KhX[row * 72 + col0] = a0; *(u16x8*)&KhX[row * 72 + col0 + 8] = a1;
    }
    if (row < 32) {
      u16x8 a0, a1;
      #pragma unroll
      for (int e = 0; e < 8; e++) {
        a0[e] = f2bf(kf[e] * Pt[31 - tl][col0 + e]);
        a1[e] = f2bf(kf[8 + e] * Pt[31 - tl][col0 + 8 + e]);
      }
      *(u16x8*)&KhX[(48 + row) * 72 + col0] = a0; *(u16x8*)&KhX[(48 + row) * 72 + col0 + 8] = a1;
    }
    if (row < 16) {
      u16x8 a0, a1;
      #pragma unroll
      for (int e = 0; e < 8; e++) {
        a0[e] = f2bf(kf[e] * Pt[47 - tl][col0 + e]);
        a1[e] = f2bf(kf[8 + e] * Pt[47 - tl][col0 + 8 + e]);
      }
      *(u16x8*)&KhX[(80 + row) * 72 + col0] = a0; *(u16x8*)&KhX[(80 + row) * 72 + col0 + 8] = a1;
    }
  }
  __syncthreads();

  {
    const int jj = tid & 63, s0 = (tid >> 6) * 16;
    #pragma unroll
    for (int ds = 0; ds < 16; ds += 2) {
      u32 pk = ((u32)vA[(s0 + ds + 1) * 72 + jj] << 16) | vA[(s0 + ds) * 72 + jj];
      *(u32*)&Vt[jj * 72 + s0 + ds] = pk;
    }
  }
  __syncthreads();

  u16* aB = vA;
  {
    const int pr[6] = {1, 2, 3, 2, 3, 3};
    const int qr[6] = {0, 1, 2, 0, 1, 0};
    const int dr[6] = {0, 0, 0, 1, 1, 2};
    const int lr = lane & 15, kq = lane >> 4;
    for (int pi = w; pi < 6; pi += 4) {
      const int p = pr[pi], q = qr[pi], d = dr[pi];
      const int kbase = (d == 0) ? q * 16 : (d == 1) ? 48 + q * 16 : 80 + q * 16;
      f32x4 aacc = {};
      #pragma unroll
      for (int kf2 = 0; kf2 < 2; kf2++) {
        bf16x8 af = *(const bf16x8*)&Rh[(p * 16 + lr) * 72 + kf2 * 32 + kq * 8];
        bf16x8 bf_ = *(const bf16x8*)&KhX[(kbase + lr) * 72 + kf2 * 32 + kq * 8];
        aacc = __builtin_amdgcn_mfma_f32_16x16x32_bf16(af, bf_, aacc, 0, 0, 0);
      }
      #pragma unroll
      for (int reg = 0; reg < 4; reg++) {
        aB[(p * 16 + kq * 4 + reg) * 72 + q * 16 + lr] = f2bf(aacc[reg]);
        aB[(q * 16 + kq * 4 + reg) * 72 + p * 16 + lr] = 0;
      }
    }
    for (int e = lane; e < 256; e += 64) {
      const int tl2 = e >> 4, sl = e & 15;
      float a = 0.f;
      if (sl <= tl2) {
        const u16* rp = &rB[(w * 16 + tl2) * 72];
        const u16* kp = &kB[(w * 16 + sl) * 72];
        const float* pp = (sl == tl2) ? uL : &Pt[tl2 - 1 - sl][0];
        #pragma unroll
        for (int i0 = 0; i0 < 64; i0 += 4) {
          u16x4 ra = *(const u16x4*)(rp + i0);
          u16x4 ka = *(const u16x4*)(kp + i0);
          f32x4 pa = *(const f32x4*)(pp + i0);
          #pragma unroll
          for (int di = 0; di < 4; di++)
            a = fmaf(bf2f(ra[di]) * bf2f(ka[di]), pa[di], a);
        }
      }
      aB[(w * 16 + tl2) * 72 + w * 16 + sl] = f2bf(a);
    }
  }
  __syncthreads();

  u16* Ktt = KhX;
  {
    const int ii = tid & 63, s0 = (tid >> 6) * 16;
    #pragma unroll
    for (int ds = 0; ds < 16; ds += 2) {
      float v0 = bf2f(kB[(s0 + ds) * 72 + ii]) * Pt[63 - (s0 + ds)][ii];
      float v1 = bf2f(kB[(s0 + ds + 1) * 72 + ii]) * Pt[63 - (s0 + ds + 1)][ii];
      u32 pk = ((u32)f2bf(v1) << 16) | f2bf(v0);
      *(u32*)&Ktt[ii * 72 + s0 + ds] = pk;
    }
  }
  __syncthreads();

  const int lr = lane & 15, kq = lane >> 4;
  {
    f32x4 yac[4] = {};
    #pragma unroll
    for (int kf2 = 0; kf2 < 2; kf2++) {
      bf16x8 af = *(const bf16x8*)&aB[(w * 16 + lr) * 72 + kf2 * 32 + kq * 8];
      #pragma unroll
      for (int nf = 0; nf < 4; nf++) {
        bf16x8 bf_ = *(const bf16x8*)&Vt[(nf * 16 + lr) * 72 + kf2 * 32 + kq * 8];
        yac[nf] = __builtin_amdgcn_mfma_f32_16x16x32_bf16(af, bf_, yac[nf], 0, 0, 0);
      }
    }
    float* Yp = Yb + (size_t)bid * 4096;
    #pragma unroll
    for (int nf = 0; nf < 4; nf++)
      #pragma unroll
      for (int reg = 0; reg < 4; reg++)
        Yp[(w * 16 + kq * 4 + reg) * 64 + nf * 16 + lr] = yac[nf][reg];

    f32x4 dac[4] = {};
    #pragma unroll
    for (int kf2 = 0; kf2 < 2; kf2++) {
      bf16x8 af = *(const bf16x8*)&Ktt[(w * 16 + lr) * 72 + kf2 * 32 + kq * 8];
      #pragma unroll
      for (int nf = 0; nf < 4; nf++) {
        bf16x8 bf_ = *(const bf16x8*)&Vt[(nf * 16 + lr) * 72 + kf2 * 32 + kq * 8];
        dac[nf] = __builtin_amdgcn_mfma_f32_16x16x32_bf16(af, bf_, dac[nf], 0, 0, 0);
      }
    }
    float* Dp = Db + (size_t)bid * 4096;
    #pragma unroll
    for (int nf = 0; nf < 4; nf++)
      #pragma unroll
      for (int reg = 0; reg < 4; reg++)
        Dp[(w * 16 + kq * 4 + reg) * 64 + nf * 16 + lr] = dac[nf][reg];
  }
}

__global__ __launch_bounds__(256)
void wkv_scan(const float* __restrict__ s0g, const float* __restrict__ td,
              const float* __restrict__ Db, u16* __restrict__ Sbb,
              float* __restrict__ sout) {
  const int bh = blockIdx.x, h = bh & 31;
  const int tid = threadIdx.x;
  const int i = tid >> 2, j0 = (tid & 3) * 16;
  float d = __expf(td[h * 64 + i]);
  float w64 = exp2f(-1.4426950408889634f * d * 64.f);
  f32x4 S[4];
  const float* sp = s0g + ((size_t)bh * 64 + i) * 64 + j0;
  #pragma unroll
  for (int q = 0; q < 4; q++) S[q] = *(const f32x4*)(sp + q * 4);
  for (int c = 0; c < NCH; c++) {
    u16* op = Sbb + ((size_t)(bh * 16 + c)) * 4096 + i * 64 + j0;
    u16x8 o0, o1;
    #pragma unroll
    for (int e = 0; e < 4; e++) { o0[e] = f2bf(S[0][e]); o0[4 + e] = f2bf(S[1][e]);
                                  o1[e] = f2bf(S[2][e]); o1[4 + e] = f2bf(S[3][e]); }
    *(u16x8*)op = o0; *(u16x8*)(op + 8) = o1;
    const float* dp = Db + ((size_t)(bh * 16 + c)) * 4096 + i * 64 + j0;
    #pragma unroll
    for (int q = 0; q < 4; q++) {
      f32x4 dv = *(const f32x4*)(dp + q * 4);
      #pragma unroll
      for (int e = 0; e < 4; e++) S[q][e] = fmaf(w64, S[q][e], dv[e]);
    }
  }
  float* fo = sout + ((size_t)bh * 64 + i) * 64 + j0;
  #pragma unroll
  for (int q = 0; q < 4; q++) *(f32x4*)(fo + q * 4) = S[q];
}

__global__ __launch_bounds__(256)
void wkv_post(const u16* __restrict__ Rtb, const u16* __restrict__ Sbb,
              const float* __restrict__ Yb, const u16* __restrict__ g,
              const float* __restrict__ gnw, const float* __restrict__ gnb,
              u16* __restrict__ xo) {
  __shared__ u16 Rt[64 * 72];
  __shared__ u16 St[64 * 72];
  __shared__ u16 xoL[64 * 72];
  const int tid = threadIdx.x, bid = blockIdx.x;
  const int bh = bid >> 4, c = bid & 15;
  const int b = bh >> 5, h = bh & 31;
  const int lane = tid & 63, w = tid >> 6;
  const int row = tid >> 2, col0 = (tid & 3) * 16;

  {
    const u16* rp = Rtb + (size_t)bid * 4096 + row * 64 + col0;
    u16x8 a0 = *(const u16x8*)rp, a1 = *(const u16x8*)(rp + 8);
    *(u16x8*)&Rt[row * 72 + col0] = a0; *(u16x8*)&Rt[row * 72 + col0 + 8] = a1;
  }
  {
    const u16* sp = Sbb + ((size_t)(bh * 16 + c)) * 4096 + row * 64 + col0;
    u16x8 s0 = *(const u16x8*)sp, s1 = *(const u16x8*)(sp + 8);
    #pragma unroll
    for (int e = 0; e < 8; e++) {
      St[(col0 + e) * 72 + row] = s0[e];
      St[(col0 + 8 + e) * 72 + row] = s1[e];
    }
  }
  const int lr = lane & 15, kq = lane >> 4;
  f32x4 acc[4];
  {
    const float* Yp = Yb + (size_t)bid * 4096;
    #pragma unroll
    for (int nf = 0; nf < 4; nf++)
      #pragma unroll
      for (int reg = 0; reg < 4; reg++)
        acc[nf][reg] = Yp[(w * 16 + kq * 4 + reg) * 64 + nf * 16 + lr];
  }
  __syncthreads();
  #pragma unroll
  for (int kf2 = 0; kf2 < 2; kf2++) {
    bf16x8 af = *(const bf16x8*)&Rt[(w * 16 + lr) * 72 + kf2 * 32 + kq * 8];
    #pragma unroll
    for (int nf = 0; nf < 4; nf++) {
      bf16x8 bf_ = *(const bf16x8*)&St[(nf * 16 + lr) * 72 + kf2 * 32 + kq * 8];
      acc[nf] = __builtin_amdgcn_mfma_f32_16x16x32_bf16(af, bf_, acc[nf], 0, 0, 0);
    }
  }
  #pragma unroll
  for (int reg = 0; reg < 4; reg++) {
    float s = 0.f, ss = 0.f;
    #pragma unroll
    for (int nf = 0; nf < 4; nf++) {
      float z = acc[nf][reg] * 0.125f;
      s += z; ss += z * z;
    }
    #pragma unroll
    for (int m = 1; m < 16; m <<= 1) { s += __shfl_xor(s, m); ss += __shfl_xor(ss, m); }
    float mean = s * (1.f / 64.f);
    float var = ss * (1.f / 64.f) - mean * mean;
    float inv = rsqrtf(var + 1e-5f);
    const int tau = w * 16 + kq * 4 + reg;
    #pragma unroll
    for (int nf = 0; nf < 4; nf++) {
      const int col = nf * 16 + lr;
      float z = acc[nf][reg] * 0.125f;
      float zn = (z - mean) * inv * gnw[h * 64 + col] + gnb[h * 64 + col];
      float gv = bf2f(g[((size_t)b * Tt + c * 64 + tau) * Cc + h * 64 + col]);
      xoL[tau * 72 + col] = f2bf(zn * gv);
    }
  }
  __syncthreads();
  {
    u16x8 o0 = *(const u16x8*)&xoL[row * 72 + col0];
    u16x8 o1 = *(const u16x8*)&xoL[row * 72 + col0 + 8];
    u16* xop = xo + ((size_t)b * Tt + c * 64 + row) * Cc + h * 64 + col0;
    *(u16x8*)xop = o0; *(u16x8*)(xop + 8) = o1;
  }
}

// ---------- orchestration ----------
extern "C" void kernel_launch(void* const* d_in, const int* in_sizes, int n_in,
                              void* d_out, int out_size, void* d_ws, size_t ws_size,
                              hipStream_t stream) {
  const float* x         = (const float*)d_in[0];
  const float* att_shift = (const float*)d_in[1];
  const float* wkv0      = (const float*)d_in[2];
  const float* ffn_shift = (const float*)d_in[3];
  const float* ln1w = (const float*)d_in[4];
  const float* ln1b = (const float*)d_in[5];
  const float* ln2w = (const float*)d_in[6];
  const float* ln2b = (const float*)d_in[7];
  const float* mixk = (const float*)d_in[8];
  const float* mixv = (const float*)d_in[9];
  const float* mixr = (const float*)d_in[10];
  const float* mixg = (const float*)d_in[11];
  const float* Wr = (const float*)d_in[12];
  const float* Wk = (const float*)d_in[13];
  const float* Wv = (const float*)d_in[14];
  const float* Wg = (const float*)d_in[15];
  const float* Wo = (const float*)d_in[16];
  const float* td = (const float*)d_in[17];
  const float* tf = (const float*)d_in[18];
  const float* gnw = (const float*)d_in[19];
  const float* gnb = (const float*)d_in[20];
  const float* cmk = (const float*)d_in[21];
  const float* cmr = (const float*)d_in[22];
  const float* Wck = (const float*)d_in[23];
  const float* Wcr = (const float*)d_in[24];
  const float* Wcv = (const float*)d_in[25];

  constexpr size_t SZ_CC = (size_t)Cc * Cc * 2;
  constexpr size_t SZ_CF = (size_t)Cc * FF * 2;
  constexpr size_t SZ_AB = (size_t)BT * Cc * 2;
  constexpr size_t O_W   = 0;
  constexpr size_t O_R1  = 6 * SZ_CC + 2 * SZ_CF;
  constexpr size_t R1_SZ = 4 * SZ_AB;
  constexpr size_t O_R2  = O_R1 + R1_SZ;
  constexpr size_t R2_SZ = 3 * SZ_AB;
  constexpr size_t O_R3  = O_R2 + R2_SZ;
  constexpr size_t WS_NEED = O_R3 + SZ_AB;

  if (ws_size < WS_NEED) return;

  char* ws = (char*)d_ws;
  u16* WrT  = (u16*)(ws + O_W);
  u16* WkT  = (u16*)(ws + O_W + 1 * SZ_CC);
  u16* WvT  = (u16*)(ws + O_W + 2 * SZ_CC);
  u16* WgT  = (u16*)(ws + O_W + 3 * SZ_CC);
  u16* WoT  = (u16*)(ws + O_W + 4 * SZ_CC);
  u16* WcrT = (u16*)(ws + O_W + 5 * SZ_CC);
  u16* WckT = (u16*)(ws + O_W + 6 * SZ_CC);
  u16* WcvT = (u16*)(ws + O_W + 6 * SZ_CC + SZ_CF);

  u16*   xk  = (u16*)(ws + O_R1);
  u16*   xv  = (u16*)(ws + O_R1 + SZ_AB);
  u16*   xr  = (u16*)(ws + O_R1 + 2 * SZ_AB);
  u16*   xg  = (u16*)(ws + O_R1 + 3 * SZ_AB);
  float* Yb  = (float*)(ws + O_R1);
  u16*   Rtb = (u16*)(ws + O_R1 + 2 * SZ_AB);
  u16*   Sbb = (u16*)(ws + O_R1 + 3 * SZ_AB);
  u16*   kk  = (u16*)(ws + O_R1);
  u16*   rb  = (u16*)(ws + O_R2);
  u16*   kb  = (u16*)(ws + O_R2 + SZ_AB);
  u16*   vb  = (u16*)(ws + O_R2 + 2 * SZ_AB);
  u16*   xo  = (u16*)(ws + O_R2);
  u16*   xck = (u16*)(ws + O_R2 + SZ_AB);
  u16*   xcr = (u16*)(ws + O_R2 + 2 * SZ_AB);
  float* kv  = (float*)(ws + O_R2);
  u16*   gbuf = (u16*)(ws + O_R3);

  float* out      = (float*)d_out;
  float* x1_last  = out + (size_t)BT * Cc;
  float* wkv_out  = x1_last + (size_t)Bb * Cc;
  float* x2_last  = wkv_out + (size_t)Bb * Hh * Nd * Nd;
  float* Db       = out;  // free until Wo-gemm; scan consumes it first

  transpose6_cc<<<dim3(64, 64, 6), 256, 0, stream>>>(Wr, Wk, Wv, Wg, Wo, Wcr,
                                                     WrT, WkT, WvT, WgT, WoT, WcrT);
  transpose_to_bf16<<<dim3(224, 64), 256, 0, stream>>>(Wck, WckT, Cc, FF);
  transpose_to_bf16<<<dim3(64, 224), 256, 0, stream>>>(Wcv, WcvT, FF, Cc);

  ln_mix4<<<BT, 256, 0, stream>>>(x, att_shift, ln1w, ln1b,
                                  mixk, mixv, mixr, mixg, xk, xv, xr, xg, x1_last);
  gemm256_proj<<<dim3(8, 16, 4), 512, 0, stream>>>(xr, xk, xv, xg,
                                                   WrT, WkT, WvT, WgT,
                                                   rb, kb, vb, gbuf);
  wkv_pre<<<Bb * Hh * NCH, 256, 0, stream>>>(rb, kb, vb, td, tf, Yb, Db, Rtb);
  wkv_scan<<<Bb * Hh, 256, 0, stream>>>(wkv0, td, Db, Sbb, wkv_out);
  wkv_post<<<Bb * Hh * NCH, 256, 0, stream>>>(Rtb, Sbb, Yb, gbuf, gnw, gnb, xo);
  gemm128n<4><<<dim3(16, 16), 512, 0, stream>>>(xo, WoT, Cc, Cc, out, nullptr, x, nullptr);
  ln_mix2<<<BT, 256, 0, stream>>>(out, ffn_shift, ln2w, ln2b, cmk, cmr, xck, xcr, x2_last);
  gemm256<3><<<dim3(28, 16), 512, 0, stream>>>(xck, WckT, FF, Cc, nullptr, kk, nullptr, nullptr);
  gemm128n<0><<<dim3(16, 16), 512, 0, stream>>>(kk, WcvT, Cc, FF, kv, nullptr, nullptr, nullptr);
  gemm128n<5><<<dim3(16, 16), 512, 0, stream>>>(xcr, WcrT, Cc, Cc, out, nullptr, out, kv);

  (void)in_sizes; (void)n_in; (void)out_size;
}

// Round 7
// 724.488 us; speedup vs baseline: 1.9613x; 1.0149x over previous
//
#include <hip/hip_runtime.h>
#include <cstdint>
#include <cstddef>

typedef unsigned short u16;
typedef unsigned int u32;
typedef short bf16x8 __attribute__((ext_vector_type(8)));
typedef unsigned short u16x4 __attribute__((ext_vector_type(4)));
typedef unsigned short u16x8 __attribute__((ext_vector_type(8)));
typedef float f32x4 __attribute__((ext_vector_type(4)));

#define DEV __device__ __forceinline__

// ---------- constants ----------
constexpr int Bb = 4, Tt = 1024, Cc = 2048, Hh = 32, Nd = 64, FF = 7168;
constexpr int BT = Bb * Tt; // 4096
constexpr int NCH = 16;     // chunks of 64

// ---------- helpers ----------
DEV u16 f2bf(float f) {
  union { float f; unsigned u; } un; un.f = f;
  unsigned r = un.u + 0x7FFFu + ((un.u >> 16) & 1u);
  return (u16)(r >> 16);
}
DEV float bf2f(u16 h) {
  union { unsigned u; float f; } un; un.u = ((unsigned)h) << 16;
  return un.f;
}
DEV void gll16(const u16* gp, u16* lp) {
  __builtin_amdgcn_global_load_lds(
      (const __attribute__((address_space(1))) unsigned int*)gp,
      (__attribute__((address_space(3))) unsigned int*)lp,
      16, 0, 0);
}
// XCD-bijective swizzle: final blockIdx f -> original tile id o, so each XCD
// (f%8) owns a CONTIGUOUS chunk of original tile order. Requires nwg%8==0.
DEV int xcd_swz(int f, int nwg) {
  int q = nwg >> 3;
  return (f & 7) * q + (f >> 3);
}

// ---------- transpose + f32->bf16: W[Kk][Nn] -> Wt[Nn][Kk] ----------
DEV void transp_body(const float* __restrict__ W, u16* __restrict__ Wt,
                     int Kk, int Nn, float (*tile)[33]) {
  int n0 = blockIdx.x * 32, k0 = blockIdx.y * 32;
  int tx = threadIdx.x & 31, ty = threadIdx.x >> 5;
  #pragma unroll
  for (int r = 0; r < 32; r += 8)
    tile[r + ty][tx] = W[(size_t)(k0 + r + ty) * Nn + n0 + tx];
  __syncthreads();
  #pragma unroll
  for (int r = 0; r < 32; r += 8)
    Wt[(size_t)(n0 + r + ty) * Kk + k0 + tx] = f2bf(tile[tx][r + ty]);
}

__global__ void transpose_to_bf16(const float* __restrict__ W, u16* __restrict__ Wt,
                                  int Kk, int Nn) {
  __shared__ float tile[32][33];
  transp_body(W, Wt, Kk, Nn, tile);
}

__global__ void transpose6_cc(const float* __restrict__ W0, const float* __restrict__ W1,
                              const float* __restrict__ W2, const float* __restrict__ W3,
                              const float* __restrict__ W4, const float* __restrict__ W5,
                              u16* __restrict__ T0, u16* __restrict__ T1,
                              u16* __restrict__ T2, u16* __restrict__ T3,
                              u16* __restrict__ T4, u16* __restrict__ T5) {
  __shared__ float tile[32][33];
  const int z = blockIdx.z;
  const float* W = (z == 0) ? W0 : (z == 1) ? W1 : (z == 2) ? W2 :
                   (z == 3) ? W3 : (z == 4) ? W4 : W5;
  u16* T = (z == 0) ? T0 : (z == 1) ? T1 : (z == 2) ? T2 :
           (z == 3) ? T3 : (z == 4) ? T4 : T5;
  transp_body(W, T, Cc, Cc, tile);
}

// ---------- block LayerNorm stats helper ----------
DEV void block_ln(const float* __restrict__ src, int tid, float* red,
                  float vals[8], float& mean, float& inv) {
  float s = 0.f, ss = 0.f;
  #pragma unroll
  for (int i = 0; i < 8; i++) {
    float t = src[tid + i * 256];
    vals[i] = t; s += t; ss += t * t;
  }
  #pragma unroll
  for (int m = 1; m < 64; m <<= 1) { s += __shfl_xor(s, m); ss += __shfl_xor(ss, m); }
  int lane = tid & 63, wv = tid >> 6;
  __syncthreads();
  if (lane == 0) { red[wv] = s; red[4 + wv] = ss; }
  __syncthreads();
  s = red[0] + red[1] + red[2] + red[3];
  ss = red[4] + red[5] + red[6] + red[7];
  mean = s * (1.f / Cc);
  float var = ss * (1.f / Cc) - mean * mean;
  inv = rsqrtf(var + 1e-5f);
}

// ---------- fused LN + 4-way mix ----------
__global__ __launch_bounds__(256)
void ln_mix4(const float* __restrict__ x, const float* __restrict__ shift,
             const float* __restrict__ w, const float* __restrict__ b,
             const float* __restrict__ mk, const float* __restrict__ mv,
             const float* __restrict__ mr, const float* __restrict__ mg,
             u16* __restrict__ xk, u16* __restrict__ xv,
             u16* __restrict__ xr, u16* __restrict__ xg,
             float* __restrict__ last) {
  int row = blockIdx.x;
  int t = row & (Tt - 1), bb = row >> 10;
  int tid = threadIdx.x;
  __shared__ float red[8];
  const float* cur = x + (size_t)row * Cc;
  float cv[8], pv[8], cm, ci, pm = 0.f, pi = 1.f;
  block_ln(cur, tid, red, cv, cm, ci);
  bool t0 = (t == 0);
  const float* prev = t0 ? (shift + (size_t)bb * Cc) : (cur - Cc);
  if (!t0) {
    block_ln(prev, tid, red, pv, pm, pi);
  } else {
    #pragma unroll
    for (int i = 0; i < 8; i++) pv[i] = prev[tid + i * 256];
  }
  size_t o = (size_t)row * Cc;
  bool isLast = (t == Tt - 1);
  #pragma unroll
  for (int i = 0; i < 8; i++) {
    int c = tid + i * 256;
    float xc = (cv[i] - cm) * ci * w[c] + b[c];
    float xp = t0 ? pv[i] : (pv[i] - pm) * pi * w[c] + b[c];
    xk[o + c] = f2bf(xp + mk[c] * (xc - xp));
    xv[o + c] = f2bf(xp + mv[c] * (xc - xp));
    xr[o + c] = f2bf(xp + mr[c] * (xc - xp));
    xg[o + c] = f2bf(xp + mg[c] * (xc - xp));
    if (isLast) last[(size_t)bb * Cc + c] = xc;
  }
}

// ---------- fused LN + 2-way mix ----------
__global__ __launch_bounds__(256)
void ln_mix2(const float* __restrict__ x, const float* __restrict__ shift,
             const float* __restrict__ w, const float* __restrict__ b,
             const float* __restrict__ ck, const float* __restrict__ cr,
             u16* __restrict__ xck, u16* __restrict__ xcr,
             float* __restrict__ last) {
  int row = blockIdx.x;
  int t = row & (Tt - 1), bb = row >> 10;
  int tid = threadIdx.x;
  __shared__ float red[8];
  const float* cur = x + (size_t)row * Cc;
  float cv[8], pv[8], cm, ci, pm = 0.f, pi = 1.f;
  block_ln(cur, tid, red, cv, cm, ci);
  bool t0 = (t == 0);
  const float* prev = t0 ? (shift + (size_t)bb * Cc) : (cur - Cc);
  if (!t0) {
    block_ln(prev, tid, red, pv, pm, pi);
  } else {
    #pragma unroll
    for (int i = 0; i < 8; i++) pv[i] = prev[tid + i * 256];
  }
  size_t o = (size_t)row * Cc;
  bool isLast = (t == Tt - 1);
  #pragma unroll
  for (int i = 0; i < 8; i++) {
    int c = tid + i * 256;
    float xc = (cv[i] - cm) * ci * w[c] + b[c];
    float xp = t0 ? pv[i] : (pv[i] - pm) * pi * w[c] + b[c];
    xck[o + c] = f2bf(xp + ck[c] * (xc - xp));
    xcr[o + c] = f2bf(xp + cr[c] * (xc - xp));
    if (isLast) last[(size_t)bb * Cc + c] = xc;
  }
}

// ================= 256xBN deep-pipelined GEMM (8-wave, BK=64) =================
DEV int swzoff(int row, int off) {
  return (row << 7) +
         (off ^ ((((row >> 1) & 1) << 4) | (((row >> 2) & 1) << 5) | (((row >> 3) & 1) << 6)));
}

DEV void stage_half(const u16* __restrict__ gbase, int ldK, u16* slot, int tid) {
  #pragma unroll
  for (int c2 = 0; c2 < 2; c2++) {
    const int D = c2 * 8192 + tid * 16;
    const int row = D >> 7;
    const int off = (D & 127) ^ ((((row >> 1) & 1) << 4) | (((row >> 2) & 1) << 5) | (((row >> 3) & 1) << 6));
    gll16(gbase + (size_t)row * ldK + (off >> 1), (u16*)((char*)slot + D));
  }
}

// EPI: 0=f32, 1=bf16(+act silu), 3=relu^2->bf16, 4=X1+val->f32,
//      6=X1+sigmoid(val)*(X2+bf2f(X2b))->f32
template <int EPI, int NB>
DEV void g256_core(const u16* __restrict__ A, const u16* __restrict__ Bt,
                   int N, int K, int ldK,
                   float* __restrict__ Co, u16* __restrict__ Cb,
                   const float* __restrict__ X1, const float* __restrict__ X2,
                   const u16* __restrict__ X2b,
                   u16 (*lds)[8192], int m0, int n0, int act) {
  const int tid = threadIdx.x;
  const int w = tid >> 6, lane = tid & 63;
  const int l15 = lane & 15, l4 = lane >> 4;
  const int wm = (w & 3) * 64;
  const int wn = (w >> 2) * (NB * 64);
  const int ahalf = wm >> 7;
  const int arow0 = wm & 127;
  const int bhalf = (NB == 2) ? (w >> 2) : 0;
  const int nt = K >> 6;

  const u16* Ag = A + (size_t)m0 * ldK;
  const u16* Bg = Bt + (size_t)n0 * ldK;

  f32x4 acc[4][NB * 4] = {};
  bf16x8 a[4][2];

  stage_half(Ag, ldK, lds[0], tid);
  stage_half(Ag + (size_t)128 * ldK, ldK, lds[1], tid);
  stage_half(Bg, ldK, lds[4], tid);
  if constexpr (NB == 2) stage_half(Bg + (size_t)128 * ldK, ldK, lds[5], tid);
  if (nt > 1) {
    stage_half(Ag + 64, ldK, lds[2], tid);
    stage_half(Ag + (size_t)128 * ldK + 64, ldK, lds[3], tid);
    asm volatile("s_waitcnt vmcnt(4)" ::: "memory");
  } else {
    asm volatile("s_waitcnt vmcnt(0)" ::: "memory");
  }
  asm volatile("s_barrier" ::: "memory");

  for (int t = 0; t < nt; t++) {
    const int buf = t & 1;
    const char* Aslot = (const char*)lds[buf * 2 + ahalf];
    const char* Bslot = (const char*)lds[4 + buf * NB + bhalf];

#define G256_PHASE(p)                                                                       \
    {                                                                                       \
      constexpr int nh = (p) >> 1, kh = (p) & 1;                                            \
      if constexpr ((p) < 2) {                                                              \
        _Pragma("unroll")                                                                   \
        for (int mf = 0; mf < 4; mf++) {                                                    \
          const int row = arow0 + mf * 16 + l15;                                            \
          a[mf][kh] = *(const bf16x8*)(Aslot + swzoff(row, kh * 64 + l4 * 16));             \
        }                                                                                   \
      }                                                                                     \
      bf16x8 bfr[2 * NB];                                                                   \
      _Pragma("unroll")                                                                     \
      for (int j = 0; j < 2 * NB; j++) {                                                    \
        const int row = (NB == 2 ? 0 : wn) + (nh * 2 * NB + j) * 16 + l15;                  \
        bfr[j] = *(const bf16x8*)(Bslot + swzoff(row, kh * 64 + l4 * 16));                  \
      }                                                                                     \
      if constexpr ((p) == 0) {                                                             \
        if (t + 1 < nt) stage_half(Bg + (size_t)(t + 1) * 64, ldK,                          \
                                   lds[4 + ((t + 1) & 1) * NB], tid);                       \
      } else if constexpr ((p) == 1) {                                                      \
        if constexpr (NB == 2) {                                                            \
          if (t + 1 < nt) stage_half(Bg + (size_t)128 * ldK + (size_t)(t + 1) * 64, ldK,    \
                                     lds[4 + ((t + 1) & 1) * NB + 1], tid);                 \
        }                                                                                   \
      } else if constexpr ((p) == 2) {                                                      \
        if (t + 2 < nt) stage_half(Ag + (size_t)(t + 2) * 64, ldK, lds[buf << 1], tid);     \
      } else {                                                                              \
        if (t + 2 < nt) stage_half(Ag + (size_t)128 * ldK + (size_t)(t + 2) * 64, ldK,      \
                                   lds[(buf << 1) + 1], tid);                               \
      }                                                                                     \
      asm volatile("s_barrier" ::: "memory");                                               \
      __builtin_amdgcn_s_setprio(1);                                                       \
      _Pragma("unroll")                                                                     \
      for (int mf = 0; mf < 4; mf++)                                                        \
        _Pragma("unroll")                                                                   \
        for (int j = 0; j < 2 * NB; j++)                                                    \
          acc[mf][nh * 2 * NB + j] = __builtin_amdgcn_mfma_f32_16x16x32_bf16(               \
              a[mf][kh], bfr[j], acc[mf][nh * 2 * NB + j], 0, 0, 0);                        \
      __builtin_amdgcn_s_setprio(0);                                                       \
      if constexpr ((p) == 3) {                                                             \
        if (t + 2 < nt) asm volatile("s_waitcnt vmcnt(4)" ::: "memory");                    \
        else            asm volatile("s_waitcnt vmcnt(0)" ::: "memory");                    \
      }                                                                                     \
      asm volatile("s_barrier" ::: "memory");                                               \
    }

    G256_PHASE(0)
    G256_PHASE(1)
    G256_PHASE(2)
    G256_PHASE(3)
#undef G256_PHASE
  }

  #pragma unroll
  for (int mf = 0; mf < 4; mf++) {
    #pragma unroll
    for (int reg = 0; reg < 4; reg++) {
      const int gr = m0 + wm + mf * 16 + l4 * 4 + reg;
      const size_t ro = (size_t)gr * N;
      #pragma unroll
      for (int nf = 0; nf < NB * 4; nf++) {
        const int gc = n0 + wn + nf * 16 + l15;
        float val = acc[mf][nf][reg];
        if constexpr (EPI == 0) {
          Co[ro + gc] = val;
        } else if constexpr (EPI == 1) {
          if (act) val = val / (1.f + __expf(-val));
          Cb[ro + gc] = f2bf(val);
        } else if constexpr (EPI == 3) {
          float tr = fmaxf(val, 0.f);
          Cb[ro + gc] = f2bf(tr * tr);
        } else if constexpr (EPI == 4) {
          Co[ro + gc] = X1[ro + gc] + val;
        } else {
          float s = 1.f / (1.f + __expf(-val));
          float kvv = X2[ro + gc] + bf2f(X2b[ro + gc]);
          Co[ro + gc] = fmaf(s, kvv, X1[ro + gc]);
        }
      }
    }
  }
}

// BN=256 swizzled wrapper (grid 1D, nwg%8==0; tile order: x fastest over NX)
template <int EPI>
__global__ __launch_bounds__(512)
void gemm256s(const u16* __restrict__ A, const u16* __restrict__ Bt,
              int N, int K,
              float* __restrict__ Co, u16* __restrict__ Cb,
              const float* __restrict__ X1, int NX) {
  __shared__ __align__(16) u16 lds[8][8192];
  int o = xcd_swz(blockIdx.x, gridDim.x);
  int xb = o % NX, yb = o / NX;
  g256_core<EPI, 2>(A, Bt, N, K, K, Co, Cb, X1, nullptr, nullptr, lds,
                    yb * 256, xb * 256, 0);
}

// BN=128 swizzled wrapper
template <int EPI>
__global__ __launch_bounds__(512)
void gemm128s(const u16* __restrict__ A, const u16* __restrict__ Bt,
              int N, int K,
              float* __restrict__ Co, u16* __restrict__ Cb,
              const float* __restrict__ X1, const float* __restrict__ X2,
              const u16* __restrict__ X2b, int NX) {
  __shared__ __align__(16) u16 lds[6][8192];
  int o = xcd_swz(blockIdx.x, gridDim.x);
  int xb = o % NX, yb = o / NX;
  g256_core<EPI, 1>(A, Bt, N, K, K, Co, Cb, X1, X2, X2b, lds,
                    yb * 256, xb * 128, 0);
}

// projection GEMMs: grid 1D = 8*16*4, swizzled
__global__ __launch_bounds__(512)
void gemm256_proj(const u16* __restrict__ A0, const u16* __restrict__ A1,
                  const u16* __restrict__ A2, const u16* __restrict__ A3,
                  const u16* __restrict__ B0, const u16* __restrict__ B1,
                  const u16* __restrict__ B2, const u16* __restrict__ B3,
                  u16* __restrict__ C0, u16* __restrict__ C1,
                  u16* __restrict__ C2, u16* __restrict__ C3) {
  __shared__ __align__(16) u16 lds[8][8192];
  int o = xcd_swz(blockIdx.x, gridDim.x);
  int xb = o & 7, yb = (o >> 3) & 15, z = o >> 7;
  const u16* A = (z == 0) ? A0 : (z == 1) ? A1 : (z == 2) ? A2 : A3;
  const u16* Bt = (z == 0) ? B0 : (z == 1) ? B1 : (z == 2) ? B2 : B3;
  u16* Cb = (z == 0) ? C0 : (z == 1) ? C1 : (z == 2) ? C2 : C3;
  g256_core<1, 2>(A, Bt, Cc, Cc, Cc, nullptr, Cb, nullptr, nullptr, nullptr, lds,
                  yb * 256, xb * 256, z == 3);
}

// split-K=2 Wcv GEMM: M=4096, N=2048, K=7168 -> two K-halves of 3584.
// z=0 -> f32 partial kv0; z=1 -> bf16 partial kv1.
__global__ __launch_bounds__(512)
void gemm256_splitk(const u16* __restrict__ A, const u16* __restrict__ Bt,
                    float* __restrict__ kv0, u16* __restrict__ kv1) {
  __shared__ __align__(16) u16 lds[8][8192];
  int o = xcd_swz(blockIdx.x, gridDim.x);
  int xb = o & 7, yb = (o >> 3) & 15, z = o >> 7;
  const int Koff = z * (FF / 2);
  if (z == 0)
    g256_core<0, 2>(A + Koff, Bt + Koff, Cc, FF / 2, FF, kv0, nullptr,
                    nullptr, nullptr, nullptr, lds, yb * 256, xb * 256, 0);
  else
    g256_core<1, 2>(A + Koff, Bt + Koff, Cc, FF / 2, FF, nullptr, kv1,
                    nullptr, nullptr, nullptr, lds, yb * 256, xb * 256, 0);
}

// ======================= chunked WKV : three kernels =======================
__global__ __launch_bounds__(256)
void wkv_pre(const u16* __restrict__ rg, const u16* __restrict__ kg,
             const u16* __restrict__ vg, const float* __restrict__ td,
             const float* __restrict__ tf,
             float* __restrict__ Yb, float* __restrict__ Db,
             u16* __restrict__ Rtb) {
  __shared__ float Pt[64][68];
  __shared__ float uL[64];
  __shared__ u16 rB[64 * 72];
  __shared__ u16 kB[64 * 72];
  __shared__ u16 Rh[64 * 72];
  __shared__ u16 KhX[96 * 72];
  __shared__ u16 vA[64 * 72];
  __shared__ u16 Vt[64 * 72];

  const int tid = threadIdx.x, bid = blockIdx.x;
  const int bh = bid >> 4, c = bid & 15;
  const int b = bh >> 5, h = bh & 31;
  const int lane = tid & 63, w = tid >> 6;

  {
    int i = tid & 63;
    float d = __expf(td[h * 64 + i]);
    float c1 = -1.4426950408889634f * d;
    int e0 = (tid >> 6) * 16;
    #pragma unroll
    for (int e = 0; e < 16; e++) Pt[e0 + e][i] = exp2f(c1 * (float)(e0 + e));
    if (tid < 64) uL[tid] = tf[h * 64 + tid];
  }
  __syncthreads();

  const int row = tid >> 2, col0 = (tid & 3) * 16;
  const int tl = row & 15;
  {
    size_t gro = ((size_t)b * Tt + c * 64 + row) * Cc + h * 64 + col0;
    u16x8 rv0 = *(const u16x8*)(rg + gro);
    u16x8 rv1 = *(const u16x8*)(rg + gro + 8);
    u16x8 kv0 = *(const u16x8*)(kg + gro);
    u16x8 kv1 = *(const u16x8*)(kg + gro + 8);
    u16x8 vv0 = *(const u16x8*)(vg + gro);
    u16x8 vv1 = *(const u16x8*)(vg + gro + 8);
    *(u16x8*)&rB[row * 72 + col0] = rv0; *(u16x8*)&rB[row * 72 + col0 + 8] = rv1;
    *(u16x8*)&kB[row * 72 + col0] = kv0; *(u16x8*)&kB[row * 72 + col0 + 8] = kv1;
    *(u16x8*)&vA[row * 72 + col0] = vv0; *(u16x8*)&vA[row * 72 + col0 + 8] = vv1;
    float rf[16], kf[16];
    #pragma unroll
    for (int e = 0; e < 8; e++) { rf[e] = bf2f(rv0[e]); rf[8 + e] = bf2f(rv1[e]); }
    #pragma unroll
    for (int e = 0; e < 8; e++) { kf[e] = bf2f(kv0[e]); kf[8 + e] = bf2f(kv1[e]); }
    u16x8 o0, o1, t0_, t1_;
    #pragma unroll
    for (int e = 0; e < 8; e++) {
      o0[e] = f2bf(rf[e] * Pt[tl][col0 + e]);
      o1[e] = f2bf(rf[8 + e] * Pt[tl][col0 + 8 + e]);
      t0_[e] = f2bf(rf[e] * Pt[row][col0 + e]);
      t1_[e] = f2bf(rf[8 + e] * Pt[row][col0 + 8 + e]);
    }
    *(u16x8*)&Rh[row * 72 + col0] = o0; *(u16x8*)&Rh[row * 72 + col0 + 8] = o1;
    u16* rtp = Rtb + (size_t)bid * 4096 + row * 64 + col0;
    *(u16x8*)rtp = t0_; *(u16x8*)(rtp + 8) = t1_;
    if (row < 48) {
      u16x8 a0, a1;
      #pragma unroll
      for (int e = 0; e < 8; e++) {
        a0[e] = f2bf(kf[e] * Pt[15 - tl][col0 + e]);
        a1[e] = f2bf(kf[8 + e] * Pt[15 - tl][col0 + 8 + e]);
      }
      *(u16x8*)&KhX[row * 72 + col0] = a0; *(u16x8*)&KhX[row * 72 + col0 + 8] = a1;
    }
    if (row < 32) {
      u16x8 a0, a1;
      #pragma unroll
      for (int e = 0; e < 8; e++) {
        a0[e] = f2bf(kf[e] * Pt[31 - tl][col0 + e]);
        a1[e] = f2bf(kf[8 + e] * Pt[31 - tl][col0 + 8 + e]);
      }
      *(u16x8*)&KhX[(48 + row) * 72 + col0] = a0; *(u16x8*)&KhX[(48 + row) * 72 + col0 + 8] = a1;
    }
    if (row < 16) {
      u16x8 a0, a1;
      #pragma unroll
      for (int e = 0; e < 8; e++) {
        a0[e] = f2bf(kf[e] * Pt[47 - tl][col0 + e]);
        a1[e] = f2bf(kf[8 + e] * Pt[47 - tl][col0 + 8 + e]);
      }
      *(u16x8*)&KhX[(80 + row) * 72 + col0] = a0; *(u16x8*)&KhX[(80 + row) * 72 + col0 + 8] = a1;
    }
  }
  __syncthreads();

  {
    const int jj = tid & 63, s0 = (tid >> 6) * 16;
    #pragma unroll
    for (int ds = 0; ds < 16; ds += 2) {
      u32 pk = ((u32)vA[(s0 + ds + 1) * 72 + jj] << 16) | vA[(s0 + ds) * 72 + jj];
      *(u32*)&Vt[jj * 72 + s0 + ds] = pk;
    }
  }
  __syncthreads();

  u16* aB = vA;
  {
    const int pr[6] = {1, 2, 3, 2, 3, 3};
    const int qr[6] = {0, 1, 2, 0, 1, 0};
    const int dr[6] = {0, 0, 0, 1, 1, 2};
    const int lr = lane & 15, kq = lane >> 4;
    for (int pi = w; pi < 6; pi += 4) {
      const int p = pr[pi], q = qr[pi], d = dr[pi];
      const int kbase = (d == 0) ? q * 16 : (d == 1) ? 48 + q * 16 : 80 + q * 16;
      f32x4 aacc = {};
      #pragma unroll
      for (int kf2 = 0; kf2 < 2; kf2++) {
        bf16x8 af = *(const bf16x8*)&Rh[(p * 16 + lr) * 72 + kf2 * 32 + kq * 8];
        bf16x8 bf_ = *(const bf16x8*)&KhX[(kbase + lr) * 72 + kf2 * 32 + kq * 8];
        aacc = __builtin_amdgcn_mfma_f32_16x16x32_bf16(af, bf_, aacc, 0, 0, 0);
      }
      #pragma unroll
      for (int reg = 0; reg < 4; reg++) {
        aB[(p * 16 + kq * 4 + reg) * 72 + q * 16 + lr] = f2bf(aacc[reg]);
        aB[(q * 16 + kq * 4 + reg) * 72 + p * 16 + lr] = 0;
      }
    }
    for (int e = lane; e < 256; e += 64) {
      const int tl2 = e >> 4, sl = e & 15;
      float a = 0.f;
      if (sl <= tl2) {
        const u16* rp = &rB[(w * 16 + tl2) * 72];
        const u16* kp = &kB[(w * 16 + sl) * 72];
        const float* pp = (sl == tl2) ? uL : &Pt[tl2 - 1 - sl][0];
        #pragma unroll
        for (int i0 = 0; i0 < 64; i0 += 4) {
          u16x4 ra = *(const u16x4*)(rp + i0);
          u16x4 ka = *(const u16x4*)(kp + i0);
          f32x4 pa = *(const f32x4*)(pp + i0);
          #pragma unroll
          for (int di = 0; di < 4; di++)
            a = fmaf(bf2f(ra[di]) * bf2f(ka[di]), pa[di], a);
        }
      }
      aB[(w * 16 + tl2) * 72 + w * 16 + sl] = f2bf(a);
    }
  }
  __syncthreads();

  u16* Ktt = KhX;
  {
    const int ii = tid & 63, s0 = (tid >> 6) * 16;
    #pragma unroll
    for (int ds = 0; ds < 16; ds += 2) {
      float v0 = bf2f(kB[(s0 + ds) * 72 + ii]) * Pt[63 - (s0 + ds)][ii];
      float v1 = bf2f(kB[(s0 + ds + 1) * 72 + ii]) * Pt[63 - (s0 + ds + 1)][ii];
      u32 pk = ((u32)f2bf(v1) << 16) | f2bf(v0);
      *(u32*)&Ktt[ii * 72 + s0 + ds] = pk;
    }
  }
  __syncthreads();

  const int lr = lane & 15, kq = lane >> 4;
  {
    f32x4 yac[4] = {};
    #pragma unroll
    for (int kf2 = 0; kf2 < 2; kf2++) {
      bf16x8 af = *(const bf16x8*)&aB[(w * 16 + lr) * 72 + kf2 * 32 + kq * 8];
      #pragma unroll
      for (int nf = 0; nf < 4; nf++) {
        bf16x8 bf_ = *(const bf16x8*)&Vt[(nf * 16 + lr) * 72 + kf2 * 32 + kq * 8];
        yac[nf] = __builtin_amdgcn_mfma_f32_16x16x32_bf16(af, bf_, yac[nf], 0, 0, 0);
      }
    }
    float* Yp = Yb + (size_t)bid * 4096;
    #pragma unroll
    for (int nf = 0; nf < 4; nf++)
      #pragma unroll
      for (int reg = 0; reg < 4; reg++)
        Yp[(w * 16 + kq * 4 + reg) * 64 + nf * 16 + lr] = yac[nf][reg];

    f32x4 dac[4] = {};
    #pragma unroll
    for (int kf2 = 0; kf2 < 2; kf2++) {
      bf16x8 af = *(const bf16x8*)&Ktt[(w * 16 + lr) * 72 + kf2 * 32 + kq * 8];
      #pragma unroll
      for (int nf = 0; nf < 4; nf++) {
        bf16x8 bf_ = *(const bf16x8*)&Vt[(nf * 16 + lr) * 72 + kf2 * 32 + kq * 8];
        dac[nf] = __builtin_amdgcn_mfma_f32_16x16x32_bf16(af, bf_, dac[nf], 0, 0, 0);
      }
    }
    float* Dp = Db + (size_t)bid * 4096;
    #pragma unroll
    for (int nf = 0; nf < 4; nf++)
      #pragma unroll
      for (int reg = 0; reg < 4; reg++)
        Dp[(w * 16 + kq * 4 + reg) * 64 + nf * 16 + lr] = dac[nf][reg];
  }
}

__global__ __launch_bounds__(256)
void wkv_scan(const float* __restrict__ s0g, const float* __restrict__ td,
              const float* __restrict__ Db, u16* __restrict__ Sbb,
              float* __restrict__ sout) {
  const int bh = blockIdx.x, h = bh & 31;
  const int tid = threadIdx.x;
  const int i = tid >> 2, j0 = (tid & 3) * 16;
  float d = __expf(td[h * 64 + i]);
  float w64 = exp2f(-1.4426950408889634f * d * 64.f);
  f32x4 S[4];
  const float* sp = s0g + ((size_t)bh * 64 + i) * 64 + j0;
  #pragma unroll
  for (int q = 0; q < 4; q++) S[q] = *(const f32x4*)(sp + q * 4);
  for (int c = 0; c < NCH; c++) {
    u16* op = Sbb + ((size_t)(bh * 16 + c)) * 4096 + i * 64 + j0;
    u16x8 o0, o1;
    #pragma unroll
    for (int e = 0; e < 4; e++) { o0[e] = f2bf(S[0][e]); o0[4 + e] = f2bf(S[1][e]);
                                  o1[e] = f2bf(S[2][e]); o1[4 + e] = f2bf(S[3][e]); }
    *(u16x8*)op = o0; *(u16x8*)(op + 8) = o1;
    const float* dp = Db + ((size_t)(bh * 16 + c)) * 4096 + i * 64 + j0;
    #pragma unroll
    for (int q = 0; q < 4; q++) {
      f32x4 dv = *(const f32x4*)(dp + q * 4);
      #pragma unroll
      for (int e = 0; e < 4; e++) S[q][e] = fmaf(w64, S[q][e], dv[e]);
    }
  }
  float* fo = sout + ((size_t)bh * 64 + i) * 64 + j0;
  #pragma unroll
  for (int q = 0; q < 4; q++) *(f32x4*)(fo + q * 4) = S[q];
}

__global__ __launch_bounds__(256)
void wkv_post(const u16* __restrict__ Rtb, const u16* __restrict__ Sbb,
              const float* __restrict__ Yb, const u16* __restrict__ g,
              const float* __restrict__ gnw, const float* __restrict__ gnb,
              u16* __restrict__ xo) {
  __shared__ u16 Rt[64 * 72];
  __shared__ u16 St[64 * 72];
  __shared__ u16 xoL[64 * 72];
  const int tid = threadIdx.x, bid = blockIdx.x;
  const int bh = bid >> 4, c = bid & 15;
  const int b = bh >> 5, h = bh & 31;
  const int lane = tid & 63, w = tid >> 6;
  const int row = tid >> 2, col0 = (tid & 3) * 16;

  {
    const u16* rp = Rtb + (size_t)bid * 4096 + row * 64 + col0;
    u16x8 a0 = *(const u16x8*)rp, a1 = *(const u16x8*)(rp + 8);
    *(u16x8*)&Rt[row * 72 + col0] = a0; *(u16x8*)&Rt[row * 72 + col0 + 8] = a1;
  }
  {
    const u16* sp = Sbb + ((size_t)(bh * 16 + c)) * 4096 + row * 64 + col0;
    u16x8 s0 = *(const u16x8*)sp, s1 = *(const u16x8*)(sp + 8);
    #pragma unroll
    for (int e = 0; e < 8; e++) {
      St[(col0 + e) * 72 + row] = s0[e];
      St[(col0 + 8 + e) * 72 + row] = s1[e];
    }
  }
  const int lr = lane & 15, kq = lane >> 4;
  f32x4 acc[4];
  {
    const float* Yp = Yb + (size_t)bid * 4096;
    #pragma unroll
    for (int nf = 0; nf < 4; nf++)
      #pragma unroll
      for (int reg = 0; reg < 4; reg++)
        acc[nf][reg] = Yp[(w * 16 + kq * 4 + reg) * 64 + nf * 16 + lr];
  }
  __syncthreads();
  #pragma unroll
  for (int kf2 = 0; kf2 < 2; kf2++) {
    bf16x8 af = *(const bf16x8*)&Rt[(w * 16 + lr) * 72 + kf2 * 32 + kq * 8];
    #pragma unroll
    for (int nf = 0; nf < 4; nf++) {
      bf16x8 bf_ = *(const bf16x8*)&St[(nf * 16 + lr) * 72 + kf2 * 32 + kq * 8];
      acc[nf] = __builtin_amdgcn_mfma_f32_16x16x32_bf16(af, bf_, acc[nf], 0, 0, 0);
    }
  }
  #pragma unroll
  for (int reg = 0; reg < 4; reg++) {
    float s = 0.f, ss = 0.f;
    #pragma unroll
    for (int nf = 0; nf < 4; nf++) {
      float z = acc[nf][reg] * 0.125f;
      s += z; ss += z * z;
    }
    #pragma unroll
    for (int m = 1; m < 16; m <<= 1) { s += __shfl_xor(s, m); ss += __shfl_xor(ss, m); }
    float mean = s * (1.f / 64.f);
    float var = ss * (1.f / 64.f) - mean * mean;
    float inv = rsqrtf(var + 1e-5f);
    const int tau = w * 16 + kq * 4 + reg;
    #pragma unroll
    for (int nf = 0; nf < 4; nf++) {
      const int col = nf * 16 + lr;
      float z = acc[nf][reg] * 0.125f;
      float zn = (z - mean) * inv * gnw[h * 64 + col] + gnb[h * 64 + col];
      float gv = bf2f(g[((size_t)b * Tt + c * 64 + tau) * Cc + h * 64 + col]);
      xoL[tau * 72 + col] = f2bf(zn * gv);
    }
  }
  __syncthreads();
  {
    u16x8 o0 = *(const u16x8*)&xoL[row * 72 + col0];
    u16x8 o1 = *(const u16x8*)&xoL[row * 72 + col0 + 8];
    u16* xop = xo + ((size_t)b * Tt + c * 64 + row) * Cc + h * 64 + col0;
    *(u16x8*)xop = o0; *(u16x8*)(xop + 8) = o1;
  }
}

// ---------- orchestration ----------
extern "C" void kernel_launch(void* const* d_in, const int* in_sizes, int n_in,
                              void* d_out, int out_size, void* d_ws, size_t ws_size,
                              hipStream_t stream) {
  const float* x         = (const float*)d_in[0];
  const float* att_shift = (const float*)d_in[1];
  const float* wkv0      = (const float*)d_in[2];
  const float* ffn_shift = (const float*)d_in[3];
  const float* ln1w = (const float*)d_in[4];
  const float* ln1b = (const float*)d_in[5];
  const float* ln2w = (const float*)d_in[6];
  const float* ln2b = (const float*)d_in[7];
  const float* mixk = (const float*)d_in[8];
  const float* mixv = (const float*)d_in[9];
  const float* mixr = (const float*)d_in[10];
  const float* mixg = (const float*)d_in[11];
  const float* Wr = (const float*)d_in[12];
  const float* Wk = (const float*)d_in[13];
  const float* Wv = (const float*)d_in[14];
  const float* Wg = (const float*)d_in[15];
  const float* Wo = (const float*)d_in[16];
  const float* td = (const float*)d_in[17];
  const float* tf = (const float*)d_in[18];
  const float* gnw = (const float*)d_in[19];
  const float* gnb = (const float*)d_in[20];
  const float* cmk = (const float*)d_in[21];
  const float* cmr = (const float*)d_in[22];
  const float* Wck = (const float*)d_in[23];
  const float* Wcr = (const float*)d_in[24];
  const float* Wcv = (const float*)d_in[25];

  constexpr size_t SZ_CC = (size_t)Cc * Cc * 2;
  constexpr size_t SZ_CF = (size_t)Cc * FF * 2;
  constexpr size_t SZ_AB = (size_t)BT * Cc * 2;
  constexpr size_t O_W   = 0;
  constexpr size_t O_R1  = 6 * SZ_CC + 2 * SZ_CF;
  constexpr size_t R1_SZ = 4 * SZ_AB;
  constexpr size_t O_R2  = O_R1 + R1_SZ;
  constexpr size_t R2_SZ = 3 * SZ_AB;
  constexpr size_t O_R3  = O_R2 + R2_SZ;
  constexpr size_t WS_NEED = O_R3 + SZ_AB;

  if (ws_size < WS_NEED) return;

  char* ws = (char*)d_ws;
  u16* WrT  = (u16*)(ws + O_W);
  u16* WkT  = (u16*)(ws + O_W + 1 * SZ_CC);
  u16* WvT  = (u16*)(ws + O_W + 2 * SZ_CC);
  u16* WgT  = (u16*)(ws + O_W + 3 * SZ_CC);
  u16* WoT  = (u16*)(ws + O_W + 4 * SZ_CC);
  u16* WcrT = (u16*)(ws + O_W + 5 * SZ_CC);
  u16* WckT = (u16*)(ws + O_W + 6 * SZ_CC);
  u16* WcvT = (u16*)(ws + O_W + 6 * SZ_CC + SZ_CF);

  // R1: xk,xv,xr,xg -> (Yb | Rtb | Sbb) -> kk
  u16*   xk  = (u16*)(ws + O_R1);
  u16*   xv  = (u16*)(ws + O_R1 + SZ_AB);
  u16*   xr  = (u16*)(ws + O_R1 + 2 * SZ_AB);
  u16*   xg  = (u16*)(ws + O_R1 + 3 * SZ_AB);
  float* Yb  = (float*)(ws + O_R1);
  u16*   Rtb = (u16*)(ws + O_R1 + 2 * SZ_AB);
  u16*   Sbb = (u16*)(ws + O_R1 + 3 * SZ_AB);
  u16*   kk  = (u16*)(ws + O_R1);
  // R2: rb,kb,vb -> xcr,xck,xo -> xcr,kv0(f32,32MB over xck+xo)
  u16*   rb  = (u16*)(ws + O_R2);
  u16*   kb  = (u16*)(ws + O_R2 + SZ_AB);
  u16*   vb  = (u16*)(ws + O_R2 + 2 * SZ_AB);
  u16*   xcr = (u16*)(ws + O_R2);
  u16*   xck = (u16*)(ws + O_R2 + SZ_AB);
  u16*   xo  = (u16*)(ws + O_R2 + 2 * SZ_AB);
  float* kv0 = (float*)(ws + O_R2 + SZ_AB);
  // R3: gbuf -> kv1 (bf16)
  u16*   gbuf = (u16*)(ws + O_R3);
  u16*   kv1  = (u16*)(ws + O_R3);

  float* out      = (float*)d_out;
  float* x1_last  = out + (size_t)BT * Cc;
  float* wkv_out  = x1_last + (size_t)Bb * Cc;
  float* x2_last  = wkv_out + (size_t)Bb * Hh * Nd * Nd;
  float* Db       = out;  // free until Wo-gemm; scan consumes it first

  transpose6_cc<<<dim3(64, 64, 6), 256, 0, stream>>>(Wr, Wk, Wv, Wg, Wo, Wcr,
                                                     WrT, WkT, WvT, WgT, WoT, WcrT);
  transpose_to_bf16<<<dim3(224, 64), 256, 0, stream>>>(Wck, WckT, Cc, FF);
  transpose_to_bf16<<<dim3(64, 224), 256, 0, stream>>>(Wcv, WcvT, FF, Cc);

  ln_mix4<<<BT, 256, 0, stream>>>(x, att_shift, ln1w, ln1b,
                                  mixk, mixv, mixr, mixg, xk, xv, xr, xg, x1_last);
  gemm256_proj<<<512, 512, 0, stream>>>(xr, xk, xv, xg,
                                        WrT, WkT, WvT, WgT,
                                        rb, kb, vb, gbuf);
  wkv_pre<<<Bb * Hh * NCH, 256, 0, stream>>>(rb, kb, vb, td, tf, Yb, Db, Rtb);
  wkv_scan<<<Bb * Hh, 256, 0, stream>>>(wkv0, td, Db, Sbb, wkv_out);
  wkv_post<<<Bb * Hh * NCH, 256, 0, stream>>>(Rtb, Sbb, Yb, gbuf, gnw, gnb, xo);
  // x_after = x + xo @ Wo   (BN=128, 256 blocks, swizzled)
  gemm128s<4><<<256, 512, 0, stream>>>(xo, WoT, Cc, Cc, out, nullptr, x,
                                       nullptr, nullptr, 16);
  ln_mix2<<<BT, 256, 0, stream>>>(out, ffn_shift, ln2w, ln2b, cmk, cmr, xck, xcr, x2_last);
  // kk = relu(xck @ Wck)^2   (BN=256, 448 blocks, swizzled)
  gemm256s<3><<<448, 512, 0, stream>>>(xck, WckT, FF, Cc, nullptr, kk, nullptr, 28);
  // kv partials = kk @ Wcv   (split-K=2, 256 blocks, swizzled)
  gemm256_splitk<<<256, 512, 0, stream>>>(kk, WcvT, kv0, kv1);
  // out = x_after + sigmoid(xcr @ Wcr) * (kv0 + kv1)
  gemm128s<6><<<256, 512, 0, stream>>>(xcr, WcrT, Cc, Cc, out, nullptr, out,
                                       kv0, kv1, 16);

  (void)in_sizes; (void)n_in; (void)out_size;
}